// Round 1
// baseline (6474.332 us; speedup 1.0000x reference)
//
#include <hip/hip_runtime.h>
#include <cstdint>

#define B_ 16
#define N_ 1024
#define T_ 12
#define HD 64
#define BN_ (B_*N_)     // 16384
#define BNT (B_*N_*T_)  // 196608
#define TD (T_*HD)      // 768

__device__ __forceinline__ float sigmoidf_(float x) { return 1.f / (1.f + __expf(-x)); }

#define F4E(v, ii) ((ii)==0?(v).x:((ii)==1?(v).y:((ii)==2?(v).z:(v).w)))

// ---------------- reductions ----------------
__device__ __forceinline__ float blkRedMax(float v, float* red) {
  #pragma unroll
  for (int off = 32; off >= 1; off >>= 1) v = fmaxf(v, __shfl_xor(v, off));
  int w = threadIdx.x >> 6;
  if ((threadIdx.x & 63) == 0) red[w] = v;
  __syncthreads();
  v = fmaxf(fmaxf(red[0], red[1]), fmaxf(red[2], red[3]));
  __syncthreads();
  return v;
}
__device__ __forceinline__ float blkRedSum(float v, float* red) {
  #pragma unroll
  for (int off = 32; off >= 1; off >>= 1) v += __shfl_xor(v, off);
  int w = threadIdx.x >> 6;
  if ((threadIdx.x & 63) == 0) red[w] = v;
  __syncthreads();
  v = red[0] + red[1] + red[2] + red[3];
  __syncthreads();
  return v;
}

// ---------------- K1: embed concat + gfs_fc + GLU ----------------
__global__ __launch_bounds__(256) void k_embed(
    const float* __restrict__ flow, const int* __restrict__ day, const int* __restrict__ week,
    const float* __restrict__ semb, const float* __restrict__ demb, const float* __restrict__ wemb,
    const float* __restrict__ w1, const float* __restrict__ b1,
    const float* __restrict__ w2, const float* __restrict__ b2,
    float* __restrict__ out)
{
  __shared__ float sW1t[64*64];    // [k][d]  (transposed for bank-friendly reads)
  __shared__ float sW2t[64*128];   // [k][j]
  __shared__ float svv[16][64];
  __shared__ float sx[16][64];
  int tid = threadIdx.x;
  for (int i = tid; i < 4096; i += 256) sW1t[(i & 63)*64  + (i >> 6)] = w1[i];
  for (int i = tid; i < 8192; i += 256) sW2t[(i & 63)*128 + (i >> 6)] = w2[i];
  int row0 = blockIdx.x * 16;
  for (int i = tid; i < 1024; i += 256) {
    int r = i >> 6, c = i & 63;
    int row = row0 + r;
    int n = (row / T_) % N_;
    float val;
    if (c == 0)      val = flow[row];
    else if (c < 33) val = semb[n*32 + (c-1)];
    else if (c < 49) val = demb[day[row]*16 + (c-33)];
    else             val = wemb[week[row]*15 + (c-49)];
    svv[r][c] = val;
  }
  __syncthreads();
  for (int i = tid; i < 1024; i += 256) {
    int r = i >> 6, d = i & 63;
    float acc = b1[d];
    #pragma unroll 8
    for (int k = 0; k < 64; ++k) acc += sW1t[k*64 + d] * svv[r][k];
    sx[r][d] = acc;
  }
  __syncthreads();
  for (int i = tid; i < 1024; i += 256) {
    int r = i >> 6, d = i & 63;
    float lo = b2[d], hi = b2[64 + d];
    #pragma unroll 8
    for (int k = 0; k < 64; ++k) {
      float xv = sx[r][k];
      lo += sW2t[k*128 + d]      * xv;
      hi += sW2t[k*128 + 64 + d] * xv;
    }
    out[(size_t)(row0 + r)*64 + d] = lo * sigmoidf_(hi);
  }
}

// ---------------- K2: A = softmax(relu(A1),1) + softmax(relu(A2),1) ----------------
__global__ __launch_bounds__(256) void k_aprep(
    const float* __restrict__ A1, const float* __restrict__ A2, float* __restrict__ Aout)
{
  __shared__ float red[4];
  int m = blockIdx.x, tid = threadIdx.x;
  float mx0, is0, mx1, is1;
  {
    const float* src = A1 + (size_t)m*N_;
    float mx = 0.f;
    for (int i = tid; i < N_; i += 256) mx = fmaxf(mx, fmaxf(src[i], 0.f));
    mx = blkRedMax(mx, red);
    float s = 0.f;
    for (int i = tid; i < N_; i += 256) s += __expf(fmaxf(src[i], 0.f) - mx);
    s = blkRedSum(s, red);
    mx0 = mx; is0 = 1.f / s;
  }
  {
    const float* src = A2 + (size_t)m*N_;
    float mx = 0.f;
    for (int i = tid; i < N_; i += 256) mx = fmaxf(mx, fmaxf(src[i], 0.f));
    mx = blkRedMax(mx, red);
    float s = 0.f;
    for (int i = tid; i < N_; i += 256) s += __expf(fmaxf(src[i], 0.f) - mx);
    s = blkRedSum(s, red);
    mx1 = mx; is1 = 1.f / s;
  }
  const float* s1 = A1 + (size_t)m*N_;
  const float* s2 = A2 + (size_t)m*N_;
  for (int i = tid; i < N_; i += 256) {
    float v1 = __expf(fmaxf(s1[i], 0.f) - mx0) * is0;
    float v2 = __expf(fmaxf(s2[i], 0.f) - mx1) * is1;
    Aout[(size_t)m*N_ + i] = v1 + v2;
  }
}

// ---------------- K3/K8: C[b] (MxP) = A (MxK) @ X[b] (KxP) ----------------
__global__ __launch_bounds__(256) void k_gemm(
    const float* __restrict__ A, const float* __restrict__ X, float* __restrict__ C,
    int M, int K, int P)
{
  __shared__ float sA[16][64];
  __shared__ float sX[16][64];
  int tid = threadIdx.x;
  int b = blockIdx.z;
  const float* Xb = X + (size_t)b * K * P;
  float* Cb = C + (size_t)b * M * P;
  int m0 = blockIdx.y * 64, p0 = blockIdx.x * 64;
  int tm = (tid >> 4) * 4, tp = (tid & 15) * 4;
  float acc[4][4] = {};
  for (int k0 = 0; k0 < K; k0 += 16) {
    for (int i = tid; i < 1024; i += 256) {
      int m = i >> 4, k = i & 15;
      sA[k][m] = A[(size_t)(m0+m)*K + k0 + k];
      int kk = i >> 6, p = i & 63;
      sX[kk][p] = Xb[(size_t)(k0+kk)*P + p0 + p];
    }
    __syncthreads();
    #pragma unroll
    for (int k = 0; k < 16; ++k) {
      float av[4], xv[4];
      *(float4*)av = *(const float4*)&sA[k][tm];
      *(float4*)xv = *(const float4*)&sX[k][tp];
      #pragma unroll
      for (int u = 0; u < 4; ++u)
        #pragma unroll
        for (int v = 0; v < 4; ++v) acc[u][v] += av[u]*xv[v];
    }
    __syncthreads();
  }
  #pragma unroll
  for (int u = 0; u < 4; ++u)
    #pragma unroll
    for (int v = 0; v < 4; ++v)
      Cb[(size_t)(m0+tm+u)*P + p0+tp+v] = acc[u][v];
}

// ---------------- K4: out = relu(in @ gc_weight) rowwise ----------------
__global__ __launch_bounds__(256) void k_rowmat_relu(
    const float* __restrict__ in, const float* __restrict__ W, float* __restrict__ out)
{
  __shared__ float sW[4096];   // [d][e] natural layout
  __shared__ float sx[16][64];
  int tid = threadIdx.x;
  for (int i = tid; i < 4096; i += 256) sW[i] = W[i];
  int row0 = blockIdx.x * 16;
  for (int i = tid; i < 1024; i += 256) sx[i >> 6][i & 63] = in[(size_t)row0*64 + i];
  __syncthreads();
  for (int i = tid; i < 1024; i += 256) {
    int r = i >> 6, e = i & 63;
    float acc = 0.f;
    #pragma unroll 8
    for (int d = 0; d < 64; ++d) acc += sx[r][d] * sW[d*64 + e];
    out[(size_t)(row0 + r)*64 + e] = fmaxf(acc, 0.f);
  }
}

// ---------------- K5: full ds temporal-conv block, 4 (b,n) pairs per block ----------------
__global__ __launch_bounds__(256) void k_ds(
    const float* __restrict__ xg,
    const float* __restrict__ wi,  const float* __restrict__ bi,
    const float* __restrict__ w1m, const float* __restrict__ b1m,
    const float* __restrict__ w1g, const float* __restrict__ b1g,
    const float* __restrict__ w2m, const float* __restrict__ b2m,
    const float* __restrict__ w2g, const float* __restrict__ b2g,
    const float* __restrict__ wfc, const float* __restrict__ bfc,
    float* __restrict__ out)
{
  __shared__ float smem[13312];           // 52 KB
  float* xinit = smem;                    // [4][14][128]  (t padded)
  float* xin   = smem + 7168;             // [4][14][64]   (t padded) -- dead after phase 2
  float* pout  = smem + 7168;             // [4][12][128]  -- reuses xin space
  int tid = threadIdx.x;
  int bn0 = blockIdx.x * 4;

  // phase 1: load input tile with zero pad rows; zero xinit pads
  for (int i = tid; i < 4*14*64; i += 256) {
    int g = i / 896, r = i - g*896, tp = r >> 6, d = r & 63;
    float v = 0.f;
    if (tp >= 1 && tp <= 12) v = xg[((size_t)(bn0+g)*12 + (tp-1))*64 + d];
    xin[i] = v;
  }
  for (int i = tid; i < 512; i += 256) {
    int g = i >> 7, j = i & 127;
    xinit[g*1792 + j] = 0.f;
    xinit[g*1792 + 13*128 + j] = 0.f;
  }
  __syncthreads();

  // phase 2: x_init = conv1x3(xin, wi) + bi   (128 out channels)
  {
    int o = tid & 127, th = tid >> 7, t0 = th*6;
    float acc[4][6];
    float bias = bi[o];
    #pragma unroll
    for (int g = 0; g < 4; ++g)
      #pragma unroll
      for (int t = 0; t < 6; ++t) acc[g][t] = bias;
    for (int i0 = 0; i0 < 64; i0 += 4) {
      float w[12];
      #pragma unroll
      for (int k = 0; k < 3; ++k)
        #pragma unroll
        for (int ii = 0; ii < 4; ++ii)
          w[k*4+ii] = wi[o*192 + (i0+ii)*3 + k];
      #pragma unroll
      for (int g = 0; g < 4; ++g) {
        float4 xq[8];
        #pragma unroll
        for (int u = 0; u < 8; ++u)
          xq[u] = *(const float4*)&xin[g*896 + (t0+u)*64 + i0];
        #pragma unroll
        for (int k = 0; k < 3; ++k)
          #pragma unroll
          for (int ii = 0; ii < 4; ++ii) {
            float wv = w[k*4+ii];
            #pragma unroll
            for (int t = 0; t < 6; ++t)
              acc[g][t] += wv * F4E(xq[t+k], ii);
          }
      }
    }
    #pragma unroll
    for (int g = 0; g < 4; ++g)
      #pragma unroll
      for (int t = 0; t < 6; ++t)
        xinit[g*1792 + (t0 + t + 1)*128 + o] = acc[g][t];
  }
  __syncthreads();

  // phases 3+4: gated convs on each 64-ch half
  {
    int o = tid & 63, th = tid >> 6, t0 = th*3;
    #pragma unroll
    for (int half = 0; half < 2; ++half) {
      const float* wm  = half ? w2m : w1m;
      const float* wgt = half ? w2g : w1g;
      float bm = (half ? b2m : b1m)[o];
      float bg = (half ? b2g : b1g)[o];
      float accm[4][3], accg[4][3];
      #pragma unroll
      for (int g = 0; g < 4; ++g)
        #pragma unroll
        for (int t = 0; t < 3; ++t) { accm[g][t] = bm; accg[g][t] = bg; }
      for (int i0 = 0; i0 < 64; i0 += 4) {
        float wma[12], wga[12];
        #pragma unroll
        for (int k = 0; k < 3; ++k)
          #pragma unroll
          for (int ii = 0; ii < 4; ++ii) {
            wma[k*4+ii] = wm [o*192 + (i0+ii)*3 + k];
            wga[k*4+ii] = wgt[o*192 + (i0+ii)*3 + k];
          }
        #pragma unroll
        for (int g = 0; g < 4; ++g) {
          float4 xq[5];
          #pragma unroll
          for (int u = 0; u < 5; ++u)
            xq[u] = *(const float4*)&xinit[g*1792 + (t0+u)*128 + half*64 + i0];
          #pragma unroll
          for (int k = 0; k < 3; ++k)
            #pragma unroll
            for (int ii = 0; ii < 4; ++ii) {
              float wvm = wma[k*4+ii], wvg = wga[k*4+ii];
              #pragma unroll
              for (int t = 0; t < 3; ++t) {
                float xv = F4E(xq[t+k], ii);
                accm[g][t] += wvm * xv;
                accg[g][t] += wvg * xv;
              }
            }
        }
      }
      #pragma unroll
      for (int g = 0; g < 4; ++g)
        #pragma unroll
        for (int t = 0; t < 3; ++t)
          pout[g*1536 + (t0+t)*128 + half*64 + o] = accm[g][t] * sigmoidf_(accg[g][t]);
    }
  }
  __syncthreads();

  // fused = relu(pout + x_init)
  for (int i = tid; i < 6144; i += 256) {
    int g = i / 1536, r = i - g*1536, t = r >> 7, j = r & 127;
    pout[i] = fmaxf(pout[i] + xinit[g*1792 + (t+1)*128 + j], 0.f);
  }
  __syncthreads();

  // ds_fc: out[t][e] = bfc[e] + sum_j fused[t][j]*wfc[e*128+j]
  {
    int o = tid & 63, th = tid >> 6, t0 = th*3;
    float acc[4][3];
    float bias = bfc[o];
    #pragma unroll
    for (int g = 0; g < 4; ++g)
      #pragma unroll
      for (int t = 0; t < 3; ++t) acc[g][t] = bias;
    for (int j0 = 0; j0 < 128; j0 += 4) {
      float4 w4 = *(const float4*)&wfc[o*128 + j0];
      #pragma unroll
      for (int g = 0; g < 4; ++g)
        #pragma unroll
        for (int t = 0; t < 3; ++t) {
          float4 f4 = *(const float4*)&pout[g*1536 + (t0+t)*128 + j0];
          acc[g][t] += w4.x*f4.x + w4.y*f4.y + w4.z*f4.z + w4.w*f4.w;
        }
    }
    #pragma unroll
    for (int g = 0; g < 4; ++g)
      #pragma unroll
      for (int t = 0; t < 3; ++t)
        out[((size_t)(bn0+g)*12 + (t0+t))*64 + o] = acc[g][t];
  }
}

// ---------------- K6: attention + FFN + 2x layernorm, one (b,n) per block ----------------
__global__ __launch_bounds__(256) void k_attn(
    const float* __restrict__ xg,
    const float* __restrict__ wq, const float* __restrict__ bq,
    const float* __restrict__ wk, const float* __restrict__ bk,
    const float* __restrict__ wv, const float* __restrict__ bv,
    const float* __restrict__ wo, const float* __restrict__ bo,
    const float* __restrict__ f1w, const float* __restrict__ f1b,
    const float* __restrict__ f2w, const float* __restrict__ f2b,
    const float* __restrict__ g1, const float* __restrict__ be1,
    const float* __restrict__ g2, const float* __restrict__ be2,
    float* __restrict__ outg)
{
  __shared__ float sy[768], sq[768], sk[768], svv[768], so[768];
  __shared__ float ss[576];
  __shared__ float sh[3072];
  __shared__ float smu[12], srs[12];
  int tid = threadIdx.x;
  size_t base = (size_t)blockIdx.x * 768;
  for (int i = tid; i < 768; i += 256) sy[i] = xg[base + i];
  __syncthreads();
  // qkv
  for (int i = tid; i < 2304; i += 256) {
    int sel = i / 768, r = i - sel*768, t = r >> 6, d = r & 63;
    const float* W = sel == 0 ? wq : (sel == 1 ? wk : wv);
    float acc = (sel == 0 ? bq : (sel == 1 ? bk : bv))[d];
    const float* wr = W + d*64;
    const float* yr = sy + t*64;
    #pragma unroll 8
    for (int j = 0; j < 64; ++j) acc += wr[j] * yr[j];
    (sel == 0 ? sq : (sel == 1 ? sk : svv))[r] = acc;
  }
  __syncthreads();
  // scores
  for (int i = tid; i < 576; i += 256) {
    int h = i / 144, r = i - h*144, l = r / 12, s2 = r - l*12;
    const float* qr = sq + l*64 + h*16;
    const float* kr = sk + s2*64 + h*16;
    float acc = 0.f;
    #pragma unroll
    for (int j = 0; j < 16; ++j) acc += qr[j]*kr[j];
    ss[i] = acc * 0.25f;   // 1/sqrt(16)
  }
  __syncthreads();
  if (tid < 48) {
    float* row = ss + tid*12;
    float mx = row[0];
    for (int j = 1; j < 12; ++j) mx = fmaxf(mx, row[j]);
    float sum = 0.f;
    for (int j = 0; j < 12; ++j) { float e = __expf(row[j]-mx); row[j] = e; sum += e; }
    float inv = 1.f/sum;
    for (int j = 0; j < 12; ++j) row[j] *= inv;
  }
  __syncthreads();
  // o = attn @ v
  for (int i = tid; i < 768; i += 256) {
    int l = i >> 6, d = i & 63, h = d >> 4;
    float acc = 0.f;
    #pragma unroll
    for (int s2 = 0; s2 < 12; ++s2) acc += ss[h*144 + l*12 + s2] * svv[s2*64 + d];
    so[i] = acc;
  }
  __syncthreads();
  // z = y + wo(o) + bo  -> sq
  for (int i = tid; i < 768; i += 256) {
    int t = i >> 6, d = i & 63;
    float acc = bo[d];
    const float* wr = wo + d*64;
    const float* orow = so + t*64;
    #pragma unroll 8
    for (int j = 0; j < 64; ++j) acc += wr[j]*orow[j];
    sq[i] = sy[i] + acc;
  }
  __syncthreads();
  if (tid < 12) {
    const float* row = sq + tid*64;
    float m = 0.f;
    for (int j = 0; j < 64; ++j) m += row[j];
    m *= (1.f/64.f);
    float v = 0.f;
    for (int j = 0; j < 64; ++j) { float dd = row[j]-m; v += dd*dd; }
    v *= (1.f/64.f);
    smu[tid] = m; srs[tid] = rsqrtf(v + 1e-5f);
  }
  __syncthreads();
  for (int i = tid; i < 768; i += 256) {
    int t = i >> 6, d = i & 63;
    sk[i] = (sq[i]-smu[t])*srs[t]*g1[d] + be1[d];  // y1 -> sk
  }
  __syncthreads();
  // ff1
  for (int i = tid; i < 3072; i += 256) {
    int t = i >> 8, f = i & 255;
    float acc = f1b[f];
    const float* wr = f1w + f*64;
    const float* yr = sk + t*64;
    #pragma unroll 8
    for (int j = 0; j < 64; ++j) acc += wr[j]*yr[j];
    sh[i] = fmaxf(acc, 0.f);
  }
  __syncthreads();
  // ff2 + residual -> sq
  for (int i = tid; i < 768; i += 256) {
    int t = i >> 6, d = i & 63;
    float acc = f2b[d];
    const float* wr = f2w + d*256;
    const float* hr = sh + t*256;
    #pragma unroll 8
    for (int j = 0; j < 256; ++j) acc += wr[j]*hr[j];
    sq[i] = sk[i] + acc;
  }
  __syncthreads();
  if (tid < 12) {
    const float* row = sq + tid*64;
    float m = 0.f;
    for (int j = 0; j < 64; ++j) m += row[j];
    m *= (1.f/64.f);
    float v = 0.f;
    for (int j = 0; j < 64; ++j) { float dd = row[j]-m; v += dd*dd; }
    v *= (1.f/64.f);
    smu[tid] = m; srs[tid] = rsqrtf(v + 1e-5f);
  }
  __syncthreads();
  for (int i = tid; i < 768; i += 256) {
    int t = i >> 6, d = i & 63;
    outg[base + i] = (sq[i]-smu[t])*srs[t]*g2[d] + be2[d];
  }
}

// ---------------- K7: fuse-matrix prep ----------------
__global__ void k_mvec(const float* __restrict__ flow, const float* __restrict__ clw,
                       const float* __restrict__ clb, float* __restrict__ mv)
{
  int n = blockIdx.x*blockDim.x + threadIdx.x;
  if (n < N_) {
    float s = 0.f;
    float bias = clb[0];
    for (int b = 0; b < B_; ++b) {
      const float* f = flow + ((size_t)b*N_ + n)*T_;
      float acc = bias;
      #pragma unroll
      for (int t = 0; t < T_; ++t) acc += f[t]*clw[t];
      s += fmaxf(acc, 0.f);
    }
    mv[n] = s * (1.f/16.f);
  }
}

__global__ void k_fusemat(const float* __restrict__ mv, float* __restrict__ F)
{
  int idx = blockIdx.x*256 + threadIdx.x;
  int m = idx >> 10, n = idx & 1023;
  float x = 0.5f*(mv[m] + mv[n]);
  F[idx] = 1.f/(1.f + __expf(-x));
}

// ---------------- launch ----------------
extern "C" void kernel_launch(void* const* d_in, const int* in_sizes, int n_in,
                              void* d_out, int out_size, void* d_ws, size_t ws_size,
                              hipStream_t stream)
{
  const float* flow = (const float*)d_in[0];
  const int*   day  = (const int*)d_in[1];
  const int*   week = (const int*)d_in[2];
  const float* semb = (const float*)d_in[3];
  const float* demb = (const float*)d_in[4];
  const float* wemb = (const float*)d_in[5];
  const float* gfsw = (const float*)d_in[6];
  const float* gfsb = (const float*)d_in[7];
  const float* gluw = (const float*)d_in[8];
  const float* glub = (const float*)d_in[9];
  const float* gcw  = (const float*)d_in[10];
  const float* gcA  = (const float*)d_in[11];
  const float* gcA2 = (const float*)d_in[12];
  const float* wi   = (const float*)d_in[13];
  const float* bi   = (const float*)d_in[14];
  const float* w1m  = (const float*)d_in[15];
  const float* b1m  = (const float*)d_in[16];
  const float* w1g  = (const float*)d_in[17];
  const float* b1g  = (const float*)d_in[18];
  const float* w2m  = (const float*)d_in[19];
  const float* b2m  = (const float*)d_in[20];
  const float* w2g  = (const float*)d_in[21];
  const float* b2g  = (const float*)d_in[22];
  const float* wfc  = (const float*)d_in[23];
  const float* bfc  = (const float*)d_in[24];
  const float* wq   = (const float*)d_in[25];
  const float* bq   = (const float*)d_in[26];
  const float* wk   = (const float*)d_in[27];
  const float* bk   = (const float*)d_in[28];
  const float* wv   = (const float*)d_in[29];
  const float* bv   = (const float*)d_in[30];
  const float* wo   = (const float*)d_in[31];
  const float* bo   = (const float*)d_in[32];
  const float* f1w  = (const float*)d_in[33];
  const float* f1b  = (const float*)d_in[34];
  const float* f2w  = (const float*)d_in[35];
  const float* f2b  = (const float*)d_in[36];
  const float* g1   = (const float*)d_in[37];
  const float* be1  = (const float*)d_in[38];
  const float* g2   = (const float*)d_in[39];
  const float* be2  = (const float*)d_in[40];
  const float* clw  = (const float*)d_in[41];
  const float* clb  = (const float*)d_in[42];

  float* out = (float*)d_out;
  char* ws = (char*)d_ws;
  float* Amat = (float*)ws;                                   // 4 MB (N*N)
  float* mv   = (float*)(ws + (size_t)4*1024*1024);           // 4 KB
  float* buf0 = (float*)(ws + (size_t)4*1024*1024 + 65536);   // 48 MB (BNT*64)

  // x0 = GLU(gfs_fc(embed)) -> buf0
  k_embed<<<BNT/16, 256, 0, stream>>>(flow, day, week, semb, demb, wemb,
                                      gfsw, gfsb, gluw, glub, buf0);
  // combined adjacency
  k_aprep<<<N_, 256, 0, stream>>>(gcA, gcA2, Amat);
  // hs = A @ x0 -> d_out
  dim3 gg(TD/64, N_/64, B_);
  k_gemm<<<gg, 256, 0, stream>>>(Amat, buf0, out, N_, N_, TD);
  // x2 = relu(hs @ gc_weight) -> buf0
  k_rowmat_relu<<<BNT/16, 256, 0, stream>>>(out, gcw, buf0);
  // x3 = ds block -> d_out
  k_ds<<<BN_/4, 256, 0, stream>>>(buf0, wi, bi, w1m, b1m, w1g, b1g,
                                  w2m, b2m, w2g, b2g, wfc, bfc, out);
  // y2 = attn+ffn block -> buf0
  k_attn<<<BN_, 256, 0, stream>>>(out, wq, bq, wk, bk, wv, bv, wo, bo,
                                  f1w, f1b, f2w, f2b, g1, be1, g2, be2, buf0);
  // fuse matrix
  k_mvec<<<N_/256, 256, 0, stream>>>(flow, clw, clb, mv);
  k_fusemat<<<(N_*N_)/256, 256, 0, stream>>>(mv, Amat);
  // out = fuse @ y2 -> d_out
  k_gemm<<<gg, 256, 0, stream>>>(Amat, buf0, out, N_, N_, TD);
}

// Round 2
// 2686.618 us; speedup vs baseline: 2.4098x; 2.4098x over previous
//
#include <hip/hip_runtime.h>
#include <cstdint>

#define B_ 16
#define N_ 1024
#define T_ 12
#define HD 64
#define BN_ (B_*N_)     // 16384
#define BNT (B_*N_*T_)  // 196608
#define TD (T_*HD)      // 768

__device__ __forceinline__ float sigmoidf_(float x) { return 1.f / (1.f + __expf(-x)); }

#define F4E(v, ii) ((ii)==0?(v).x:((ii)==1?(v).y:((ii)==2?(v).z:(v).w)))

// ---------------- reductions ----------------
__device__ __forceinline__ float blkRedMax(float v, float* red) {
  #pragma unroll
  for (int off = 32; off >= 1; off >>= 1) v = fmaxf(v, __shfl_xor(v, off));
  int w = threadIdx.x >> 6;
  if ((threadIdx.x & 63) == 0) red[w] = v;
  __syncthreads();
  v = fmaxf(fmaxf(red[0], red[1]), fmaxf(red[2], red[3]));
  __syncthreads();
  return v;
}
__device__ __forceinline__ float blkRedSum(float v, float* red) {
  #pragma unroll
  for (int off = 32; off >= 1; off >>= 1) v += __shfl_xor(v, off);
  int w = threadIdx.x >> 6;
  if ((threadIdx.x & 63) == 0) red[w] = v;
  __syncthreads();
  v = red[0] + red[1] + red[2] + red[3];
  __syncthreads();
  return v;
}
__device__ __forceinline__ float waveRedSum(float v) {
  #pragma unroll
  for (int off = 32; off >= 1; off >>= 1) v += __shfl_xor(v, off);
  return v;
}

// ---------------- K1: embed concat + gfs_fc + GLU ----------------
__global__ __launch_bounds__(256) void k_embed(
    const float* __restrict__ flow, const int* __restrict__ day, const int* __restrict__ week,
    const float* __restrict__ semb, const float* __restrict__ demb, const float* __restrict__ wemb,
    const float* __restrict__ w1, const float* __restrict__ b1,
    const float* __restrict__ w2, const float* __restrict__ b2,
    float* __restrict__ out)
{
  __shared__ float sW1t[64*64];    // [k][d]
  __shared__ float sW2t[64*128];   // [k][j]
  __shared__ float svv[16][64];
  __shared__ float sx[16][64];
  int tid = threadIdx.x;
  for (int i = tid; i < 4096; i += 256) sW1t[(i & 63)*64  + (i >> 6)] = w1[i];
  for (int i = tid; i < 8192; i += 256) sW2t[(i & 63)*128 + (i >> 6)] = w2[i];
  int row0 = blockIdx.x * 16;
  for (int i = tid; i < 1024; i += 256) {
    int r = i >> 6, c = i & 63;
    int row = row0 + r;
    int n = (row / T_) % N_;
    float val;
    if (c == 0)      val = flow[row];
    else if (c < 33) val = semb[n*32 + (c-1)];
    else if (c < 49) val = demb[day[row]*16 + (c-33)];
    else             val = wemb[week[row]*15 + (c-49)];
    svv[r][c] = val;
  }
  __syncthreads();
  for (int i = tid; i < 1024; i += 256) {
    int r = i >> 6, d = i & 63;
    float acc = b1[d];
    #pragma unroll 8
    for (int k = 0; k < 64; ++k) acc += sW1t[k*64 + d] * svv[r][k];
    sx[r][d] = acc;
  }
  __syncthreads();
  for (int i = tid; i < 1024; i += 256) {
    int r = i >> 6, d = i & 63;
    float lo = b2[d], hi = b2[64 + d];
    #pragma unroll 8
    for (int k = 0; k < 64; ++k) {
      float xv = sx[r][k];
      lo += sW2t[k*128 + d]      * xv;
      hi += sW2t[k*128 + 64 + d] * xv;
    }
    out[(size_t)(row0 + r)*64 + d] = lo * sigmoidf_(hi);
  }
}

// ---------------- K2: A = softmax(relu(A1),1) + softmax(relu(A2),1) ----------------
__global__ __launch_bounds__(256) void k_aprep(
    const float* __restrict__ A1, const float* __restrict__ A2, float* __restrict__ Aout)
{
  __shared__ float red[4];
  int m = blockIdx.x, tid = threadIdx.x;
  float mx0, is0, mx1, is1;
  {
    const float* src = A1 + (size_t)m*N_;
    float mx = 0.f;
    for (int i = tid; i < N_; i += 256) mx = fmaxf(mx, fmaxf(src[i], 0.f));
    mx = blkRedMax(mx, red);
    float s = 0.f;
    for (int i = tid; i < N_; i += 256) s += __expf(fmaxf(src[i], 0.f) - mx);
    s = blkRedSum(s, red);
    mx0 = mx; is0 = 1.f / s;
  }
  {
    const float* src = A2 + (size_t)m*N_;
    float mx = 0.f;
    for (int i = tid; i < N_; i += 256) mx = fmaxf(mx, fmaxf(src[i], 0.f));
    mx = blkRedMax(mx, red);
    float s = 0.f;
    for (int i = tid; i < N_; i += 256) s += __expf(fmaxf(src[i], 0.f) - mx);
    s = blkRedSum(s, red);
    mx1 = mx; is1 = 1.f / s;
  }
  const float* s1 = A1 + (size_t)m*N_;
  const float* s2 = A2 + (size_t)m*N_;
  for (int i = tid; i < N_; i += 256) {
    float v1 = __expf(fmaxf(s1[i], 0.f) - mx0) * is0;
    float v2 = __expf(fmaxf(s2[i], 0.f) - mx1) * is1;
    Aout[(size_t)m*N_ + i] = v1 + v2;
  }
}

// ---------------- K3/K8: C[b] (MxP) = A (MxK) @ X[b] (KxP) ----------------
__global__ __launch_bounds__(256) void k_gemm(
    const float* __restrict__ A, const float* __restrict__ X, float* __restrict__ C,
    int M, int K, int P)
{
  __shared__ float sA[16][64];
  __shared__ float sX[16][64];
  int tid = threadIdx.x;
  int b = blockIdx.z;
  const float* Xb = X + (size_t)b * K * P;
  float* Cb = C + (size_t)b * M * P;
  int m0 = blockIdx.y * 64, p0 = blockIdx.x * 64;
  int tm = (tid >> 4) * 4, tp = (tid & 15) * 4;
  float acc[4][4] = {};
  for (int k0 = 0; k0 < K; k0 += 16) {
    for (int i = tid; i < 1024; i += 256) {
      int m = i >> 4, k = i & 15;
      sA[k][m] = A[(size_t)(m0+m)*K + k0 + k];
      int kk = i >> 6, p = i & 63;
      sX[kk][p] = Xb[(size_t)(k0+kk)*P + p0 + p];
    }
    __syncthreads();
    #pragma unroll
    for (int k = 0; k < 16; ++k) {
      float av[4], xv[4];
      *(float4*)av = *(const float4*)&sA[k][tm];
      *(float4*)xv = *(const float4*)&sX[k][tp];
      #pragma unroll
      for (int u = 0; u < 4; ++u)
        #pragma unroll
        for (int v = 0; v < 4; ++v) acc[u][v] += av[u]*xv[v];
    }
    __syncthreads();
  }
  #pragma unroll
  for (int u = 0; u < 4; ++u)
    #pragma unroll
    for (int v = 0; v < 4; ++v)
      Cb[(size_t)(m0+tm+u)*P + p0+tp+v] = acc[u][v];
}

// ---------------- K4: out = relu(in @ gc_weight) rowwise ----------------
__global__ __launch_bounds__(256) void k_rowmat_relu(
    const float* __restrict__ in, const float* __restrict__ W, float* __restrict__ out)
{
  __shared__ float sW[4096];
  __shared__ float sx[16][64];
  int tid = threadIdx.x;
  for (int i = tid; i < 4096; i += 256) sW[i] = W[i];
  int row0 = blockIdx.x * 16;
  for (int i = tid; i < 1024; i += 256) sx[i >> 6][i & 63] = in[(size_t)row0*64 + i];
  __syncthreads();
  for (int i = tid; i < 1024; i += 256) {
    int r = i >> 6, e = i & 63;
    float acc = 0.f;
    #pragma unroll 8
    for (int d = 0; d < 64; ++d) acc += sx[r][d] * sW[d*64 + e];
    out[(size_t)(row0 + r)*64 + e] = fmaxf(acc, 0.f);
  }
}

// ---------------- K5: ds temporal-conv block ----------------
__global__ __launch_bounds__(256) void k_ds(
    const float* __restrict__ xg,
    const float* __restrict__ wi,  const float* __restrict__ bi,
    const float* __restrict__ w1m, const float* __restrict__ b1m,
    const float* __restrict__ w1g, const float* __restrict__ b1g,
    const float* __restrict__ w2m, const float* __restrict__ b2m,
    const float* __restrict__ w2g, const float* __restrict__ b2g,
    const float* __restrict__ wfc, const float* __restrict__ bfc,
    float* __restrict__ out)
{
  __shared__ float smem[13312];
  float* xinit = smem;                    // [4][14][128]
  float* xin   = smem + 7168;             // [4][14][64]
  float* pout  = smem + 7168;             // [4][12][128]
  int tid = threadIdx.x;
  int bn0 = blockIdx.x * 4;

  for (int i = tid; i < 4*14*64; i += 256) {
    int g = i / 896, r = i - g*896, tp = r >> 6, d = r & 63;
    float v = 0.f;
    if (tp >= 1 && tp <= 12) v = xg[((size_t)(bn0+g)*12 + (tp-1))*64 + d];
    xin[i] = v;
  }
  for (int i = tid; i < 512; i += 256) {
    int g = i >> 7, j = i & 127;
    xinit[g*1792 + j] = 0.f;
    xinit[g*1792 + 13*128 + j] = 0.f;
  }
  __syncthreads();

  {
    int o = tid & 127, th = tid >> 7, t0 = th*6;
    float acc[4][6];
    float bias = bi[o];
    #pragma unroll
    for (int g = 0; g < 4; ++g)
      #pragma unroll
      for (int t = 0; t < 6; ++t) acc[g][t] = bias;
    for (int i0 = 0; i0 < 64; i0 += 4) {
      float w[12];
      #pragma unroll
      for (int k = 0; k < 3; ++k)
        #pragma unroll
        for (int ii = 0; ii < 4; ++ii)
          w[k*4+ii] = wi[o*192 + (i0+ii)*3 + k];
      #pragma unroll
      for (int g = 0; g < 4; ++g) {
        float4 xq[8];
        #pragma unroll
        for (int u = 0; u < 8; ++u)
          xq[u] = *(const float4*)&xin[g*896 + (t0+u)*64 + i0];
        #pragma unroll
        for (int k = 0; k < 3; ++k)
          #pragma unroll
          for (int ii = 0; ii < 4; ++ii) {
            float wv = w[k*4+ii];
            #pragma unroll
            for (int t = 0; t < 6; ++t)
              acc[g][t] += wv * F4E(xq[t+k], ii);
          }
      }
    }
    #pragma unroll
    for (int g = 0; g < 4; ++g)
      #pragma unroll
      for (int t = 0; t < 6; ++t)
        xinit[g*1792 + (t0 + t + 1)*128 + o] = acc[g][t];
  }
  __syncthreads();

  {
    int o = tid & 63, th = tid >> 6, t0 = th*3;
    #pragma unroll
    for (int half = 0; half < 2; ++half) {
      const float* wm  = half ? w2m : w1m;
      const float* wgt = half ? w2g : w1g;
      float bm = (half ? b2m : b1m)[o];
      float bg = (half ? b2g : b1g)[o];
      float accm[4][3], accg[4][3];
      #pragma unroll
      for (int g = 0; g < 4; ++g)
        #pragma unroll
        for (int t = 0; t < 3; ++t) { accm[g][t] = bm; accg[g][t] = bg; }
      for (int i0 = 0; i0 < 64; i0 += 4) {
        float wma[12], wga[12];
        #pragma unroll
        for (int k = 0; k < 3; ++k)
          #pragma unroll
          for (int ii = 0; ii < 4; ++ii) {
            wma[k*4+ii] = wm [o*192 + (i0+ii)*3 + k];
            wga[k*4+ii] = wgt[o*192 + (i0+ii)*3 + k];
          }
        #pragma unroll
        for (int g = 0; g < 4; ++g) {
          float4 xq[5];
          #pragma unroll
          for (int u = 0; u < 5; ++u)
            xq[u] = *(const float4*)&xinit[g*1792 + (t0+u)*128 + half*64 + i0];
          #pragma unroll
          for (int k = 0; k < 3; ++k)
            #pragma unroll
            for (int ii = 0; ii < 4; ++ii) {
              float wvm = wma[k*4+ii], wvg = wga[k*4+ii];
              #pragma unroll
              for (int t = 0; t < 3; ++t) {
                float xv = F4E(xq[t+k], ii);
                accm[g][t] += wvm * xv;
                accg[g][t] += wvg * xv;
              }
            }
        }
      }
      #pragma unroll
      for (int g = 0; g < 4; ++g)
        #pragma unroll
        for (int t = 0; t < 3; ++t)
          pout[g*1536 + (t0+t)*128 + half*64 + o] = accm[g][t] * sigmoidf_(accg[g][t]);
    }
  }
  __syncthreads();

  for (int i = tid; i < 6144; i += 256) {
    int g = i / 1536, r = i - g*1536, t = r >> 7, j = r & 127;
    pout[i] = fmaxf(pout[i] + xinit[g*1792 + (t+1)*128 + j], 0.f);
  }
  __syncthreads();

  {
    int o = tid & 63, th = tid >> 6, t0 = th*3;
    float acc[4][3];
    float bias = bfc[o];
    #pragma unroll
    for (int g = 0; g < 4; ++g)
      #pragma unroll
      for (int t = 0; t < 3; ++t) acc[g][t] = bias;
    for (int j0 = 0; j0 < 128; j0 += 4) {
      float4 w4 = *(const float4*)&wfc[o*128 + j0];
      #pragma unroll
      for (int g = 0; g < 4; ++g)
        #pragma unroll
        for (int t = 0; t < 3; ++t) {
          float4 f4 = *(const float4*)&pout[g*1536 + (t0+t)*128 + j0];
          acc[g][t] += w4.x*f4.x + w4.y*f4.y + w4.z*f4.z + w4.w*f4.w;
        }
    }
    #pragma unroll
    for (int g = 0; g < 4; ++g)
      #pragma unroll
      for (int t = 0; t < 3; ++t)
        out[((size_t)(bn0+g)*12 + (t0+t))*64 + o] = acc[g][t];
  }
}

// ---------------- K-wprep: transpose weights for k_attn2 ----------------
// wT layout (floats): wqkvT[64][192] @0 | woT[64][64] @12288 | f1wT[64][256] @16384 | f2wT[256][64] @32768
__global__ void k_wprep(const float* __restrict__ wq, const float* __restrict__ wk,
                        const float* __restrict__ wv, const float* __restrict__ wo,
                        const float* __restrict__ f1w, const float* __restrict__ f2w,
                        float* __restrict__ wT)
{
  int tid = blockIdx.x*256 + threadIdx.x;   // 16384 threads
  if (tid < 4096) {
    int d = tid >> 6, j = tid & 63;
    wT[j*192 + d]        = wq[tid];
    wT[j*192 + 64 + d]   = wk[tid];
    wT[j*192 + 128 + d]  = wv[tid];
    wT[12288 + j*64 + d] = wo[tid];
  }
  { // f1w: [256][64] -> f1wT[j][f]
    int f = tid >> 6, j = tid & 63;
    wT[16384 + j*256 + f] = f1w[tid];
  }
  { // f2w: [64][256] -> f2wT[f][d]
    int d = tid >> 8, f = tid & 255;
    wT[32768 + f*64 + d] = f2w[tid];
  }
}

// ---------------- K6: attention + FFN + 2x LN, ONE WAVE per (b,n) ----------------
// 4 waves per block, no __syncthreads. Lane d owns feature dim d; the 12 time
// rows live in registers. Cross-dim broadcasts go through per-wave LDS in a
// t-packed float4 layout: uniform-address ds_read_b128 = conflict-free broadcast.
__global__ __launch_bounds__(256) void k_attn2(
    const float* __restrict__ xg,
    const float* __restrict__ wT,
    const float* __restrict__ bq, const float* __restrict__ bk, const float* __restrict__ bv,
    const float* __restrict__ bo,
    const float* __restrict__ f1b, const float* __restrict__ f2b,
    const float* __restrict__ g1, const float* __restrict__ be1,
    const float* __restrict__ g2, const float* __restrict__ be2,
    float* __restrict__ outg)
{
  __shared__ float4 yq_all[4][3][64];    // 12 KB: y / o / y1 broadcasts (t-packed)
  __shared__ float  big_all[4][3072];    // 48 KB: qq|kq|ss  then  hq (f4[3][256])
  int lane = threadIdx.x & 63, wid = threadIdx.x >> 6;
  float4 (*yq)[64] = yq_all[wid];
  float* big = big_all[wid];
  float4* qq = (float4*)big;             // [3][64]
  float4* kq = qq + 192;                 // [3][64]
  float*  ss = big + 1536;               // [576]
  float4* hq = (float4*)big;             // [3][256] (after attnv)

  int bn = blockIdx.x*4 + wid;
  size_t base = (size_t)bn * 768;
  const float* wqkvT = wT;
  const float* woT   = wT + 12288;
  const float* f1wT  = wT + 16384;
  const float* f2wT  = wT + 32768;

  // P0: load y rows (coalesced), publish t-packed broadcast copy
  float y[12];
  #pragma unroll
  for (int t = 0; t < 12; ++t) y[t] = xg[base + t*64 + lane];
  #pragma unroll
  for (int tg = 0; tg < 3; ++tg)
    yq[tg][lane] = make_float4(y[4*tg], y[4*tg+1], y[4*tg+2], y[4*tg+3]);

  // P1: qkv (lane d computes q/k/v[t][d], 36 independent accumulators)
  float qa[12], ka[12], va[12];
  {
    float bqv = bq[lane], bkv = bk[lane], bvv = bv[lane];
    #pragma unroll
    for (int t = 0; t < 12; ++t) { qa[t] = bqv; ka[t] = bkv; va[t] = bvv; }
  }
  for (int j = 0; j < 64; ++j) {
    float wq_ = wqkvT[j*192 + lane];
    float wk_ = wqkvT[j*192 + 64 + lane];
    float wv_ = wqkvT[j*192 + 128 + lane];
    #pragma unroll
    for (int tg = 0; tg < 3; ++tg) {
      float4 yy = yq[tg][j];
      #pragma unroll
      for (int e = 0; e < 4; ++e) {
        float yv = F4E(yy, e); int t = tg*4 + e;
        qa[t] += wq_*yv; ka[t] += wk_*yv; va[t] += wv_*yv;
      }
    }
  }

  // P2: publish q,k (t-packed)
  #pragma unroll
  for (int tg = 0; tg < 3; ++tg) {
    qq[tg*64 + lane] = make_float4(qa[4*tg], qa[4*tg+1], qa[4*tg+2], qa[4*tg+3]);
    kq[tg*64 + lane] = make_float4(ka[4*tg], ka[4*tg+1], ka[4*tg+2], ka[4*tg+3]);
  }

  // P3: scores (576 = 9 per lane), ss[idx] linear => conflict-free writes
  #pragma unroll
  for (int it = 0; it < 9; ++it) {
    int idx = it*64 + lane;
    int h = idx/144, rem = idx - h*144, l = rem/12, s = rem - l*12;
    const float* qp = (const float*)(qq + ((l>>2)*64 + h*16));
    const float* kp = (const float*)(kq + ((s>>2)*64 + h*16));
    int le = l & 3, se = s & 3;
    float acc = 0.f;
    #pragma unroll
    for (int j = 0; j < 16; ++j) acc += qp[j*4 + le] * kp[j*4 + se];
    ss[idx] = acc * 0.25f;
  }

  // P4: softmax over s (48 rows, lanes 0..47)
  if (lane < 48) {
    float* row = ss + lane*12;
    float4 r0 = *(float4*)row, r1 = *(float4*)(row+4), r2 = *(float4*)(row+8);
    float mx = fmaxf(fmaxf(fmaxf(r0.x,r0.y),fmaxf(r0.z,r0.w)),
               fmaxf(fmaxf(fmaxf(r1.x,r1.y),fmaxf(r1.z,r1.w)),
                     fmaxf(fmaxf(r2.x,r2.y),fmaxf(r2.z,r2.w))));
    r0.x=__expf(r0.x-mx); r0.y=__expf(r0.y-mx); r0.z=__expf(r0.z-mx); r0.w=__expf(r0.w-mx);
    r1.x=__expf(r1.x-mx); r1.y=__expf(r1.y-mx); r1.z=__expf(r1.z-mx); r1.w=__expf(r1.w-mx);
    r2.x=__expf(r2.x-mx); r2.y=__expf(r2.y-mx); r2.z=__expf(r2.z-mx); r2.w=__expf(r2.w-mx);
    float sum = r0.x+r0.y+r0.z+r0.w + r1.x+r1.y+r1.z+r1.w + r2.x+r2.y+r2.z+r2.w;
    float inv = 1.f/sum;
    r0.x*=inv; r0.y*=inv; r0.z*=inv; r0.w*=inv;
    r1.x*=inv; r1.y*=inv; r1.z*=inv; r1.w*=inv;
    r2.x*=inv; r2.y*=inv; r2.z*=inv; r2.w*=inv;
    *(float4*)row = r0; *(float4*)(row+4) = r1; *(float4*)(row+8) = r2;
  }

  // P5: o = attn @ v  (v in regs), publish o t-packed into yq region
  float ov[12];
  {
    int h = lane >> 4;
    #pragma unroll
    for (int l = 0; l < 12; ++l) {
      const float* sr = ss + h*144 + l*12;
      float4 a0 = *(const float4*)sr, a1 = *(const float4*)(sr+4), a2 = *(const float4*)(sr+8);
      ov[l] = a0.x*va[0]+a0.y*va[1]+a0.z*va[2]+a0.w*va[3]
            + a1.x*va[4]+a1.y*va[5]+a1.z*va[6]+a1.w*va[7]
            + a2.x*va[8]+a2.y*va[9]+a2.z*va[10]+a2.w*va[11];
    }
  }
  #pragma unroll
  for (int tg = 0; tg < 3; ++tg)
    yq[tg][lane] = make_float4(ov[4*tg], ov[4*tg+1], ov[4*tg+2], ov[4*tg+3]);

  // P6: z = y + o @ woT + bo
  float z[12];
  {
    float bov = bo[lane];
    #pragma unroll
    for (int t = 0; t < 12; ++t) z[t] = bov;
    for (int j = 0; j < 64; ++j) {
      float w = woT[j*64 + lane];
      #pragma unroll
      for (int tg = 0; tg < 3; ++tg) {
        float4 oo = yq[tg][j];
        #pragma unroll
        for (int e = 0; e < 4; ++e) z[tg*4+e] += w * F4E(oo, e);
      }
    }
    #pragma unroll
    for (int t = 0; t < 12; ++t) z[t] += y[t];
  }

  // P7: LN1 (cross-lane reduce), publish y1 t-packed
  float y1[12];
  {
    float g1v = g1[lane], b1v = be1[lane];
    #pragma unroll
    for (int t = 0; t < 12; ++t) {
      float m = waveRedSum(z[t]) * (1.f/64.f);
      float dd = z[t] - m;
      float vv = waveRedSum(dd*dd) * (1.f/64.f);
      y1[t] = dd * rsqrtf(vv + 1e-5f) * g1v + b1v;
    }
  }
  #pragma unroll
  for (int tg = 0; tg < 3; ++tg)
    yq[tg][lane] = make_float4(y1[4*tg], y1[4*tg+1], y1[4*tg+2], y1[4*tg+3]);

  // P8: ff1 (lane d computes f = d, d+64, d+128, d+192), publish h t-packed
  {
    float h8[48];
    float fb0 = f1b[lane], fb1 = f1b[lane+64], fb2 = f1b[lane+128], fb3 = f1b[lane+192];
    #pragma unroll
    for (int t = 0; t < 12; ++t) { h8[t] = fb0; h8[12+t] = fb1; h8[24+t] = fb2; h8[36+t] = fb3; }
    for (int j = 0; j < 64; ++j) {
      float w0 = f1wT[j*256 + lane];
      float w1 = f1wT[j*256 + 64 + lane];
      float w2 = f1wT[j*256 + 128 + lane];
      float w3 = f1wT[j*256 + 192 + lane];
      #pragma unroll
      for (int tg = 0; tg < 3; ++tg) {
        float4 yy = yq[tg][j];
        #pragma unroll
        for (int e = 0; e < 4; ++e) {
          float yv = F4E(yy, e); int t = tg*4 + e;
          h8[t] += w0*yv; h8[12+t] += w1*yv; h8[24+t] += w2*yv; h8[36+t] += w3*yv;
        }
      }
    }
    #pragma unroll
    for (int u = 0; u < 4; ++u)
      #pragma unroll
      for (int t = 0; t < 48; ++t) { }
    #pragma unroll
    for (int i = 0; i < 48; ++i) h8[i] = fmaxf(h8[i], 0.f);
    #pragma unroll
    for (int tg = 0; tg < 3; ++tg)
      #pragma unroll
      for (int u = 0; u < 4; ++u)
        hq[tg*256 + lane + 64*u] =
          make_float4(h8[u*12 + 4*tg], h8[u*12 + 4*tg + 1], h8[u*12 + 4*tg + 2], h8[u*12 + 4*tg + 3]);
  }

  // P9: z2 = y1 + h @ f2wT + f2b
  float z2[12];
  {
    float b2v = f2b[lane];
    #pragma unroll
    for (int t = 0; t < 12; ++t) z2[t] = b2v;
    for (int j = 0; j < 256; ++j) {
      float w = f2wT[j*64 + lane];
      float4 h0 = hq[j], h1 = hq[256 + j], h2 = hq[512 + j];
      z2[0] += w*h0.x; z2[1] += w*h0.y; z2[2]  += w*h0.z; z2[3]  += w*h0.w;
      z2[4] += w*h1.x; z2[5] += w*h1.y; z2[6]  += w*h1.z; z2[7]  += w*h1.w;
      z2[8] += w*h2.x; z2[9] += w*h2.y; z2[10] += w*h2.z; z2[11] += w*h2.w;
    }
    #pragma unroll
    for (int t = 0; t < 12; ++t) z2[t] += y1[t];
  }

  // P10: LN2 + store
  {
    float g2v = g2[lane], b2v = be2[lane];
    #pragma unroll
    for (int t = 0; t < 12; ++t) {
      float m = waveRedSum(z2[t]) * (1.f/64.f);
      float dd = z2[t] - m;
      float vv = waveRedSum(dd*dd) * (1.f/64.f);
      outg[base + t*64 + lane] = dd * rsqrtf(vv + 1e-5f) * g2v + b2v;
    }
  }
}

// ---------------- K7: fuse-matrix prep ----------------
__global__ void k_mvec(const float* __restrict__ flow, const float* __restrict__ clw,
                       const float* __restrict__ clb, float* __restrict__ mv)
{
  int n = blockIdx.x*blockDim.x + threadIdx.x;
  if (n < N_) {
    float s = 0.f;
    float bias = clb[0];
    for (int b = 0; b < B_; ++b) {
      const float* f = flow + ((size_t)b*N_ + n)*T_;
      float acc = bias;
      #pragma unroll
      for (int t = 0; t < T_; ++t) acc += f[t]*clw[t];
      s += fmaxf(acc, 0.f);
    }
    mv[n] = s * (1.f/16.f);
  }
}

__global__ void k_fusemat(const float* __restrict__ mv, float* __restrict__ F)
{
  int idx = blockIdx.x*256 + threadIdx.x;
  int m = idx >> 10, n = idx & 1023;
  float x = 0.5f*(mv[m] + mv[n]);
  F[idx] = 1.f/(1.f + __expf(-x));
}

// ---------------- launch ----------------
extern "C" void kernel_launch(void* const* d_in, const int* in_sizes, int n_in,
                              void* d_out, int out_size, void* d_ws, size_t ws_size,
                              hipStream_t stream)
{
  const float* flow = (const float*)d_in[0];
  const int*   day  = (const int*)d_in[1];
  const int*   week = (const int*)d_in[2];
  const float* semb = (const float*)d_in[3];
  const float* demb = (const float*)d_in[4];
  const float* wemb = (const float*)d_in[5];
  const float* gfsw = (const float*)d_in[6];
  const float* gfsb = (const float*)d_in[7];
  const float* gluw = (const float*)d_in[8];
  const float* glub = (const float*)d_in[9];
  const float* gcw  = (const float*)d_in[10];
  const float* gcA  = (const float*)d_in[11];
  const float* gcA2 = (const float*)d_in[12];
  const float* wi   = (const float*)d_in[13];
  const float* bi   = (const float*)d_in[14];
  const float* w1m  = (const float*)d_in[15];
  const float* b1m  = (const float*)d_in[16];
  const float* w1g  = (const float*)d_in[17];
  const float* b1g  = (const float*)d_in[18];
  const float* w2m  = (const float*)d_in[19];
  const float* b2m  = (const float*)d_in[20];
  const float* w2g  = (const float*)d_in[21];
  const float* b2g  = (const float*)d_in[22];
  const float* wfc  = (const float*)d_in[23];
  const float* bfc  = (const float*)d_in[24];
  const float* wq   = (const float*)d_in[25];
  const float* bq   = (const float*)d_in[26];
  const float* wk   = (const float*)d_in[27];
  const float* bk   = (const float*)d_in[28];
  const float* wv   = (const float*)d_in[29];
  const float* bv   = (const float*)d_in[30];
  const float* wo   = (const float*)d_in[31];
  const float* bo   = (const float*)d_in[32];
  const float* f1w  = (const float*)d_in[33];
  const float* f1b  = (const float*)d_in[34];
  const float* f2w  = (const float*)d_in[35];
  const float* f2b  = (const float*)d_in[36];
  const float* g1   = (const float*)d_in[37];
  const float* be1  = (const float*)d_in[38];
  const float* g2   = (const float*)d_in[39];
  const float* be2  = (const float*)d_in[40];
  const float* clw  = (const float*)d_in[41];
  const float* clb  = (const float*)d_in[42];

  float* out = (float*)d_out;
  char* ws = (char*)d_ws;
  float* Amat = (float*)ws;                                     // 4 MB
  float* mv   = (float*)(ws + (size_t)4*1024*1024);             // 4 KB (region 64 KB)
  float* wTp  = (float*)(ws + (size_t)4*1024*1024 + 65536);     // 192 KB (region 256 KB)
  float* buf0 = (float*)(ws + (size_t)4*1024*1024 + 65536 + 262144);  // 48 MB

  // weight transposes for k_attn2
  k_wprep<<<64, 256, 0, stream>>>(wq, wk, wv, wo, f1w, f2w, wTp);
  // x0 = GLU(gfs_fc(embed)) -> buf0
  k_embed<<<BNT/16, 256, 0, stream>>>(flow, day, week, semb, demb, wemb,
                                      gfsw, gfsb, gluw, glub, buf0);
  // combined adjacency
  k_aprep<<<N_, 256, 0, stream>>>(gcA, gcA2, Amat);
  // hs = A @ x0 -> d_out
  dim3 gg(TD/64, N_/64, B_);
  k_gemm<<<gg, 256, 0, stream>>>(Amat, buf0, out, N_, N_, TD);
  // x2 = relu(hs @ gc_weight) -> buf0
  k_rowmat_relu<<<BNT/16, 256, 0, stream>>>(out, gcw, buf0);
  // x3 = ds block -> d_out
  k_ds<<<BN_/4, 256, 0, stream>>>(buf0, wi, bi, w1m, b1m, w1g, b1g,
                                  w2m, b2m, w2g, b2g, wfc, bfc, out);
  // y2 = attn+ffn block -> buf0
  k_attn2<<<BN_/4, 256, 0, stream>>>(out, wTp, bq, bk, bv, bo, f1b, f2b,
                                     g1, be1, g2, be2, buf0);
  // fuse matrix
  k_mvec<<<N_/256, 256, 0, stream>>>(flow, clw, clb, mv);
  k_fusemat<<<(N_*N_)/256, 256, 0, stream>>>(mv, Amat);
  // out = fuse @ y2 -> d_out
  k_gemm<<<gg, 256, 0, stream>>>(Amat, buf0, out, N_, N_, TD);
}

// Round 3
// 1492.329 us; speedup vs baseline: 4.3384x; 1.8003x over previous
//
#include <hip/hip_runtime.h>
#include <cstdint>

#define B_ 16
#define N_ 1024
#define T_ 12
#define HD 64
#define BN_ (B_*N_)     // 16384
#define BNT (B_*N_*T_)  // 196608
#define TD (T_*HD)      // 768

typedef __attribute__((ext_vector_type(8))) short short8;
typedef __attribute__((ext_vector_type(4))) float f32x4;

__device__ __forceinline__ float sigmoidf_(float x) { return 1.f / (1.f + __expf(-x)); }

__device__ __forceinline__ unsigned short f2bf(float f) {
  unsigned int u = __float_as_uint(f);
  u += 0x7fffu + ((u >> 16) & 1u);   // round-to-nearest-even
  return (unsigned short)(u >> 16);
}

#define F4E(v, ii) ((ii)==0?(v).x:((ii)==1?(v).y:((ii)==2?(v).z:(v).w)))

// ---------------- reductions ----------------
__device__ __forceinline__ float blkRedMax(float v, float* red) {
  #pragma unroll
  for (int off = 32; off >= 1; off >>= 1) v = fmaxf(v, __shfl_xor(v, off));
  int w = threadIdx.x >> 6;
  if ((threadIdx.x & 63) == 0) red[w] = v;
  __syncthreads();
  v = fmaxf(fmaxf(red[0], red[1]), fmaxf(red[2], red[3]));
  __syncthreads();
  return v;
}
__device__ __forceinline__ float blkRedSum(float v, float* red) {
  #pragma unroll
  for (int off = 32; off >= 1; off >>= 1) v += __shfl_xor(v, off);
  int w = threadIdx.x >> 6;
  if ((threadIdx.x & 63) == 0) red[w] = v;
  __syncthreads();
  v = red[0] + red[1] + red[2] + red[3];
  __syncthreads();
  return v;
}
__device__ __forceinline__ float waveRedSum(float v) {
  #pragma unroll
  for (int off = 32; off >= 1; off >>= 1) v += __shfl_xor(v, off);
  return v;
}

// ---------------- K1: embed concat + gfs_fc + GLU ----------------
__global__ __launch_bounds__(256) void k_embed(
    const float* __restrict__ flow, const int* __restrict__ day, const int* __restrict__ week,
    const float* __restrict__ semb, const float* __restrict__ demb, const float* __restrict__ wemb,
    const float* __restrict__ w1, const float* __restrict__ b1,
    const float* __restrict__ w2, const float* __restrict__ b2,
    float* __restrict__ out)
{
  __shared__ float sW1t[64*64];    // [k][d]
  __shared__ float sW2t[64*128];   // [k][j]
  __shared__ float svv[16][64];
  __shared__ float sx[16][64];
  int tid = threadIdx.x;
  for (int i = tid; i < 4096; i += 256) sW1t[(i & 63)*64  + (i >> 6)] = w1[i];
  for (int i = tid; i < 8192; i += 256) sW2t[(i & 63)*128 + (i >> 6)] = w2[i];
  int row0 = blockIdx.x * 16;
  for (int i = tid; i < 1024; i += 256) {
    int r = i >> 6, c = i & 63;
    int row = row0 + r;
    int n = (row / T_) % N_;
    float val;
    if (c == 0)      val = flow[row];
    else if (c < 33) val = semb[n*32 + (c-1)];
    else if (c < 49) val = demb[day[row]*16 + (c-33)];
    else             val = wemb[week[row]*15 + (c-49)];
    svv[r][c] = val;
  }
  __syncthreads();
  for (int i = tid; i < 1024; i += 256) {
    int r = i >> 6, d = i & 63;
    float acc = b1[d];
    #pragma unroll 8
    for (int k = 0; k < 64; ++k) acc += sW1t[k*64 + d] * svv[r][k];
    sx[r][d] = acc;
  }
  __syncthreads();
  for (int i = tid; i < 1024; i += 256) {
    int r = i >> 6, d = i & 63;
    float lo = b2[d], hi = b2[64 + d];
    #pragma unroll 8
    for (int k = 0; k < 64; ++k) {
      float xv = sx[r][k];
      lo += sW2t[k*128 + d]      * xv;
      hi += sW2t[k*128 + 64 + d] * xv;
    }
    out[(size_t)(row0 + r)*64 + d] = lo * sigmoidf_(hi);
  }
}

// ---------------- K2: A = softmax(relu(A1),1) + softmax(relu(A2),1) ----------------
__global__ __launch_bounds__(256) void k_aprep(
    const float* __restrict__ A1, const float* __restrict__ A2, float* __restrict__ Aout)
{
  __shared__ float red[4];
  int m = blockIdx.x, tid = threadIdx.x;
  float mx0, is0, mx1, is1;
  {
    const float* src = A1 + (size_t)m*N_;
    float mx = 0.f;
    for (int i = tid; i < N_; i += 256) mx = fmaxf(mx, fmaxf(src[i], 0.f));
    mx = blkRedMax(mx, red);
    float s = 0.f;
    for (int i = tid; i < N_; i += 256) s += __expf(fmaxf(src[i], 0.f) - mx);
    s = blkRedSum(s, red);
    mx0 = mx; is0 = 1.f / s;
  }
  {
    const float* src = A2 + (size_t)m*N_;
    float mx = 0.f;
    for (int i = tid; i < N_; i += 256) mx = fmaxf(mx, fmaxf(src[i], 0.f));
    mx = blkRedMax(mx, red);
    float s = 0.f;
    for (int i = tid; i < N_; i += 256) s += __expf(fmaxf(src[i], 0.f) - mx);
    s = blkRedSum(s, red);
    mx1 = mx; is1 = 1.f / s;
  }
  const float* s1 = A1 + (size_t)m*N_;
  const float* s2 = A2 + (size_t)m*N_;
  for (int i = tid; i < N_; i += 256) {
    float v1 = __expf(fmaxf(s1[i], 0.f) - mx0) * is0;
    float v2 = __expf(fmaxf(s2[i], 0.f) - mx1) * is1;
    Aout[(size_t)m*N_ + i] = v1 + v2;
  }
}

// ---------------- K3: bf16 MFMA batched GEMM: C[b](1024 x P) = A(1024x1024) @ X[b](1024 x P) ----
// 128x128 tile, BK=32, 4 waves (2x2 of 64x64), fp32->bf16 conversion during staging.
__global__ __launch_bounds__(256) void k_gemm_mfma(
    const float* __restrict__ A, const float* __restrict__ X, float* __restrict__ C,
    int K, int P)
{
  __shared__ unsigned short sA[128*40];   // [m][k] pad-40
  __shared__ unsigned short sB[128*40];   // [p][k] (transposed) pad-40
  int tid = threadIdx.x, lane = tid & 63, wid = tid >> 6;
  int M = gridDim.y * 128;
  int b = blockIdx.z;
  const float* Xb = X + (size_t)b*K*P;
  float* Cb = C + (size_t)b*M*P;
  int m0 = blockIdx.y*128, p0 = blockIdx.x*128;
  int wr = wid >> 1, wc = wid & 1;

  f32x4 acc[4][4] = {};

  for (int k0 = 0; k0 < K; k0 += 32) {
    // stage A tile: 128 rows x 32 k (k contiguous in global -> float4 loads)
    #pragma unroll
    for (int pass = 0; pass < 4; ++pass) {
      int r = (tid >> 3) + 32*pass, kk = (tid & 7)*4;
      float4 v = *(const float4*)&A[(size_t)(m0+r)*K + k0 + kk];
      ushort4 h; h.x = f2bf(v.x); h.y = f2bf(v.y); h.z = f2bf(v.z); h.w = f2bf(v.w);
      *(ushort4*)&sA[r*40 + kk] = h;
    }
    // stage B tile transposed: sB[p][k] from X[k][p] (p contiguous -> coalesced loads)
    #pragma unroll
    for (int pass = 0; pass < 4; ++pass) {
      int p  = (tid & 63) + 64*(pass & 1);
      int k4 = (tid >> 6)*4 + 16*(pass >> 1);
      float f0 = Xb[(size_t)(k0+k4+0)*P + p0 + p];
      float f1 = Xb[(size_t)(k0+k4+1)*P + p0 + p];
      float f2 = Xb[(size_t)(k0+k4+2)*P + p0 + p];
      float f3 = Xb[(size_t)(k0+k4+3)*P + p0 + p];
      ushort4 h; h.x = f2bf(f0); h.y = f2bf(f1); h.z = f2bf(f2); h.w = f2bf(f3);
      *(ushort4*)&sB[p*40 + k4] = h;
    }
    __syncthreads();
    // fragment loads: lane l holds A[l&15][(l>>4)*8 + j], B[(l>>4)*8 + j][l&15]
    short8 af[4], bf[4];
    #pragma unroll
    for (int f = 0; f < 4; ++f) {
      af[f] = *(const short8*)&sA[(wr*64 + f*16 + (lane & 15))*40 + (lane >> 4)*8];
      bf[f] = *(const short8*)&sB[(wc*64 + f*16 + (lane & 15))*40 + (lane >> 4)*8];
    }
    #pragma unroll
    for (int fm = 0; fm < 4; ++fm)
      #pragma unroll
      for (int fn = 0; fn < 4; ++fn)
        acc[fm][fn] = __builtin_amdgcn_mfma_f32_16x16x32_bf16(af[fm], bf[fn], acc[fm][fn], 0, 0, 0);
    __syncthreads();
  }
  // C write: col = lane&15, row = (lane>>4)*4 + reg   [m89 mapping]
  #pragma unroll
  for (int fm = 0; fm < 4; ++fm) {
    int row = m0 + wr*64 + fm*16 + (lane >> 4)*4;
    #pragma unroll
    for (int fn = 0; fn < 4; ++fn) {
      int col = p0 + wc*64 + fn*16 + (lane & 15);
      #pragma unroll
      for (int r = 0; r < 4; ++r)
        Cb[(size_t)(row + r)*P + col] = acc[fm][fn][r];
    }
  }
}

// ---------------- K4: out = relu(in @ gc_weight) rowwise ----------------
__global__ __launch_bounds__(256) void k_rowmat_relu(
    const float* __restrict__ in, const float* __restrict__ W, float* __restrict__ out)
{
  __shared__ float sW[4096];
  __shared__ float sx[16][64];
  int tid = threadIdx.x;
  for (int i = tid; i < 4096; i += 256) sW[i] = W[i];
  int row0 = blockIdx.x * 16;
  for (int i = tid; i < 1024; i += 256) sx[i >> 6][i & 63] = in[(size_t)row0*64 + i];
  __syncthreads();
  for (int i = tid; i < 1024; i += 256) {
    int r = i >> 6, e = i & 63;
    float acc = 0.f;
    #pragma unroll 8
    for (int d = 0; d < 64; ++d) acc += sx[r][d] * sW[d*64 + e];
    out[(size_t)(row0 + r)*64 + e] = fmaxf(acc, 0.f);
  }
}

// ---------------- K-wprep2: transpose conv weights for k_ds2 ----------------
// wTc layout (floats): wiT[(i*3+k)*128+o] @0 | w1mT @24576 | w1gT @36864 | w2mT @49152 | w2gT @61440 | wfcT[j*64+e] @73728
__global__ void k_wprep2(const float* __restrict__ wi,
                         const float* __restrict__ w1m, const float* __restrict__ w1g,
                         const float* __restrict__ w2m, const float* __restrict__ w2g,
                         const float* __restrict__ wfc, float* __restrict__ wTc)
{
  int t = blockIdx.x*256 + threadIdx.x;   // 96*256 = 24576
  if (t < 24576) {
    int o = t / 192, r = t % 192;        // wi[o][i][k], r = i*3+k
    wTc[r*128 + o] = wi[t];
  }
  if (t < 12288) {
    int o = t / 192, r = t % 192;
    wTc[24576 + r*64 + o] = w1m[t];
    wTc[36864 + r*64 + o] = w1g[t];
    wTc[49152 + r*64 + o] = w2m[t];
    wTc[61440 + r*64 + o] = w2g[t];
  }
  if (t < 8192) {
    int e = t >> 7, j = t & 127;         // wfc[e][j]
    wTc[73728 + j*64 + e] = wfc[t];
  }
}

// ---------------- K5: ds temporal-conv block, ONE WAVE per (b,n) ----------------
// Lane owns output channel(s); cross-channel broadcasts via per-wave LDS [128][16]
// (uniform-address ds_read_b128 = conflict-free broadcast). No __syncthreads.
__global__ __launch_bounds__(256) void k_ds2(
    const float* __restrict__ xg, const float* __restrict__ wTc,
    const float* __restrict__ bi,
    const float* __restrict__ b1m, const float* __restrict__ b1g,
    const float* __restrict__ b2m, const float* __restrict__ b2g,
    const float* __restrict__ bfc,
    float* __restrict__ out)
{
  __shared__ float xb_all[4][2048];      // 4 waves x 8KB
  int lane = threadIdx.x & 63, wid = threadIdx.x >> 6;
  float* xb = xb_all[wid];
  int bn = blockIdx.x*4 + wid;
  size_t base = (size_t)bn * 768;

  // load x (lane = channel), publish broadcast rows [ch][tp], tp = t+1 with zero pads
  float x[12];
  #pragma unroll
  for (int t = 0; t < 12; ++t) x[t] = xg[base + t*64 + lane];
  {
    float4* d0 = (float4*)(xb + lane*16);
    d0[0] = make_float4(0.f,  x[0], x[1],  x[2]);
    d0[1] = make_float4(x[3], x[4], x[5],  x[6]);
    d0[2] = make_float4(x[7], x[8], x[9],  x[10]);
    d0[3] = make_float4(x[11], 0.f, 0.f,   0.f);
  }

  // ---- init conv: 128 out channels; lane owns o=lane and o=lane+64 ----
  float alo[12], ahi[12];
  #pragma unroll
  for (int t = 0; t < 12; ++t) { alo[t] = 0.f; ahi[t] = 0.f; }
  {
    const float* wiT = wTc;
    #pragma unroll 2
    for (int i = 0; i < 64; ++i) {
      float4 q0 = *(const float4*)&xb[i*16];
      float4 q1 = *(const float4*)&xb[i*16 + 4];
      float4 q2 = *(const float4*)&xb[i*16 + 8];
      float4 q3 = *(const float4*)&xb[i*16 + 12];
      float xr[16] = {q0.x,q0.y,q0.z,q0.w, q1.x,q1.y,q1.z,q1.w,
                      q2.x,q2.y,q2.z,q2.w, q3.x,q3.y,q3.z,q3.w};
      #pragma unroll
      for (int k = 0; k < 3; ++k) {
        float wlo = wiT[(i*3+k)*128 + lane];
        float whi = wiT[(i*3+k)*128 + 64 + lane];
        #pragma unroll
        for (int t = 0; t < 12; ++t) {
          float xv = xr[t+k];
          alo[t] += wlo*xv; ahi[t] += whi*xv;
        }
      }
    }
    float blo = bi[lane], bhi = bi[64+lane];
    #pragma unroll
    for (int t = 0; t < 12; ++t) { alo[t] += blo; ahi[t] += bhi; }
  }

  // publish x_init broadcast (overwrites x region; in-order DS per wave => safe)
  {
    float4* d0 = (float4*)(xb + lane*16);
    d0[0] = make_float4(0.f, alo[0], alo[1],  alo[2]);
    d0[1] = make_float4(alo[3], alo[4], alo[5], alo[6]);
    d0[2] = make_float4(alo[7], alo[8], alo[9], alo[10]);
    d0[3] = make_float4(alo[11], 0.f, 0.f, 0.f);
    float4* d1 = (float4*)(xb + (64+lane)*16);
    d1[0] = make_float4(0.f, ahi[0], ahi[1],  ahi[2]);
    d1[1] = make_float4(ahi[3], ahi[4], ahi[5], ahi[6]);
    d1[2] = make_float4(ahi[7], ahi[8], ahi[9], ahi[10]);
    d1[3] = make_float4(ahi[11], 0.f, 0.f, 0.f);
  }

  // ---- gated convs: p1 on rows 0..63, p2 on rows 64..127 ----
  float fl[12], fh[12];
  #pragma unroll
  for (int half = 0; half < 2; ++half) {
    const float* wmT = wTc + (half ? 49152 : 24576);
    const float* wgT = wTc + (half ? 61440 : 36864);
    float am[12], ag[12];
    #pragma unroll
    for (int t = 0; t < 12; ++t) { am[t] = 0.f; ag[t] = 0.f; }
    int rbase = half*64;
    #pragma unroll 2
    for (int i = 0; i < 64; ++i) {
      float4 q0 = *(const float4*)&xb[(rbase+i)*16];
      float4 q1 = *(const float4*)&xb[(rbase+i)*16 + 4];
      float4 q2 = *(const float4*)&xb[(rbase+i)*16 + 8];
      float4 q3 = *(const float4*)&xb[(rbase+i)*16 + 12];
      float xr[16] = {q0.x,q0.y,q0.z,q0.w, q1.x,q1.y,q1.z,q1.w,
                      q2.x,q2.y,q2.z,q2.w, q3.x,q3.y,q3.z,q3.w};
      #pragma unroll
      for (int k = 0; k < 3; ++k) {
        float wm = wmT[(i*3+k)*64 + lane];
        float wg = wgT[(i*3+k)*64 + lane];
        #pragma unroll
        for (int t = 0; t < 12; ++t) {
          float xv = xr[t+k];
          am[t] += wm*xv; ag[t] += wg*xv;
        }
      }
    }
    float bm = (half ? b2m : b1m)[lane];
    float bg = (half ? b2g : b1g)[lane];
    float* res = half ? ahi : alo;
    float* fo  = half ? fh  : fl;
    #pragma unroll
    for (int t = 0; t < 12; ++t) {
      float po = (am[t]+bm) * sigmoidf_(ag[t]+bg);
      fo[t] = fmaxf(po + res[t], 0.f);      // fused = relu(gated + x_init)
    }
  }

  // publish fused broadcast (t at positions 0..11)
  {
    float4* d0 = (float4*)(xb + lane*16);
    d0[0] = make_float4(fl[0], fl[1], fl[2],  fl[3]);
    d0[1] = make_float4(fl[4], fl[5], fl[6],  fl[7]);
    d0[2] = make_float4(fl[8], fl[9], fl[10], fl[11]);
    float4* d1 = (float4*)(xb + (64+lane)*16);
    d1[0] = make_float4(fh[0], fh[1], fh[2],  fh[3]);
    d1[1] = make_float4(fh[4], fh[5], fh[6],  fh[7]);
    d1[2] = make_float4(fh[8], fh[9], fh[10], fh[11]);
  }

  // ---- ds_fc: out[t][e=lane] = bfc + sum_j fused[j][t] * wfcT[j][e] ----
  {
    const float* wfcT = wTc + 73728;
    float fa[12];
    #pragma unroll
    for (int t = 0; t < 12; ++t) fa[t] = 0.f;
    #pragma unroll 4
    for (int j = 0; j < 128; ++j) {
      float4 q0 = *(const float4*)&xb[j*16];
      float4 q1 = *(const float4*)&xb[j*16 + 4];
      float4 q2 = *(const float4*)&xb[j*16 + 8];
      float w = wfcT[j*64 + lane];
      fa[0] += w*q0.x; fa[1] += w*q0.y; fa[2]  += w*q0.z; fa[3]  += w*q0.w;
      fa[4] += w*q1.x; fa[5] += w*q1.y; fa[6]  += w*q1.z; fa[7]  += w*q1.w;
      fa[8] += w*q2.x; fa[9] += w*q2.y; fa[10] += w*q2.z; fa[11] += w*q2.w;
    }
    float bv = bfc[lane];
    #pragma unroll
    for (int t = 0; t < 12; ++t)
      out[base + t*64 + lane] = fa[t] + bv;
  }
}

// ---------------- K-wprep: transpose weights for k_attn2 ----------------
__global__ void k_wprep(const float* __restrict__ wq, const float* __restrict__ wk,
                        const float* __restrict__ wv, const float* __restrict__ wo,
                        const float* __restrict__ f1w, const float* __restrict__ f2w,
                        float* __restrict__ wT)
{
  int tid = blockIdx.x*256 + threadIdx.x;   // 16384 threads
  if (tid < 4096) {
    int d = tid >> 6, j = tid & 63;
    wT[j*192 + d]        = wq[tid];
    wT[j*192 + 64 + d]   = wk[tid];
    wT[j*192 + 128 + d]  = wv[tid];
    wT[12288 + j*64 + d] = wo[tid];
  }
  { // f1w: [256][64] -> f1wT[j][f]
    int f = tid >> 6, j = tid & 63;
    wT[16384 + j*256 + f] = f1w[tid];
  }
  { // f2w: [64][256] -> f2wT[f][d]
    int d = tid >> 8, f = tid & 255;
    wT[32768 + f*64 + d] = f2w[tid];
  }
}

// ---------------- K6: attention + FFN + 2x LN, ONE WAVE per (b,n) ----------------
__global__ __launch_bounds__(256) void k_attn2(
    const float* __restrict__ xg,
    const float* __restrict__ wT,
    const float* __restrict__ bq, const float* __restrict__ bk, const float* __restrict__ bv,
    const float* __restrict__ bo,
    const float* __restrict__ f1b, const float* __restrict__ f2b,
    const float* __restrict__ g1, const float* __restrict__ be1,
    const float* __restrict__ g2, const float* __restrict__ be2,
    float* __restrict__ outg)
{
  __shared__ float4 yq_all[4][3][64];    // 12 KB
  __shared__ float  big_all[4][3072];    // 48 KB
  int lane = threadIdx.x & 63, wid = threadIdx.x >> 6;
  float4 (*yq)[64] = yq_all[wid];
  float* big = big_all[wid];
  float4* qq = (float4*)big;             // [3][64]
  float4* kq = qq + 192;                 // [3][64]
  float*  ss = big + 1536;               // [576]
  float4* hq = (float4*)big;             // [3][256] (after attnv)

  int bn = blockIdx.x*4 + wid;
  size_t base = (size_t)bn * 768;
  const float* wqkvT = wT;
  const float* woT   = wT + 12288;
  const float* f1wT  = wT + 16384;
  const float* f2wT  = wT + 32768;

  float y[12];
  #pragma unroll
  for (int t = 0; t < 12; ++t) y[t] = xg[base + t*64 + lane];
  #pragma unroll
  for (int tg = 0; tg < 3; ++tg)
    yq[tg][lane] = make_float4(y[4*tg], y[4*tg+1], y[4*tg+2], y[4*tg+3]);

  float qa[12], ka[12], va[12];
  {
    float bqv = bq[lane], bkv = bk[lane], bvv = bv[lane];
    #pragma unroll
    for (int t = 0; t < 12; ++t) { qa[t] = bqv; ka[t] = bkv; va[t] = bvv; }
  }
  for (int j = 0; j < 64; ++j) {
    float wq_ = wqkvT[j*192 + lane];
    float wk_ = wqkvT[j*192 + 64 + lane];
    float wv_ = wqkvT[j*192 + 128 + lane];
    #pragma unroll
    for (int tg = 0; tg < 3; ++tg) {
      float4 yy = yq[tg][j];
      #pragma unroll
      for (int e = 0; e < 4; ++e) {
        float yv = F4E(yy, e); int t = tg*4 + e;
        qa[t] += wq_*yv; ka[t] += wk_*yv; va[t] += wv_*yv;
      }
    }
  }

  #pragma unroll
  for (int tg = 0; tg < 3; ++tg) {
    qq[tg*64 + lane] = make_float4(qa[4*tg], qa[4*tg+1], qa[4*tg+2], qa[4*tg+3]);
    kq[tg*64 + lane] = make_float4(ka[4*tg], ka[4*tg+1], ka[4*tg+2], ka[4*tg+3]);
  }

  #pragma unroll
  for (int it = 0; it < 9; ++it) {
    int idx = it*64 + lane;
    int h = idx/144, rem = idx - h*144, l = rem/12, s = rem - l*12;
    const float* qp = (const float*)(qq + ((l>>2)*64 + h*16));
    const float* kp = (const float*)(kq + ((s>>2)*64 + h*16));
    int le = l & 3, se = s & 3;
    float acc = 0.f;
    #pragma unroll
    for (int j = 0; j < 16; ++j) acc += qp[j*4 + le] * kp[j*4 + se];
    ss[idx] = acc * 0.25f;
  }

  if (lane < 48) {
    float* row = ss + lane*12;
    float4 r0 = *(float4*)row, r1 = *(float4*)(row+4), r2 = *(float4*)(row+8);
    float mx = fmaxf(fmaxf(fmaxf(r0.x,r0.y),fmaxf(r0.z,r0.w)),
               fmaxf(fmaxf(fmaxf(r1.x,r1.y),fmaxf(r1.z,r1.w)),
                     fmaxf(fmaxf(r2.x,r2.y),fmaxf(r2.z,r2.w))));
    r0.x=__expf(r0.x-mx); r0.y=__expf(r0.y-mx); r0.z=__expf(r0.z-mx); r0.w=__expf(r0.w-mx);
    r1.x=__expf(r1.x-mx); r1.y=__expf(r1.y-mx); r1.z=__expf(r1.z-mx); r1.w=__expf(r1.w-mx);
    r2.x=__expf(r2.x-mx); r2.y=__expf(r2.y-mx); r2.z=__expf(r2.z-mx); r2.w=__expf(r2.w-mx);
    float sum = r0.x+r0.y+r0.z+r0.w + r1.x+r1.y+r1.z+r1.w + r2.x+r2.y+r2.z+r2.w;
    float inv = 1.f/sum;
    r0.x*=inv; r0.y*=inv; r0.z*=inv; r0.w*=inv;
    r1.x*=inv; r1.y*=inv; r1.z*=inv; r1.w*=inv;
    r2.x*=inv; r2.y*=inv; r2.z*=inv; r2.w*=inv;
    *(float4*)row = r0; *(float4*)(row+4) = r1; *(float4*)(row+8) = r2;
  }

  float ov[12];
  {
    int h = lane >> 4;
    #pragma unroll
    for (int l = 0; l < 12; ++l) {
      const float* sr = ss + h*144 + l*12;
      float4 a0 = *(const float4*)sr, a1 = *(const float4*)(sr+4), a2 = *(const float4*)(sr+8);
      ov[l] = a0.x*va[0]+a0.y*va[1]+a0.z*va[2]+a0.w*va[3]
            + a1.x*va[4]+a1.y*va[5]+a1.z*va[6]+a1.w*va[7]
            + a2.x*va[8]+a2.y*va[9]+a2.z*va[10]+a2.w*va[11];
    }
  }
  #pragma unroll
  for (int tg = 0; tg < 3; ++tg)
    yq[tg][lane] = make_float4(ov[4*tg], ov[4*tg+1], ov[4*tg+2], ov[4*tg+3]);

  float z[12];
  {
    float bov = bo[lane];
    #pragma unroll
    for (int t = 0; t < 12; ++t) z[t] = bov;
    for (int j = 0; j < 64; ++j) {
      float w = woT[j*64 + lane];
      #pragma unroll
      for (int tg = 0; tg < 3; ++tg) {
        float4 oo = yq[tg][j];
        #pragma unroll
        for (int e = 0; e < 4; ++e) z[tg*4+e] += w * F4E(oo, e);
      }
    }
    #pragma unroll
    for (int t = 0; t < 12; ++t) z[t] += y[t];
  }

  float y1[12];
  {
    float g1v = g1[lane], b1v = be1[lane];
    #pragma unroll
    for (int t = 0; t < 12; ++t) {
      float m = waveRedSum(z[t]) * (1.f/64.f);
      float dd = z[t] - m;
      float vv = waveRedSum(dd*dd) * (1.f/64.f);
      y1[t] = dd * rsqrtf(vv + 1e-5f) * g1v + b1v;
    }
  }
  #pragma unroll
  for (int tg = 0; tg < 3; ++tg)
    yq[tg][lane] = make_float4(y1[4*tg], y1[4*tg+1], y1[4*tg+2], y1[4*tg+3]);

  {
    float h8[48];
    float fb0 = f1b[lane], fb1 = f1b[lane+64], fb2 = f1b[lane+128], fb3 = f1b[lane+192];
    #pragma unroll
    for (int t = 0; t < 12; ++t) { h8[t] = fb0; h8[12+t] = fb1; h8[24+t] = fb2; h8[36+t] = fb3; }
    for (int j = 0; j < 64; ++j) {
      float w0 = f1wT[j*256 + lane];
      float w1 = f1wT[j*256 + 64 + lane];
      float w2 = f1wT[j*256 + 128 + lane];
      float w3 = f1wT[j*256 + 192 + lane];
      #pragma unroll
      for (int tg = 0; tg < 3; ++tg) {
        float4 yy = yq[tg][j];
        #pragma unroll
        for (int e = 0; e < 4; ++e) {
          float yv = F4E(yy, e); int t = tg*4 + e;
          h8[t] += w0*yv; h8[12+t] += w1*yv; h8[24+t] += w2*yv; h8[36+t] += w3*yv;
        }
      }
    }
    #pragma unroll
    for (int i = 0; i < 48; ++i) h8[i] = fmaxf(h8[i], 0.f);
    #pragma unroll
    for (int tg = 0; tg < 3; ++tg)
      #pragma unroll
      for (int u = 0; u < 4; ++u)
        hq[tg*256 + lane + 64*u] =
          make_float4(h8[u*12 + 4*tg], h8[u*12 + 4*tg + 1], h8[u*12 + 4*tg + 2], h8[u*12 + 4*tg + 3]);
  }

  float z2[12];
  {
    float b2v = f2b[lane];
    #pragma unroll
    for (int t = 0; t < 12; ++t) z2[t] = b2v;
    for (int j = 0; j < 256; ++j) {
      float w = f2wT[j*64 + lane];
      float4 h0 = hq[j], h1 = hq[256 + j], h2 = hq[512 + j];
      z2[0] += w*h0.x; z2[1] += w*h0.y; z2[2]  += w*h0.z; z2[3]  += w*h0.w;
      z2[4] += w*h1.x; z2[5] += w*h1.y; z2[6]  += w*h1.z; z2[7]  += w*h1.w;
      z2[8] += w*h2.x; z2[9] += w*h2.y; z2[10] += w*h2.z; z2[11] += w*h2.w;
    }
    #pragma unroll
    for (int t = 0; t < 12; ++t) z2[t] += y1[t];
  }

  {
    float g2v = g2[lane], b2v = be2[lane];
    #pragma unroll
    for (int t = 0; t < 12; ++t) {
      float m = waveRedSum(z2[t]) * (1.f/64.f);
      float dd = z2[t] - m;
      float vv = waveRedSum(dd*dd) * (1.f/64.f);
      outg[base + t*64 + lane] = dd * rsqrtf(vv + 1e-5f) * g2v + b2v;
    }
  }
}

// ---------------- K7: fuse-matrix prep ----------------
__global__ void k_mvec(const float* __restrict__ flow, const float* __restrict__ clw,
                       const float* __restrict__ clb, float* __restrict__ mv)
{
  int n = blockIdx.x*blockDim.x + threadIdx.x;
  if (n < N_) {
    float s = 0.f;
    float bias = clb[0];
    for (int b = 0; b < B_; ++b) {
      const float* f = flow + ((size_t)b*N_ + n)*T_;
      float acc = bias;
      #pragma unroll
      for (int t = 0; t < T_; ++t) acc += f[t]*clw[t];
      s += fmaxf(acc, 0.f);
    }
    mv[n] = s * (1.f/16.f);
  }
}

__global__ void k_fusemat(const float* __restrict__ mv, float* __restrict__ F)
{
  int idx = blockIdx.x*256 + threadIdx.x;
  int m = idx >> 10, n = idx & 1023;
  float x = 0.5f*(mv[m] + mv[n]);
  F[idx] = 1.f/(1.f + __expf(-x));
}

// ---------------- launch ----------------
extern "C" void kernel_launch(void* const* d_in, const int* in_sizes, int n_in,
                              void* d_out, int out_size, void* d_ws, size_t ws_size,
                              hipStream_t stream)
{
  const float* flow = (const float*)d_in[0];
  const int*   day  = (const int*)d_in[1];
  const int*   week = (const int*)d_in[2];
  const float* semb = (const float*)d_in[3];
  const float* demb = (const float*)d_in[4];
  const float* wemb = (const float*)d_in[5];
  const float* gfsw = (const float*)d_in[6];
  const float* gfsb = (const float*)d_in[7];
  const float* gluw = (const float*)d_in[8];
  const float* glub = (const float*)d_in[9];
  const float* gcw  = (const float*)d_in[10];
  const float* gcA  = (const float*)d_in[11];
  const float* gcA2 = (const float*)d_in[12];
  const float* wi   = (const float*)d_in[13];
  const float* bi   = (const float*)d_in[14];
  const float* w1m  = (const float*)d_in[15];
  const float* b1m  = (const float*)d_in[16];
  const float* w1g  = (const float*)d_in[17];
  const float* b1g  = (const float*)d_in[18];
  const float* w2m  = (const float*)d_in[19];
  const float* b2m  = (const float*)d_in[20];
  const float* w2g  = (const float*)d_in[21];
  const float* b2g  = (const float*)d_in[22];
  const float* wfc  = (const float*)d_in[23];
  const float* bfc  = (const float*)d_in[24];
  const float* wq   = (const float*)d_in[25];
  const float* bq   = (const float*)d_in[26];
  const float* wk   = (const float*)d_in[27];
  const float* bk   = (const float*)d_in[28];
  const float* wv   = (const float*)d_in[29];
  const float* bv   = (const float*)d_in[30];
  const float* wo   = (const float*)d_in[31];
  const float* bo   = (const float*)d_in[32];
  const float* f1w  = (const float*)d_in[33];
  const float* f1b  = (const float*)d_in[34];
  const float* f2w  = (const float*)d_in[35];
  const float* f2b  = (const float*)d_in[36];
  const float* g1   = (const float*)d_in[37];
  const float* be1  = (const float*)d_in[38];
  const float* g2   = (const float*)d_in[39];
  const float* be2  = (const float*)d_in[40];
  const float* clw  = (const float*)d_in[41];
  const float* clb  = (const float*)d_in[42];

  float* out = (float*)d_out;
  char* ws = (char*)d_ws;
  float* Amat = (float*)ws;                                         // 4 MB
  float* mv   = (float*)(ws + (size_t)4*1024*1024);                 // 64 KB region
  float* wTp  = (float*)(ws + (size_t)4*1024*1024 + 65536);         // 256 KB region
  float* wTc  = (float*)(ws + (size_t)4*1024*1024 + 65536 + 262144);// 384 KB region
  float* buf0 = (float*)(ws + (size_t)5*1024*1024);                 // 48 MB

  k_wprep<<<64, 256, 0, stream>>>(wq, wk, wv, wo, f1w, f2w, wTp);
  k_wprep2<<<96, 256, 0, stream>>>(wi, w1m, w1g, w2m, w2g, wfc, wTc);
  // x0 = GLU(gfs_fc(embed)) -> buf0
  k_embed<<<BNT/16, 256, 0, stream>>>(flow, day, week, semb, demb, wemb,
                                      gfsw, gfsb, gluw, glub, buf0);
  // combined adjacency
  k_aprep<<<N_, 256, 0, stream>>>(gcA, gcA2, Amat);
  // hs = A @ x0 -> d_out  (bf16 MFMA)
  dim3 gg(TD/128, N_/128, B_);
  k_gemm_mfma<<<gg, 256, 0, stream>>>(Amat, buf0, out, N_, TD);
  // x2 = relu(hs @ gc_weight) -> buf0
  k_rowmat_relu<<<BNT/16, 256, 0, stream>>>(out, gcw, buf0);
  // x3 = ds block -> d_out
  k_ds2<<<BN_/4, 256, 0, stream>>>(buf0, wTc, bi, b1m, b1g, b2m, b2g, bfc, out);
  // y2 = attn+ffn block -> buf0
  k_attn2<<<BN_/4, 256, 0, stream>>>(out, wTp, bq, bk, bv, bo, f1b, f2b,
                                     g1, be1, g2, be2, buf0);
  // fuse matrix
  k_mvec<<<N_/256, 256, 0, stream>>>(flow, clw, clb, mv);
  k_fusemat<<<(N_*N_)/256, 256, 0, stream>>>(mv, Amat);
  // out = fuse @ y2 -> d_out  (bf16 MFMA)
  k_gemm_mfma<<<gg, 256, 0, stream>>>(Amat, buf0, out, N_, TD);
}

// Round 4
// 1029.225 us; speedup vs baseline: 6.2905x; 1.4500x over previous
//
#include <hip/hip_runtime.h>
#include <cstdint>

#define B_ 16
#define N_ 1024
#define T_ 12
#define HD 64
#define BN_ (B_*N_)     // 16384
#define BNT (B_*N_*T_)  // 196608
#define TD (T_*HD)      // 768

typedef __attribute__((ext_vector_type(8))) short short8;
typedef __attribute__((ext_vector_type(4))) float f32x4;

__device__ __forceinline__ float sigmoidf_(float x) { return 1.f / (1.f + __expf(-x)); }

__device__ __forceinline__ unsigned short f2bf(float f) {
  unsigned int u = __float_as_uint(f);
  u += 0x7fffu + ((u >> 16) & 1u);   // round-to-nearest-even
  return (unsigned short)(u >> 16);
}

#define F4E(v, ii) ((ii)==0?(v).x:((ii)==1?(v).y:((ii)==2?(v).z:(v).w)))

// ---------------- reductions ----------------
__device__ __forceinline__ float blkRedMax(float v, float* red) {
  #pragma unroll
  for (int off = 32; off >= 1; off >>= 1) v = fmaxf(v, __shfl_xor(v, off));
  int w = threadIdx.x >> 6;
  if ((threadIdx.x & 63) == 0) red[w] = v;
  __syncthreads();
  v = fmaxf(fmaxf(red[0], red[1]), fmaxf(red[2], red[3]));
  __syncthreads();
  return v;
}
__device__ __forceinline__ float blkRedSum(float v, float* red) {
  #pragma unroll
  for (int off = 32; off >= 1; off >>= 1) v += __shfl_xor(v, off);
  int w = threadIdx.x >> 6;
  if ((threadIdx.x & 63) == 0) red[w] = v;
  __syncthreads();
  v = red[0] + red[1] + red[2] + red[3];
  __syncthreads();
  return v;
}
__device__ __forceinline__ float waveRedSum(float v) {
  #pragma unroll
  for (int off = 32; off >= 1; off >>= 1) v += __shfl_xor(v, off);
  return v;
}

// ---------------- K-wprep: weight transposes (attn + embed/glu) ----------------
// wT floats: wqkvT[64][192]@0 | woT[64][64]@12288 | f1wT[64][256]@16384 | f2wT[256][64]@32768
//            w1T[64][64]@49152 | w2T[64][128]@53248
__global__ void k_wprep(const float* __restrict__ wq, const float* __restrict__ wk,
                        const float* __restrict__ wv, const float* __restrict__ wo,
                        const float* __restrict__ f1w, const float* __restrict__ f2w,
                        const float* __restrict__ w1, const float* __restrict__ w2,
                        float* __restrict__ wT)
{
  int tid = blockIdx.x*256 + threadIdx.x;   // 16384 threads
  if (tid < 4096) {
    int d = tid >> 6, j = tid & 63;
    wT[j*192 + d]        = wq[tid];
    wT[j*192 + 64 + d]   = wk[tid];
    wT[j*192 + 128 + d]  = wv[tid];
    wT[12288 + j*64 + d] = wo[tid];
    wT[49152 + j*64 + d] = w1[tid];            // gfs_fc_w[d][j] -> w1T[j][d]
  }
  if (tid < 8192) {
    int o = tid >> 6, j = tid & 63;
    wT[53248 + j*128 + o] = w2[tid];           // glu_w[o][j] -> w2T[j][o]
  }
  { // f1w: [256][64] -> f1wT[j][f]
    int f = tid >> 6, j = tid & 63;
    wT[16384 + j*256 + f] = f1w[tid];
  }
  { // f2w: [64][256] -> f2wT[f][d]
    int d = tid >> 8, f = tid & 255;
    wT[32768 + f*64 + d] = f2w[tid];
  }
}

// ---------------- K1: embed + gfs_fc + GLU + (x @ gc_weight), ONE WAVE per 16 rows ----------
// Output xw = GLU(...) @ gc_weight, in bf16 (relu deferred to GEMM1 epilogue).
__global__ __launch_bounds__(256) void k_embed2(
    const float* __restrict__ flow, const int* __restrict__ day, const int* __restrict__ week,
    const float* __restrict__ semb, const float* __restrict__ demb, const float* __restrict__ wemb,
    const float* __restrict__ wT, const float* __restrict__ b1,
    const float* __restrict__ b2, const float* __restrict__ gcw,
    unsigned short* __restrict__ outw)
{
  __shared__ float4 vb_all[4][256];      // 4 waves x 4KB: [dim j][4 row-quads]
  int lane = threadIdx.x & 63, wid = threadIdx.x >> 6;
  float4* vb = vb_all[wid];
  const float* w1T = wT + 49152;
  const float* w2T = wT + 53248;
  int row0 = (blockIdx.x*4 + wid) * 16;

  // gather: lane = input feature c, 16 rows
  float x[16];
  #pragma unroll
  for (int r = 0; r < 16; ++r) {
    int row = row0 + r;
    int n = (row / T_) & (N_-1);
    int c = lane;
    float val;
    if (c == 0)      val = flow[row];
    else if (c < 33) val = semb[n*32 + (c-1)];
    else if (c < 49) val = demb[day[row]*16 + (c-33)];
    else             val = wemb[week[row]*15 + (c-49)];
    x[r] = val;
  }
  #pragma unroll
  for (int q = 0; q < 4; ++q)
    vb[lane*4 + q] = make_float4(x[4*q], x[4*q+1], x[4*q+2], x[4*q+3]);

  // fc: lane = out dim d
  float acc[16];
  {
    float bv = b1[lane];
    #pragma unroll
    for (int r = 0; r < 16; ++r) acc[r] = bv;
    for (int j = 0; j < 64; ++j) {
      float w = w1T[j*64 + lane];
      #pragma unroll
      for (int q = 0; q < 4; ++q) {
        float4 v = vb[j*4 + q];
        acc[4*q]   += w*v.x; acc[4*q+1] += w*v.y;
        acc[4*q+2] += w*v.z; acc[4*q+3] += w*v.w;
      }
    }
  }
  // publish fc result (in-order DS per wave => safe overwrite)
  #pragma unroll
  for (int q = 0; q < 4; ++q)
    vb[lane*4 + q] = make_float4(acc[4*q], acc[4*q+1], acc[4*q+2], acc[4*q+3]);

  // glu: lane computes lo (dim lane) and hi (dim 64+lane)
  float lo[16], hi[16];
  {
    float blo = b2[lane], bhi = b2[64 + lane];
    #pragma unroll
    for (int r = 0; r < 16; ++r) { lo[r] = blo; hi[r] = bhi; }
    for (int j = 0; j < 64; ++j) {
      float wl = w2T[j*128 + lane];
      float wh = w2T[j*128 + 64 + lane];
      #pragma unroll
      for (int q = 0; q < 4; ++q) {
        float4 v = vb[j*4 + q];
        lo[4*q]   += wl*v.x; lo[4*q+1] += wl*v.y; lo[4*q+2] += wl*v.z; lo[4*q+3] += wl*v.w;
        hi[4*q]   += wh*v.x; hi[4*q+1] += wh*v.y; hi[4*q+2] += wh*v.z; hi[4*q+3] += wh*v.w;
      }
    }
    #pragma unroll
    for (int r = 0; r < 16; ++r) lo[r] = lo[r] * sigmoidf_(hi[r]);
  }
  // publish x0
  #pragma unroll
  for (int q = 0; q < 4; ++q)
    vb[lane*4 + q] = make_float4(lo[4*q], lo[4*q+1], lo[4*q+2], lo[4*q+3]);

  // gc: xw[r][e=lane] = sum_d x0[r][d] * gcw[d][e]   (gcw natural layout, coalesced)
  {
    #pragma unroll
    for (int r = 0; r < 16; ++r) acc[r] = 0.f;
    for (int j = 0; j < 64; ++j) {
      float w = gcw[j*64 + lane];
      #pragma unroll
      for (int q = 0; q < 4; ++q) {
        float4 v = vb[j*4 + q];
        acc[4*q]   += w*v.x; acc[4*q+1] += w*v.y;
        acc[4*q+2] += w*v.z; acc[4*q+3] += w*v.w;
      }
    }
    #pragma unroll
    for (int r = 0; r < 16; ++r)
      outw[(size_t)(row0 + r)*64 + lane] = f2bf(acc[r]);
  }
}

// ---------------- K2: A = softmax(relu(A1),1) + softmax(relu(A2),1), bf16 out ------------
__global__ __launch_bounds__(256) void k_aprep(
    const float* __restrict__ A1, const float* __restrict__ A2, unsigned short* __restrict__ Aout)
{
  __shared__ float red[4];
  int m = blockIdx.x, tid = threadIdx.x;
  float mx0, is0, mx1, is1;
  {
    const float* src = A1 + (size_t)m*N_;
    float mx = 0.f;
    for (int i = tid; i < N_; i += 256) mx = fmaxf(mx, fmaxf(src[i], 0.f));
    mx = blkRedMax(mx, red);
    float s = 0.f;
    for (int i = tid; i < N_; i += 256) s += __expf(fmaxf(src[i], 0.f) - mx);
    s = blkRedSum(s, red);
    mx0 = mx; is0 = 1.f / s;
  }
  {
    const float* src = A2 + (size_t)m*N_;
    float mx = 0.f;
    for (int i = tid; i < N_; i += 256) mx = fmaxf(mx, fmaxf(src[i], 0.f));
    mx = blkRedMax(mx, red);
    float s = 0.f;
    for (int i = tid; i < N_; i += 256) s += __expf(fmaxf(src[i], 0.f) - mx);
    s = blkRedSum(s, red);
    mx1 = mx; is1 = 1.f / s;
  }
  const float* s1 = A1 + (size_t)m*N_;
  const float* s2 = A2 + (size_t)m*N_;
  for (int i = tid; i < N_; i += 256) {
    float v1 = __expf(fmaxf(s1[i], 0.f) - mx0) * is0;
    float v2 = __expf(fmaxf(s2[i], 0.f) - mx1) * is1;
    Aout[(size_t)m*N_ + i] = f2bf(v1 + v2);
  }
}

// ---------------- K3: bf16 MFMA batched GEMM: C[b](1024xP) = A(1024x1024) @ X[b](1024xP) ----
// A,X in bf16; 128x128 tile, BK=32, 4 waves; optional relu epilogue.
template<int RELU>
__global__ __launch_bounds__(256) void k_gemm_mfma(
    const unsigned short* __restrict__ A, const unsigned short* __restrict__ X,
    float* __restrict__ C, int K, int P)
{
  __shared__ unsigned short sA[128*40];   // [m][k] pad-40
  __shared__ unsigned short sB[128*40];   // [p][k] (transposed) pad-40
  int tid = threadIdx.x, lane = tid & 63, wid = tid >> 6;
  int M = gridDim.y * 128;
  int b = blockIdx.z;
  const unsigned short* Xb = X + (size_t)b*K*P;
  float* Cb = C + (size_t)b*M*P;
  int m0 = blockIdx.y*128, p0 = blockIdx.x*128;
  int wr = wid >> 1, wc = wid & 1;

  f32x4 acc[4][4] = {};

  for (int k0 = 0; k0 < K; k0 += 32) {
    // stage A: 128 rows x 32 k, bf16 16B loads
    #pragma unroll
    for (int pass = 0; pass < 2; ++pass) {
      int r = (tid >> 2) + 64*pass, kk = (tid & 3)*8;
      short8 v = *(const short8*)&A[(size_t)(m0+r)*K + k0 + kk];
      *(short8*)&sA[r*40 + kk] = v;
    }
    // stage B transposed: sB[p][k] from X[k][p] (p contiguous -> coalesced)
    #pragma unroll
    for (int pass = 0; pass < 4; ++pass) {
      int p  = (tid & 63) + 64*(pass & 1);
      int k4 = (tid >> 6)*4 + 16*(pass >> 1);
      ushort4 h;
      h.x = Xb[(size_t)(k0+k4+0)*P + p0 + p];
      h.y = Xb[(size_t)(k0+k4+1)*P + p0 + p];
      h.z = Xb[(size_t)(k0+k4+2)*P + p0 + p];
      h.w = Xb[(size_t)(k0+k4+3)*P + p0 + p];
      *(ushort4*)&sB[p*40 + k4] = h;
    }
    __syncthreads();
    short8 af[4], bf[4];
    #pragma unroll
    for (int f = 0; f < 4; ++f) {
      af[f] = *(const short8*)&sA[(wr*64 + f*16 + (lane & 15))*40 + (lane >> 4)*8];
      bf[f] = *(const short8*)&sB[(wc*64 + f*16 + (lane & 15))*40 + (lane >> 4)*8];
    }
    #pragma unroll
    for (int fm = 0; fm < 4; ++fm)
      #pragma unroll
      for (int fn = 0; fn < 4; ++fn)
        acc[fm][fn] = __builtin_amdgcn_mfma_f32_16x16x32_bf16(af[fm], bf[fn], acc[fm][fn], 0, 0, 0);
    __syncthreads();
  }
  #pragma unroll
  for (int fm = 0; fm < 4; ++fm) {
    int row = m0 + wr*64 + fm*16 + (lane >> 4)*4;
    #pragma unroll
    for (int fn = 0; fn < 4; ++fn) {
      int col = p0 + wc*64 + fn*16 + (lane & 15);
      #pragma unroll
      for (int r = 0; r < 4; ++r) {
        float v = acc[fm][fn][r];
        if (RELU) v = fmaxf(v, 0.f);
        Cb[(size_t)(row + r)*P + col] = v;
      }
    }
  }
}

// ---------------- K-wprep2: transpose conv weights for k_ds2 ----------------
__global__ void k_wprep2(const float* __restrict__ wi,
                         const float* __restrict__ w1m, const float* __restrict__ w1g,
                         const float* __restrict__ w2m, const float* __restrict__ w2g,
                         const float* __restrict__ wfc, float* __restrict__ wTc)
{
  int t = blockIdx.x*256 + threadIdx.x;   // 96*256 = 24576
  if (t < 24576) {
    int o = t / 192, r = t % 192;
    wTc[r*128 + o] = wi[t];
  }
  if (t < 12288) {
    int o = t / 192, r = t % 192;
    wTc[24576 + r*64 + o] = w1m[t];
    wTc[36864 + r*64 + o] = w1g[t];
    wTc[49152 + r*64 + o] = w2m[t];
    wTc[61440 + r*64 + o] = w2g[t];
  }
  if (t < 8192) {
    int e = t >> 7, j = t & 127;
    wTc[73728 + j*64 + e] = wfc[t];
  }
}

// ---------------- K5: ds temporal-conv block, ONE WAVE per (b,n), in-place safe ---------
__global__ __launch_bounds__(256) void k_ds2(
    const float* xg, const float* __restrict__ wTc,
    const float* __restrict__ bi,
    const float* __restrict__ b1m, const float* __restrict__ b1g,
    const float* __restrict__ b2m, const float* __restrict__ b2g,
    const float* __restrict__ bfc,
    float* out)
{
  __shared__ float xb_all[4][2048];
  int lane = threadIdx.x & 63, wid = threadIdx.x >> 6;
  float* xb = xb_all[wid];
  int bn = blockIdx.x*4 + wid;
  size_t base = (size_t)bn * 768;

  float x[12];
  #pragma unroll
  for (int t = 0; t < 12; ++t) x[t] = xg[base + t*64 + lane];
  {
    float4* d0 = (float4*)(xb + lane*16);
    d0[0] = make_float4(0.f,  x[0], x[1],  x[2]);
    d0[1] = make_float4(x[3], x[4], x[5],  x[6]);
    d0[2] = make_float4(x[7], x[8], x[9],  x[10]);
    d0[3] = make_float4(x[11], 0.f, 0.f,   0.f);
  }

  float alo[12], ahi[12];
  #pragma unroll
  for (int t = 0; t < 12; ++t) { alo[t] = 0.f; ahi[t] = 0.f; }
  {
    const float* wiT = wTc;
    #pragma unroll 2
    for (int i = 0; i < 64; ++i) {
      float4 q0 = *(const float4*)&xb[i*16];
      float4 q1 = *(const float4*)&xb[i*16 + 4];
      float4 q2 = *(const float4*)&xb[i*16 + 8];
      float4 q3 = *(const float4*)&xb[i*16 + 12];
      float xr[16] = {q0.x,q0.y,q0.z,q0.w, q1.x,q1.y,q1.z,q1.w,
                      q2.x,q2.y,q2.z,q2.w, q3.x,q3.y,q3.z,q3.w};
      #pragma unroll
      for (int k = 0; k < 3; ++k) {
        float wlo = wiT[(i*3+k)*128 + lane];
        float whi = wiT[(i*3+k)*128 + 64 + lane];
        #pragma unroll
        for (int t = 0; t < 12; ++t) {
          float xv = xr[t+k];
          alo[t] += wlo*xv; ahi[t] += whi*xv;
        }
      }
    }
    float blo = bi[lane], bhi = bi[64+lane];
    #pragma unroll
    for (int t = 0; t < 12; ++t) { alo[t] += blo; ahi[t] += bhi; }
  }

  {
    float4* d0 = (float4*)(xb + lane*16);
    d0[0] = make_float4(0.f, alo[0], alo[1],  alo[2]);
    d0[1] = make_float4(alo[3], alo[4], alo[5], alo[6]);
    d0[2] = make_float4(alo[7], alo[8], alo[9], alo[10]);
    d0[3] = make_float4(alo[11], 0.f, 0.f, 0.f);
    float4* d1 = (float4*)(xb + (64+lane)*16);
    d1[0] = make_float4(0.f, ahi[0], ahi[1],  ahi[2]);
    d1[1] = make_float4(ahi[3], ahi[4], ahi[5], ahi[6]);
    d1[2] = make_float4(ahi[7], ahi[8], ahi[9], ahi[10]);
    d1[3] = make_float4(ahi[11], 0.f, 0.f, 0.f);
  }

  float fl[12], fh[12];
  #pragma unroll
  for (int half = 0; half < 2; ++half) {
    const float* wmT = wTc + (half ? 49152 : 24576);
    const float* wgT = wTc + (half ? 61440 : 36864);
    float am[12], ag[12];
    #pragma unroll
    for (int t = 0; t < 12; ++t) { am[t] = 0.f; ag[t] = 0.f; }
    int rbase = half*64;
    #pragma unroll 2
    for (int i = 0; i < 64; ++i) {
      float4 q0 = *(const float4*)&xb[(rbase+i)*16];
      float4 q1 = *(const float4*)&xb[(rbase+i)*16 + 4];
      float4 q2 = *(const float4*)&xb[(rbase+i)*16 + 8];
      float4 q3 = *(const float4*)&xb[(rbase+i)*16 + 12];
      float xr[16] = {q0.x,q0.y,q0.z,q0.w, q1.x,q1.y,q1.z,q1.w,
                      q2.x,q2.y,q2.z,q2.w, q3.x,q3.y,q3.z,q3.w};
      #pragma unroll
      for (int k = 0; k < 3; ++k) {
        float wm = wmT[(i*3+k)*64 + lane];
        float wg = wgT[(i*3+k)*64 + lane];
        #pragma unroll
        for (int t = 0; t < 12; ++t) {
          float xv = xr[t+k];
          am[t] += wm*xv; ag[t] += wg*xv;
        }
      }
    }
    float bm = (half ? b2m : b1m)[lane];
    float bg = (half ? b2g : b1g)[lane];
    float* res = half ? ahi : alo;
    float* fo  = half ? fh  : fl;
    #pragma unroll
    for (int t = 0; t < 12; ++t) {
      float po = (am[t]+bm) * sigmoidf_(ag[t]+bg);
      fo[t] = fmaxf(po + res[t], 0.f);
    }
  }

  {
    float4* d0 = (float4*)(xb + lane*16);
    d0[0] = make_float4(fl[0], fl[1], fl[2],  fl[3]);
    d0[1] = make_float4(fl[4], fl[5], fl[6],  fl[7]);
    d0[2] = make_float4(fl[8], fl[9], fl[10], fl[11]);
    float4* d1 = (float4*)(xb + (64+lane)*16);
    d1[0] = make_float4(fh[0], fh[1], fh[2],  fh[3]);
    d1[1] = make_float4(fh[4], fh[5], fh[6],  fh[7]);
    d1[2] = make_float4(fh[8], fh[9], fh[10], fh[11]);
  }

  {
    const float* wfcT = wTc + 73728;
    float fa[12];
    #pragma unroll
    for (int t = 0; t < 12; ++t) fa[t] = 0.f;
    #pragma unroll 4
    for (int j = 0; j < 128; ++j) {
      float4 q0 = *(const float4*)&xb[j*16];
      float4 q1 = *(const float4*)&xb[j*16 + 4];
      float4 q2 = *(const float4*)&xb[j*16 + 8];
      float w = wfcT[j*64 + lane];
      fa[0] += w*q0.x; fa[1] += w*q0.y; fa[2]  += w*q0.z; fa[3]  += w*q0.w;
      fa[4] += w*q1.x; fa[5] += w*q1.y; fa[6]  += w*q1.z; fa[7]  += w*q1.w;
      fa[8] += w*q2.x; fa[9] += w*q2.y; fa[10] += w*q2.z; fa[11] += w*q2.w;
    }
    float bv = bfc[lane];
    #pragma unroll
    for (int t = 0; t < 12; ++t)
      out[base + t*64 + lane] = fa[t] + bv;
  }
}

// ---------------- K6: attention + FFN + 2x LN, ONE WAVE per (b,n); bf16 out ------------
__global__ __launch_bounds__(256) void k_attn2(
    const float* __restrict__ xg,
    const float* __restrict__ wT,
    const float* __restrict__ bq, const float* __restrict__ bk, const float* __restrict__ bv,
    const float* __restrict__ bo,
    const float* __restrict__ f1b, const float* __restrict__ f2b,
    const float* __restrict__ g1, const float* __restrict__ be1,
    const float* __restrict__ g2, const float* __restrict__ be2,
    unsigned short* __restrict__ outg)
{
  __shared__ float4 yq_all[4][3][64];
  __shared__ float  big_all[4][3072];
  int lane = threadIdx.x & 63, wid = threadIdx.x >> 6;
  float4 (*yq)[64] = yq_all[wid];
  float* big = big_all[wid];
  float4* qq = (float4*)big;
  float4* kq = qq + 192;
  float*  ss = big + 1536;
  float4* hq = (float4*)big;

  int bn = blockIdx.x*4 + wid;
  size_t base = (size_t)bn * 768;
  const float* wqkvT = wT;
  const float* woT   = wT + 12288;
  const float* f1wT  = wT + 16384;
  const float* f2wT  = wT + 32768;

  float y[12];
  #pragma unroll
  for (int t = 0; t < 12; ++t) y[t] = xg[base + t*64 + lane];
  #pragma unroll
  for (int tg = 0; tg < 3; ++tg)
    yq[tg][lane] = make_float4(y[4*tg], y[4*tg+1], y[4*tg+2], y[4*tg+3]);

  float qa[12], ka[12], va[12];
  {
    float bqv = bq[lane], bkv = bk[lane], bvv = bv[lane];
    #pragma unroll
    for (int t = 0; t < 12; ++t) { qa[t] = bqv; ka[t] = bkv; va[t] = bvv; }
  }
  for (int j = 0; j < 64; ++j) {
    float wq_ = wqkvT[j*192 + lane];
    float wk_ = wqkvT[j*192 + 64 + lane];
    float wv_ = wqkvT[j*192 + 128 + lane];
    #pragma unroll
    for (int tg = 0; tg < 3; ++tg) {
      float4 yy = yq[tg][j];
      #pragma unroll
      for (int e = 0; e < 4; ++e) {
        float yv = F4E(yy, e); int t = tg*4 + e;
        qa[t] += wq_*yv; ka[t] += wk_*yv; va[t] += wv_*yv;
      }
    }
  }

  #pragma unroll
  for (int tg = 0; tg < 3; ++tg) {
    qq[tg*64 + lane] = make_float4(qa[4*tg], qa[4*tg+1], qa[4*tg+2], qa[4*tg+3]);
    kq[tg*64 + lane] = make_float4(ka[4*tg], ka[4*tg+1], ka[4*tg+2], ka[4*tg+3]);
  }

  #pragma unroll
  for (int it = 0; it < 9; ++it) {
    int idx = it*64 + lane;
    int h = idx/144, rem = idx - h*144, l = rem/12, s = rem - l*12;
    const float* qp = (const float*)(qq + ((l>>2)*64 + h*16));
    const float* kp = (const float*)(kq + ((s>>2)*64 + h*16));
    int le = l & 3, se = s & 3;
    float acc = 0.f;
    #pragma unroll
    for (int j = 0; j < 16; ++j) acc += qp[j*4 + le] * kp[j*4 + se];
    ss[idx] = acc * 0.25f;
  }

  if (lane < 48) {
    float* row = ss + lane*12;
    float4 r0 = *(float4*)row, r1 = *(float4*)(row+4), r2 = *(float4*)(row+8);
    float mx = fmaxf(fmaxf(fmaxf(r0.x,r0.y),fmaxf(r0.z,r0.w)),
               fmaxf(fmaxf(fmaxf(r1.x,r1.y),fmaxf(r1.z,r1.w)),
                     fmaxf(fmaxf(r2.x,r2.y),fmaxf(r2.z,r2.w))));
    r0.x=__expf(r0.x-mx); r0.y=__expf(r0.y-mx); r0.z=__expf(r0.z-mx); r0.w=__expf(r0.w-mx);
    r1.x=__expf(r1.x-mx); r1.y=__expf(r1.y-mx); r1.z=__expf(r1.z-mx); r1.w=__expf(r1.w-mx);
    r2.x=__expf(r2.x-mx); r2.y=__expf(r2.y-mx); r2.z=__expf(r2.z-mx); r2.w=__expf(r2.w-mx);
    float sum = r0.x+r0.y+r0.z+r0.w + r1.x+r1.y+r1.z+r1.w + r2.x+r2.y+r2.z+r2.w;
    float inv = 1.f/sum;
    r0.x*=inv; r0.y*=inv; r0.z*=inv; r0.w*=inv;
    r1.x*=inv; r1.y*=inv; r1.z*=inv; r1.w*=inv;
    r2.x*=inv; r2.y*=inv; r2.z*=inv; r2.w*=inv;
    *(float4*)row = r0; *(float4*)(row+4) = r1; *(float4*)(row+8) = r2;
  }

  float ov[12];
  {
    int h = lane >> 4;
    #pragma unroll
    for (int l = 0; l < 12; ++l) {
      const float* sr = ss + h*144 + l*12;
      float4 a0 = *(const float4*)sr, a1 = *(const float4*)(sr+4), a2 = *(const float4*)(sr+8);
      ov[l] = a0.x*va[0]+a0.y*va[1]+a0.z*va[2]+a0.w*va[3]
            + a1.x*va[4]+a1.y*va[5]+a1.z*va[6]+a1.w*va[7]
            + a2.x*va[8]+a2.y*va[9]+a2.z*va[10]+a2.w*va[11];
    }
  }
  #pragma unroll
  for (int tg = 0; tg < 3; ++tg)
    yq[tg][lane] = make_float4(ov[4*tg], ov[4*tg+1], ov[4*tg+2], ov[4*tg+3]);

  float z[12];
  {
    float bov = bo[lane];
    #pragma unroll
    for (int t = 0; t < 12; ++t) z[t] = bov;
    for (int j = 0; j < 64; ++j) {
      float w = woT[j*64 + lane];
      #pragma unroll
      for (int tg = 0; tg < 3; ++tg) {
        float4 oo = yq[tg][j];
        #pragma unroll
        for (int e = 0; e < 4; ++e) z[tg*4+e] += w * F4E(oo, e);
      }
    }
    #pragma unroll
    for (int t = 0; t < 12; ++t) z[t] += y[t];
  }

  float y1[12];
  {
    float g1v = g1[lane], b1v = be1[lane];
    #pragma unroll
    for (int t = 0; t < 12; ++t) {
      float m = waveRedSum(z[t]) * (1.f/64.f);
      float dd = z[t] - m;
      float vv = waveRedSum(dd*dd) * (1.f/64.f);
      y1[t] = dd * rsqrtf(vv + 1e-5f) * g1v + b1v;
    }
  }
  #pragma unroll
  for (int tg = 0; tg < 3; ++tg)
    yq[tg][lane] = make_float4(y1[4*tg], y1[4*tg+1], y1[4*tg+2], y1[4*tg+3]);

  {
    float h8[48];
    float fb0 = f1b[lane], fb1 = f1b[lane+64], fb2 = f1b[lane+128], fb3 = f1b[lane+192];
    #pragma unroll
    for (int t = 0; t < 12; ++t) { h8[t] = fb0; h8[12+t] = fb1; h8[24+t] = fb2; h8[36+t] = fb3; }
    for (int j = 0; j < 64; ++j) {
      float w0 = f1wT[j*256 + lane];
      float w1 = f1wT[j*256 + 64 + lane];
      float w2 = f1wT[j*256 + 128 + lane];
      float w3 = f1wT[j*256 + 192 + lane];
      #pragma unroll
      for (int tg = 0; tg < 3; ++tg) {
        float4 yy = yq[tg][j];
        #pragma unroll
        for (int e = 0; e < 4; ++e) {
          float yv = F4E(yy, e); int t = tg*4 + e;
          h8[t] += w0*yv; h8[12+t] += w1*yv; h8[24+t] += w2*yv; h8[36+t] += w3*yv;
        }
      }
    }
    #pragma unroll
    for (int i = 0; i < 48; ++i) h8[i] = fmaxf(h8[i], 0.f);
    #pragma unroll
    for (int tg = 0; tg < 3; ++tg)
      #pragma unroll
      for (int u = 0; u < 4; ++u)
        hq[tg*256 + lane + 64*u] =
          make_float4(h8[u*12 + 4*tg], h8[u*12 + 4*tg + 1], h8[u*12 + 4*tg + 2], h8[u*12 + 4*tg + 3]);
  }

  float z2[12];
  {
    float b2v = f2b[lane];
    #pragma unroll
    for (int t = 0; t < 12; ++t) z2[t] = b2v;
    for (int j = 0; j < 256; ++j) {
      float w = f2wT[j*64 + lane];
      float4 h0 = hq[j], h1 = hq[256 + j], h2 = hq[512 + j];
      z2[0] += w*h0.x; z2[1] += w*h0.y; z2[2]  += w*h0.z; z2[3]  += w*h0.w;
      z2[4] += w*h1.x; z2[5] += w*h1.y; z2[6]  += w*h1.z; z2[7]  += w*h1.w;
      z2[8] += w*h2.x; z2[9] += w*h2.y; z2[10] += w*h2.z; z2[11] += w*h2.w;
    }
    #pragma unroll
    for (int t = 0; t < 12; ++t) z2[t] += y1[t];
  }

  {
    float g2v = g2[lane], b2v = be2[lane];
    #pragma unroll
    for (int t = 0; t < 12; ++t) {
      float m = waveRedSum(z2[t]) * (1.f/64.f);
      float dd = z2[t] - m;
      float vv = waveRedSum(dd*dd) * (1.f/64.f);
      outg[base + t*64 + lane] = f2bf(dd * rsqrtf(vv + 1e-5f) * g2v + b2v);
    }
  }
}

// ---------------- K7: fuse-matrix prep ----------------
__global__ void k_mvec(const float* __restrict__ flow, const float* __restrict__ clw,
                       const float* __restrict__ clb, float* __restrict__ mv)
{
  int n = blockIdx.x*blockDim.x + threadIdx.x;
  if (n < N_) {
    float s = 0.f;
    float bias = clb[0];
    for (int b = 0; b < B_; ++b) {
      const float* f = flow + ((size_t)b*N_ + n)*T_;
      float acc = bias;
      #pragma unroll
      for (int t = 0; t < T_; ++t) acc += f[t]*clw[t];
      s += fmaxf(acc, 0.f);
    }
    mv[n] = s * (1.f/16.f);
  }
}

__global__ void k_fusemat(const float* __restrict__ mv, unsigned short* __restrict__ F)
{
  int idx = blockIdx.x*256 + threadIdx.x;
  int m = idx >> 10, n = idx & 1023;
  float x = 0.5f*(mv[m] + mv[n]);
  F[idx] = f2bf(1.f/(1.f + __expf(-x)));
}

// ---------------- launch ----------------
extern "C" void kernel_launch(void* const* d_in, const int* in_sizes, int n_in,
                              void* d_out, int out_size, void* d_ws, size_t ws_size,
                              hipStream_t stream)
{
  const float* flow = (const float*)d_in[0];
  const int*   day  = (const int*)d_in[1];
  const int*   week = (const int*)d_in[2];
  const float* semb = (const float*)d_in[3];
  const float* demb = (const float*)d_in[4];
  const float* wemb = (const float*)d_in[5];
  const float* gfsw = (const float*)d_in[6];
  const float* gfsb = (const float*)d_in[7];
  const float* gluw = (const float*)d_in[8];
  const float* glub = (const float*)d_in[9];
  const float* gcw  = (const float*)d_in[10];
  const float* gcA  = (const float*)d_in[11];
  const float* gcA2 = (const float*)d_in[12];
  const float* wi   = (const float*)d_in[13];
  const float* bi   = (const float*)d_in[14];
  const float* w1m  = (const float*)d_in[15];
  const float* b1m  = (const float*)d_in[16];
  const float* w1g  = (const float*)d_in[17];
  const float* b1g  = (const float*)d_in[18];
  const float* w2m  = (const float*)d_in[19];
  const float* b2m  = (const float*)d_in[20];
  const float* w2g  = (const float*)d_in[21];
  const float* b2g  = (const float*)d_in[22];
  const float* wfc  = (const float*)d_in[23];
  const float* bfc  = (const float*)d_in[24];
  const float* wq   = (const float*)d_in[25];
  const float* bq   = (const float*)d_in[26];
  const float* wk   = (const float*)d_in[27];
  const float* bk   = (const float*)d_in[28];
  const float* wv   = (const float*)d_in[29];
  const float* bv   = (const float*)d_in[30];
  const float* wo   = (const float*)d_in[31];
  const float* bo   = (const float*)d_in[32];
  const float* f1w  = (const float*)d_in[33];
  const float* f1b  = (const float*)d_in[34];
  const float* f2w  = (const float*)d_in[35];
  const float* f2b  = (const float*)d_in[36];
  const float* g1   = (const float*)d_in[37];
  const float* be1  = (const float*)d_in[38];
  const float* g2   = (const float*)d_in[39];
  const float* be2  = (const float*)d_in[40];
  const float* clw  = (const float*)d_in[41];
  const float* clb  = (const float*)d_in[42];

  float* out = (float*)d_out;
  char* ws = (char*)d_ws;
  unsigned short* Amat = (unsigned short*)ws;                          // 2 MB (bf16, also fuse mat)
  float* mv  = (float*)(ws + (size_t)2*1024*1024);                     // 64 KB region
  float* wTp = (float*)(ws + (size_t)2*1024*1024 + 65536);             // 256 KB region
  float* wTc = (float*)(ws + (size_t)2*1024*1024 + 65536 + 262144);    // 384 KB region
  unsigned short* xw = (unsigned short*)(ws + (size_t)3*1024*1024);    // 24 MB (bf16, also y2)

  k_wprep<<<64, 256, 0, stream>>>(wq, wk, wv, wo, f1w, f2w, gfsw, gluw, wTp);
  k_wprep2<<<96, 256, 0, stream>>>(wi, w1m, w1g, w2m, w2g, wfc, wTc);
  // xw = GLU(gfs_fc(embed)) @ gc_weight -> bf16
  k_embed2<<<BNT/64, 256, 0, stream>>>(flow, day, week, semb, demb, wemb,
                                       wTp, gfsb, glub, gcw, xw);
  // combined adjacency (bf16)
  k_aprep<<<N_, 256, 0, stream>>>(gcA, gcA2, Amat);
  // x2 = relu(A @ xw) -> d_out   (relu fused in epilogue)
  dim3 gg(TD/128, N_/128, B_);
  k_gemm_mfma<1><<<gg, 256, 0, stream>>>(Amat, xw, out, N_, TD);
  // x3 = ds block, in-place on d_out
  k_ds2<<<BN_/4, 256, 0, stream>>>(out, wTc, bi, b1m, b1g, b2m, b2g, bfc, out);
  // y2 = attn+ffn block -> bf16 (reuse xw region)
  k_attn2<<<BN_/4, 256, 0, stream>>>(out, wTp, bq, bk, bv, bo, f1b, f2b,
                                     g1, be1, g2, be2, xw);
  // fuse matrix (bf16, reuse Amat region)
  k_mvec<<<N_/256, 256, 0, stream>>>(flow, clw, clb, mv);
  k_fusemat<<<(N_*N_)/256, 256, 0, stream>>>(mv, Amat);
  // out = fuse @ y2 -> d_out
  k_gemm_mfma<0><<<gg, 256, 0, stream>>>(Amat, xw, out, N_, TD);
}

// Round 5
// 639.061 us; speedup vs baseline: 10.1310x; 1.6105x over previous
//
#include <hip/hip_runtime.h>
#include <cstdint>

#define B_ 16
#define N_ 1024
#define T_ 12
#define HD 64
#define BN_ (B_*N_)     // 16384
#define BNT (B_*N_*T_)  // 196608
#define TD (T_*HD)      // 768

typedef __attribute__((ext_vector_type(8))) short short8;
typedef __attribute__((ext_vector_type(4))) float f32x4;

__device__ __forceinline__ float sigmoidf_(float x) { return 1.f / (1.f + __expf(-x)); }

__device__ __forceinline__ unsigned short f2bf(float f) {
  unsigned int u = __float_as_uint(f);
  u += 0x7fffu + ((u >> 16) & 1u);   // round-to-nearest-even
  return (unsigned short)(u >> 16);
}
__device__ __forceinline__ float bf2f(unsigned short h) {
  unsigned int u = ((unsigned int)h) << 16;
  return __uint_as_float(u);
}

#define F4E(v, ii) ((ii)==0?(v).x:((ii)==1?(v).y:((ii)==2?(v).z:(v).w)))

// ---------------- reductions ----------------
__device__ __forceinline__ float blkRedMax(float v, float* red) {
  #pragma unroll
  for (int off = 32; off >= 1; off >>= 1) v = fmaxf(v, __shfl_xor(v, off));
  int w = threadIdx.x >> 6;
  if ((threadIdx.x & 63) == 0) red[w] = v;
  __syncthreads();
  v = fmaxf(fmaxf(red[0], red[1]), fmaxf(red[2], red[3]));
  __syncthreads();
  return v;
}
__device__ __forceinline__ float blkRedSum(float v, float* red) {
  #pragma unroll
  for (int off = 32; off >= 1; off >>= 1) v += __shfl_xor(v, off);
  int w = threadIdx.x >> 6;
  if ((threadIdx.x & 63) == 0) red[w] = v;
  __syncthreads();
  v = red[0] + red[1] + red[2] + red[3];
  __syncthreads();
  return v;
}
__device__ __forceinline__ float waveRedSum(float v) {
  #pragma unroll
  for (int off = 32; off >= 1; off >>= 1) v += __shfl_xor(v, off);
  return v;
}

// ---------------- K-wprep: weight transposes (attn + embed/glu) ----------------
// wT floats: wqkvT[64][192]@0 | woT[64][64]@12288 | f1wT[64][256]@16384 | f2wT[256][64]@32768
//            w1T[64][64]@49152 | w2T[64][128]@53248
__global__ void k_wprep(const float* __restrict__ wq, const float* __restrict__ wk,
                        const float* __restrict__ wv, const float* __restrict__ wo,
                        const float* __restrict__ f1w, const float* __restrict__ f2w,
                        const float* __restrict__ w1, const float* __restrict__ w2,
                        float* __restrict__ wT)
{
  int tid = blockIdx.x*256 + threadIdx.x;   // 16384 threads
  if (tid < 4096) {
    int d = tid >> 6, j = tid & 63;
    wT[j*192 + d]        = wq[tid];
    wT[j*192 + 64 + d]   = wk[tid];
    wT[j*192 + 128 + d]  = wv[tid];
    wT[12288 + j*64 + d] = wo[tid];
    wT[49152 + j*64 + d] = w1[tid];
  }
  if (tid < 8192) {
    int o = tid >> 6, j = tid & 63;
    wT[53248 + j*128 + o] = w2[tid];
  }
  { // f1w: [256][64] -> f1wT[j][f]
    int f = tid >> 6, j = tid & 63;
    wT[16384 + j*256 + f] = f1w[tid];
  }
  { // f2w: [64][256] -> f2wT[f][d]
    int d = tid >> 8, f = tid & 255;
    wT[32768 + f*64 + d] = f2w[tid];
  }
}

// ---------------- K-wprep3: bf16 tap-major conv weights for k_ds3 ----------------
// W u16: WiB[128][192]@0 | Wg1B[128][192]@24576 | Wg2B[128][192]@49152 | WfB[64][128]@73728
// K-order: k = tap*64 + i
__global__ void k_wprep3(const float* __restrict__ wi,
                         const float* __restrict__ w1m, const float* __restrict__ w1g,
                         const float* __restrict__ w2m, const float* __restrict__ w2g,
                         const float* __restrict__ wfc, unsigned short* __restrict__ W)
{
  int t = blockIdx.x*256 + threadIdx.x;  // 96*256 = 24576
  {
    int o = t / 192, k = t - o*192, tap = k >> 6, i = k & 63;
    W[o*192 + k] = f2bf(wi[(o*64 + i)*3 + tap]);
  }
  if (t < 12288) {
    int o = t / 192, k = t - o*192, tap = k >> 6, i = k & 63;
    int src = (o*64 + i)*3 + tap;
    W[24576 + o*192 + k]      = f2bf(w1m[src]);
    W[24576 + (64+o)*192 + k] = f2bf(w1g[src]);
    W[49152 + o*192 + k]      = f2bf(w2m[src]);
    W[49152 + (64+o)*192 + k] = f2bf(w2g[src]);
  }
  if (t < 8192) W[73728 + t] = f2bf(wfc[t]);
}

// ---------------- K1: embed + gfs_fc + GLU + (x @ gc_weight), ONE WAVE per 16 rows ----------
__global__ __launch_bounds__(256) void k_embed2(
    const float* __restrict__ flow, const int* __restrict__ day, const int* __restrict__ week,
    const float* __restrict__ semb, const float* __restrict__ demb, const float* __restrict__ wemb,
    const float* __restrict__ wT, const float* __restrict__ b1,
    const float* __restrict__ b2, const float* __restrict__ gcw,
    unsigned short* __restrict__ outw)
{
  __shared__ float4 vb_all[4][256];
  int lane = threadIdx.x & 63, wid = threadIdx.x >> 6;
  float4* vb = vb_all[wid];
  const float* w1T = wT + 49152;
  const float* w2T = wT + 53248;
  int row0 = (blockIdx.x*4 + wid) * 16;

  float x[16];
  #pragma unroll
  for (int r = 0; r < 16; ++r) {
    int row = row0 + r;
    int n = (row / T_) & (N_-1);
    int c = lane;
    float val;
    if (c == 0)      val = flow[row];
    else if (c < 33) val = semb[n*32 + (c-1)];
    else if (c < 49) val = demb[day[row]*16 + (c-33)];
    else             val = wemb[week[row]*15 + (c-49)];
    x[r] = val;
  }
  #pragma unroll
  for (int q = 0; q < 4; ++q)
    vb[lane*4 + q] = make_float4(x[4*q], x[4*q+1], x[4*q+2], x[4*q+3]);

  float acc[16];
  {
    float bv = b1[lane];
    #pragma unroll
    for (int r = 0; r < 16; ++r) acc[r] = bv;
    for (int j = 0; j < 64; ++j) {
      float w = w1T[j*64 + lane];
      #pragma unroll
      for (int q = 0; q < 4; ++q) {
        float4 v = vb[j*4 + q];
        acc[4*q]   += w*v.x; acc[4*q+1] += w*v.y;
        acc[4*q+2] += w*v.z; acc[4*q+3] += w*v.w;
      }
    }
  }
  #pragma unroll
  for (int q = 0; q < 4; ++q)
    vb[lane*4 + q] = make_float4(acc[4*q], acc[4*q+1], acc[4*q+2], acc[4*q+3]);

  float lo[16], hi[16];
  {
    float blo = b2[lane], bhi = b2[64 + lane];
    #pragma unroll
    for (int r = 0; r < 16; ++r) { lo[r] = blo; hi[r] = bhi; }
    for (int j = 0; j < 64; ++j) {
      float wl = w2T[j*128 + lane];
      float wh = w2T[j*128 + 64 + lane];
      #pragma unroll
      for (int q = 0; q < 4; ++q) {
        float4 v = vb[j*4 + q];
        lo[4*q]   += wl*v.x; lo[4*q+1] += wl*v.y; lo[4*q+2] += wl*v.z; lo[4*q+3] += wl*v.w;
        hi[4*q]   += wh*v.x; hi[4*q+1] += wh*v.y; hi[4*q+2] += wh*v.z; hi[4*q+3] += wh*v.w;
      }
    }
    #pragma unroll
    for (int r = 0; r < 16; ++r) lo[r] = lo[r] * sigmoidf_(hi[r]);
  }
  #pragma unroll
  for (int q = 0; q < 4; ++q)
    vb[lane*4 + q] = make_float4(lo[4*q], lo[4*q+1], lo[4*q+2], lo[4*q+3]);

  {
    #pragma unroll
    for (int r = 0; r < 16; ++r) acc[r] = 0.f;
    for (int j = 0; j < 64; ++j) {
      float w = gcw[j*64 + lane];
      #pragma unroll
      for (int q = 0; q < 4; ++q) {
        float4 v = vb[j*4 + q];
        acc[4*q]   += w*v.x; acc[4*q+1] += w*v.y;
        acc[4*q+2] += w*v.z; acc[4*q+3] += w*v.w;
      }
    }
    #pragma unroll
    for (int r = 0; r < 16; ++r)
      outw[(size_t)(row0 + r)*64 + lane] = f2bf(acc[r]);
  }
}

// ---------------- K2: A = softmax(relu(A1),1) + softmax(relu(A2),1), bf16 out ------------
__global__ __launch_bounds__(256) void k_aprep(
    const float* __restrict__ A1, const float* __restrict__ A2, unsigned short* __restrict__ Aout)
{
  __shared__ float red[4];
  int m = blockIdx.x, tid = threadIdx.x;
  float mx0, is0, mx1, is1;
  {
    const float* src = A1 + (size_t)m*N_;
    float mx = 0.f;
    for (int i = tid; i < N_; i += 256) mx = fmaxf(mx, fmaxf(src[i], 0.f));
    mx = blkRedMax(mx, red);
    float s = 0.f;
    for (int i = tid; i < N_; i += 256) s += __expf(fmaxf(src[i], 0.f) - mx);
    s = blkRedSum(s, red);
    mx0 = mx; is0 = 1.f / s;
  }
  {
    const float* src = A2 + (size_t)m*N_;
    float mx = 0.f;
    for (int i = tid; i < N_; i += 256) mx = fmaxf(mx, fmaxf(src[i], 0.f));
    mx = blkRedMax(mx, red);
    float s = 0.f;
    for (int i = tid; i < N_; i += 256) s += __expf(fmaxf(src[i], 0.f) - mx);
    s = blkRedSum(s, red);
    mx1 = mx; is1 = 1.f / s;
  }
  const float* s1 = A1 + (size_t)m*N_;
  const float* s2 = A2 + (size_t)m*N_;
  for (int i = tid; i < N_; i += 256) {
    float v1 = __expf(fmaxf(s1[i], 0.f) - mx0) * is0;
    float v2 = __expf(fmaxf(s2[i], 0.f) - mx1) * is1;
    Aout[(size_t)m*N_ + i] = f2bf(v1 + v2);
  }
}

// ---------------- K3: bf16 MFMA batched GEMM ----------------
template<int RELU, int OB16>
__global__ __launch_bounds__(256) void k_gemm_mfma(
    const unsigned short* __restrict__ A, const unsigned short* __restrict__ X,
    void* __restrict__ C, int K, int P)
{
  __shared__ unsigned short sA[128*40];
  __shared__ unsigned short sB[128*40];
  int tid = threadIdx.x, lane = tid & 63, wid = tid >> 6;
  int M = gridDim.y * 128;
  int b = blockIdx.z;
  const unsigned short* Xb = X + (size_t)b*K*P;
  int m0 = blockIdx.y*128, p0 = blockIdx.x*128;
  int wr = wid >> 1, wc = wid & 1;

  f32x4 acc[4][4] = {};

  for (int k0 = 0; k0 < K; k0 += 32) {
    #pragma unroll
    for (int pass = 0; pass < 2; ++pass) {
      int r = (tid >> 2) + 64*pass, kk = (tid & 3)*8;
      short8 v = *(const short8*)&A[(size_t)(m0+r)*K + k0 + kk];
      *(short8*)&sA[r*40 + kk] = v;
    }
    #pragma unroll
    for (int pass = 0; pass < 4; ++pass) {
      int p  = (tid & 63) + 64*(pass & 1);
      int k4 = (tid >> 6)*4 + 16*(pass >> 1);
      ushort4 h;
      h.x = Xb[(size_t)(k0+k4+0)*P + p0 + p];
      h.y = Xb[(size_t)(k0+k4+1)*P + p0 + p];
      h.z = Xb[(size_t)(k0+k4+2)*P + p0 + p];
      h.w = Xb[(size_t)(k0+k4+3)*P + p0 + p];
      *(ushort4*)&sB[p*40 + k4] = h;
    }
    __syncthreads();
    short8 af[4], bf[4];
    #pragma unroll
    for (int f = 0; f < 4; ++f) {
      af[f] = *(const short8*)&sA[(wr*64 + f*16 + (lane & 15))*40 + (lane >> 4)*8];
      bf[f] = *(const short8*)&sB[(wc*64 + f*16 + (lane & 15))*40 + (lane >> 4)*8];
    }
    #pragma unroll
    for (int fm = 0; fm < 4; ++fm)
      #pragma unroll
      for (int fn = 0; fn < 4; ++fn)
        acc[fm][fn] = __builtin_amdgcn_mfma_f32_16x16x32_bf16(af[fm], bf[fn], acc[fm][fn], 0, 0, 0);
    __syncthreads();
  }
  #pragma unroll
  for (int fm = 0; fm < 4; ++fm) {
    int row = m0 + wr*64 + fm*16 + (lane >> 4)*4;
    #pragma unroll
    for (int fn = 0; fn < 4; ++fn) {
      int col = p0 + wc*64 + fn*16 + (lane & 15);
      #pragma unroll
      for (int r = 0; r < 4; ++r) {
        float v = acc[fm][fn][r];
        if (RELU) v = fmaxf(v, 0.f);
        if (OB16) {
          unsigned short* Cb = (unsigned short*)C + (size_t)b*M*P;
          Cb[(size_t)(row + r)*P + col] = f2bf(v);
        } else {
          float* Cb = (float*)C + (size_t)b*M*P;
          Cb[(size_t)(row + r)*P + col] = v;
        }
      }
    }
  }
}

// ---------------- K5: ds temporal-conv block, MFMA, 8 bn per block ----------------
// Pipeline: X(LDS) --GEMM1--> x_init(LDS,bf16) --GEMM2x2+gate+res+relu--> fused(LDS,bf16)
//           --GEMM3--> out(global fp32). Weights read as B/A-fragments direct from L2.
__global__ __launch_bounds__(256) void k_ds3(
    const unsigned short* __restrict__ xds,   // [BNT][64] bf16
    const unsigned short* __restrict__ Wall,  // WiB@0 | Wg1B@24576 | Wg2B@49152 | WfB@73728
    const float* __restrict__ bi,
    const float* __restrict__ b1m, const float* __restrict__ b1g,
    const float* __restrict__ b2m, const float* __restrict__ b2g,
    const float* __restrict__ bfc,
    float* __restrict__ outg)
{
  __shared__ unsigned short smem[36352];       // 72704 B
  unsigned short* X_lds  = smem;               // [8][14][72]
  unsigned short* xi_lds = smem + 8064;        // [8][14][136]
  unsigned short* fu_lds = smem + 23296;       // [96][136]
  const unsigned short* WiB  = Wall;
  const unsigned short* Wg1B = Wall + 24576;
  const unsigned short* Wg2B = Wall + 49152;
  const unsigned short* WfB  = Wall + 73728;

  int tid = threadIdx.x, lane = tid & 63, wid = tid >> 6;
  int l15 = lane & 15, l4 = lane >> 4;
  int bn0 = blockIdx.x * 8;

  // zero pad rows (t=0 and t=13 for each g)
  for (int i = tid; i < 8*2*72; i += 256) {
    int g = i / 144, r = i - g*144;
    int tp = (r < 72) ? 0 : 13, c = (r < 72) ? r : r - 72;
    X_lds[(g*14 + tp)*72 + c] = 0;
  }
  for (int i = tid; i < 8*2*136; i += 256) {
    int g = i / 272, r = i - g*272;
    int tp = (r < 136) ? 0 : 13, c = (r < 136) ? r : r - 136;
    xi_lds[(g*14 + tp)*136 + c] = 0;
  }
  // stage X: 8 bn x 12 t x 64 ch
  for (int i = tid; i < 768; i += 256) {
    int g = i / 96, rem = i - g*96, t = rem >> 3, i8 = rem & 7;
    short8 v = *(const short8*)&xds[(size_t)(bn0+g)*768 + t*64 + i8*8];
    *(short8*)&X_lds[(g*14 + t + 1)*72 + i8*8] = v;
  }
  __syncthreads();

  // per-lane row maps for r = mt*16 + l15 (used by A-frags, GEMM3 B-frags/epilogue)
  int ga[6], ta[6];
  #pragma unroll
  for (int mt = 0; mt < 6; ++mt) {
    int r = mt*16 + l15;
    ga[mt] = r / 12; ta[mt] = r - ga[mt]*12;
  }

  // ===== GEMM1: x_init[96][128] = im2col(X)[96][192] @ WiB^T =====
  {
    f32x4 acc1[6][2] = {};
    int nb = wid*2;
    #pragma unroll
    for (int ks = 0; ks < 6; ++ks) {
      int tap = ks >> 1, i0 = (ks & 1)*32;
      short8 af[6];
      #pragma unroll
      for (int mt = 0; mt < 6; ++mt)
        af[mt] = *(const short8*)&X_lds[(ga[mt]*14 + ta[mt] + tap)*72 + i0 + l4*8];
      short8 bf0 = *(const short8*)&WiB[(size_t)((nb  )*16 + l15)*192 + ks*32 + l4*8];
      short8 bf1 = *(const short8*)&WiB[(size_t)((nb+1)*16 + l15)*192 + ks*32 + l4*8];
      #pragma unroll
      for (int mt = 0; mt < 6; ++mt) {
        acc1[mt][0] = __builtin_amdgcn_mfma_f32_16x16x32_bf16(af[mt], bf0, acc1[mt][0], 0, 0, 0);
        acc1[mt][1] = __builtin_amdgcn_mfma_f32_16x16x32_bf16(af[mt], bf1, acc1[mt][1], 0, 0, 0);
      }
    }
    #pragma unroll
    for (int nn = 0; nn < 2; ++nn) {
      int o = (nb+nn)*16 + l15;
      float bv = bi[o];
      #pragma unroll
      for (int mt = 0; mt < 6; ++mt) {
        #pragma unroll
        for (int reg = 0; reg < 4; ++reg) {
          int r = mt*16 + l4*4 + reg;
          int g = r / 12, t = r - g*12;
          xi_lds[(g*14 + t + 1)*136 + o] = f2bf(acc1[mt][nn][reg] + bv);
        }
      }
    }
  }
  __syncthreads();

  // ===== GEMM2 (x2 halves): gated conv + gate + residual + relu -> fused =====
  #pragma unroll
  for (int h = 0; h < 2; ++h) {
    const unsigned short* Wg = h ? Wg2B : Wg1B;
    f32x4 am[6] = {}, ag[6] = {};
    #pragma unroll
    for (int ks = 0; ks < 6; ++ks) {
      int tap = ks >> 1, i0 = (ks & 1)*32;
      short8 af[6];
      #pragma unroll
      for (int mt = 0; mt < 6; ++mt)
        af[mt] = *(const short8*)&xi_lds[(ga[mt]*14 + ta[mt] + tap)*136 + h*64 + i0 + l4*8];
      short8 bm = *(const short8*)&Wg[(size_t)(wid*16 + l15)*192 + ks*32 + l4*8];
      short8 bg = *(const short8*)&Wg[(size_t)((wid+4)*16 + l15)*192 + ks*32 + l4*8];
      #pragma unroll
      for (int mt = 0; mt < 6; ++mt) {
        am[mt] = __builtin_amdgcn_mfma_f32_16x16x32_bf16(af[mt], bm, am[mt], 0, 0, 0);
        ag[mt] = __builtin_amdgcn_mfma_f32_16x16x32_bf16(af[mt], bg, ag[mt], 0, 0, 0);
      }
    }
    int o = wid*16 + l15;
    float bmv = (h ? b2m : b1m)[o];
    float bgv = (h ? b2g : b1g)[o];
    #pragma unroll
    for (int mt = 0; mt < 6; ++mt) {
      #pragma unroll
      for (int reg = 0; reg < 4; ++reg) {
        int r = mt*16 + l4*4 + reg;
        int g = r / 12, t = r - g*12;
        float pm = am[mt][reg] + bmv;
        float pg = ag[mt][reg] + bgv;
        float po = pm * sigmoidf_(pg);
        float xi = bf2f(xi_lds[(g*14 + t + 1)*136 + h*64 + o]);
        fu_lds[r*136 + h*64 + o] = f2bf(fmaxf(po + xi, 0.f));
      }
    }
  }
  __syncthreads();

  // ===== GEMM3: out[64 e][96 r] = WfB[64][128] @ fused^T =====
  {
    f32x4 a3[6] = {};
    #pragma unroll
    for (int ks = 0; ks < 4; ++ks) {
      short8 af = *(const short8*)&WfB[(size_t)(wid*16 + l15)*128 + ks*32 + l4*8];
      #pragma unroll
      for (int nt = 0; nt < 6; ++nt) {
        short8 bf = *(const short8*)&fu_lds[(nt*16 + l15)*136 + ks*32 + l4*8];
        a3[nt] = __builtin_amdgcn_mfma_f32_16x16x32_bf16(af, bf, a3[nt], 0, 0, 0);
      }
    }
    int e0 = wid*16 + l4*4;
    float4 bb = *(const float4*)&bfc[e0];
    #pragma unroll
    for (int nt = 0; nt < 6; ++nt) {
      float4 vv = make_float4(a3[nt][0] + bb.x, a3[nt][1] + bb.y,
                              a3[nt][2] + bb.z, a3[nt][3] + bb.w);
      *(float4*)&outg[((size_t)(bn0 + ga[nt])*12 + ta[nt])*64 + e0] = vv;
    }
  }
}

// ---------------- K6: attention + FFN + 2x LN, ONE WAVE per (b,n); bf16 out ------------
__global__ __launch_bounds__(256) void k_attn2(
    const float* __restrict__ xg,
    const float* __restrict__ wT,
    const float* __restrict__ bq, const float* __restrict__ bk, const float* __restrict__ bv,
    const float* __restrict__ bo,
    const float* __restrict__ f1b, const float* __restrict__ f2b,
    const float* __restrict__ g1, const float* __restrict__ be1,
    const float* __restrict__ g2, const float* __restrict__ be2,
    unsigned short* __restrict__ outg)
{
  __shared__ float4 yq_all[4][3][64];
  __shared__ float  big_all[4][3072];
  int lane = threadIdx.x & 63, wid = threadIdx.x >> 6;
  float4 (*yq)[64] = yq_all[wid];
  float* big = big_all[wid];
  float4* qq = (float4*)big;
  float4* kq = qq + 192;
  float*  ss = big + 1536;
  float4* hq = (float4*)big;

  int bn = blockIdx.x*4 + wid;
  size_t base = (size_t)bn * 768;
  const float* wqkvT = wT;
  const float* woT   = wT + 12288;
  const float* f1wT  = wT + 16384;
  const float* f2wT  = wT + 32768;

  float y[12];
  #pragma unroll
  for (int t = 0; t < 12; ++t) y[t] = xg[base + t*64 + lane];
  #pragma unroll
  for (int tg = 0; tg < 3; ++tg)
    yq[tg][lane] = make_float4(y[4*tg], y[4*tg+1], y[4*tg+2], y[4*tg+3]);

  float qa[12], ka[12], va[12];
  {
    float bqv = bq[lane], bkv = bk[lane], bvv = bv[lane];
    #pragma unroll
    for (int t = 0; t < 12; ++t) { qa[t] = bqv; ka[t] = bkv; va[t] = bvv; }
  }
  for (int j = 0; j < 64; ++j) {
    float wq_ = wqkvT[j*192 + lane];
    float wk_ = wqkvT[j*192 + 64 + lane];
    float wv_ = wqkvT[j*192 + 128 + lane];
    #pragma unroll
    for (int tg = 0; tg < 3; ++tg) {
      float4 yy = yq[tg][j];
      #pragma unroll
      for (int e = 0; e < 4; ++e) {
        float yv = F4E(yy, e); int t = tg*4 + e;
        qa[t] += wq_*yv; ka[t] += wk_*yv; va[t] += wv_*yv;
      }
    }
  }

  #pragma unroll
  for (int tg = 0; tg < 3; ++tg) {
    qq[tg*64 + lane] = make_float4(qa[4*tg], qa[4*tg+1], qa[4*tg+2], qa[4*tg+3]);
    kq[tg*64 + lane] = make_float4(ka[4*tg], ka[4*tg+1], ka[4*tg+2], ka[4*tg+3]);
  }

  #pragma unroll
  for (int it = 0; it < 9; ++it) {
    int idx = it*64 + lane;
    int h = idx/144, rem = idx - h*144, l = rem/12, s = rem - l*12;
    const float* qp = (const float*)(qq + ((l>>2)*64 + h*16));
    const float* kp = (const float*)(kq + ((s>>2)*64 + h*16));
    int le = l & 3, se = s & 3;
    float acc = 0.f;
    #pragma unroll
    for (int j = 0; j < 16; ++j) acc += qp[j*4 + le] * kp[j*4 + se];
    ss[idx] = acc * 0.25f;
  }

  if (lane < 48) {
    float* row = ss + lane*12;
    float4 r0 = *(float4*)row, r1 = *(float4*)(row+4), r2 = *(float4*)(row+8);
    float mx = fmaxf(fmaxf(fmaxf(r0.x,r0.y),fmaxf(r0.z,r0.w)),
               fmaxf(fmaxf(fmaxf(r1.x,r1.y),fmaxf(r1.z,r1.w)),
                     fmaxf(fmaxf(r2.x,r2.y),fmaxf(r2.z,r2.w))));
    r0.x=__expf(r0.x-mx); r0.y=__expf(r0.y-mx); r0.z=__expf(r0.z-mx); r0.w=__expf(r0.w-mx);
    r1.x=__expf(r1.x-mx); r1.y=__expf(r1.y-mx); r1.z=__expf(r1.z-mx); r1.w=__expf(r1.w-mx);
    r2.x=__expf(r2.x-mx); r2.y=__expf(r2.y-mx); r2.z=__expf(r2.z-mx); r2.w=__expf(r2.w-mx);
    float sum = r0.x+r0.y+r0.z+r0.w + r1.x+r1.y+r1.z+r1.w + r2.x+r2.y+r2.z+r2.w;
    float inv = 1.f/sum;
    r0.x*=inv; r0.y*=inv; r0.z*=inv; r0.w*=inv;
    r1.x*=inv; r1.y*=inv; r1.z*=inv; r1.w*=inv;
    r2.x*=inv; r2.y*=inv; r2.z*=inv; r2.w*=inv;
    *(float4*)row = r0; *(float4*)(row+4) = r1; *(float4*)(row+8) = r2;
  }

  float ov[12];
  {
    int h = lane >> 4;
    #pragma unroll
    for (int l = 0; l < 12; ++l) {
      const float* sr = ss + h*144 + l*12;
      float4 a0 = *(const float4*)sr, a1 = *(const float4*)(sr+4), a2 = *(const float4*)(sr+8);
      ov[l] = a0.x*va[0]+a0.y*va[1]+a0.z*va[2]+a0.w*va[3]
            + a1.x*va[4]+a1.y*va[5]+a1.z*va[6]+a1.w*va[7]
            + a2.x*va[8]+a2.y*va[9]+a2.z*va[10]+a2.w*va[11];
    }
  }
  #pragma unroll
  for (int tg = 0; tg < 3; ++tg)
    yq[tg][lane] = make_float4(ov[4*tg], ov[4*tg+1], ov[4*tg+2], ov[4*tg+3]);

  float z[12];
  {
    float bov = bo[lane];
    #pragma unroll
    for (int t = 0; t < 12; ++t) z[t] = bov;
    for (int j = 0; j < 64; ++j) {
      float w = woT[j*64 + lane];
      #pragma unroll
      for (int tg = 0; tg < 3; ++tg) {
        float4 oo = yq[tg][j];
        #pragma unroll
        for (int e = 0; e < 4; ++e) z[tg*4+e] += w * F4E(oo, e);
      }
    }
    #pragma unroll
    for (int t = 0; t < 12; ++t) z[t] += y[t];
  }

  float y1[12];
  {
    float g1v = g1[lane], b1v = be1[lane];
    #pragma unroll
    for (int t = 0; t < 12; ++t) {
      float m = waveRedSum(z[t]) * (1.f/64.f);
      float dd = z[t] - m;
      float vv = waveRedSum(dd*dd) * (1.f/64.f);
      y1[t] = dd * rsqrtf(vv + 1e-5f) * g1v + b1v;
    }
  }
  #pragma unroll
  for (int tg = 0; tg < 3; ++tg)
    yq[tg][lane] = make_float4(y1[4*tg], y1[4*tg+1], y1[4*tg+2], y1[4*tg+3]);

  {
    float h8[48];
    float fb0 = f1b[lane], fb1 = f1b[lane+64], fb2 = f1b[lane+128], fb3 = f1b[lane+192];
    #pragma unroll
    for (int t = 0; t < 12; ++t) { h8[t] = fb0; h8[12+t] = fb1; h8[24+t] = fb2; h8[36+t] = fb3; }
    for (int j = 0; j < 64; ++j) {
      float w0 = f1wT[j*256 + lane];
      float w1 = f1wT[j*256 + 64 + lane];
      float w2 = f1wT[j*256 + 128 + lane];
      float w3 = f1wT[j*256 + 192 + lane];
      #pragma unroll
      for (int tg = 0; tg < 3; ++tg) {
        float4 yy = yq[tg][j];
        #pragma unroll
        for (int e = 0; e < 4; ++e) {
          float yv = F4E(yy, e); int t = tg*4 + e;
          h8[t] += w0*yv; h8[12+t] += w1*yv; h8[24+t] += w2*yv; h8[36+t] += w3*yv;
        }
      }
    }
    #pragma unroll
    for (int i = 0; i < 48; ++i) h8[i] = fmaxf(h8[i], 0.f);
    #pragma unroll
    for (int tg = 0; tg < 3; ++tg)
      #pragma unroll
      for (int u = 0; u < 4; ++u)
        hq[tg*256 + lane + 64*u] =
          make_float4(h8[u*12 + 4*tg], h8[u*12 + 4*tg + 1], h8[u*12 + 4*tg + 2], h8[u*12 + 4*tg + 3]);
  }

  float z2[12];
  {
    float b2v = f2b[lane];
    #pragma unroll
    for (int t = 0; t < 12; ++t) z2[t] = b2v;
    for (int j = 0; j < 256; ++j) {
      float w = f2wT[j*64 + lane];
      float4 h0 = hq[j], h1 = hq[256 + j], h2 = hq[512 + j];
      z2[0] += w*h0.x; z2[1] += w*h0.y; z2[2]  += w*h0.z; z2[3]  += w*h0.w;
      z2[4] += w*h1.x; z2[5] += w*h1.y; z2[6]  += w*h1.z; z2[7]  += w*h1.w;
      z2[8] += w*h2.x; z2[9] += w*h2.y; z2[10] += w*h2.z; z2[11] += w*h2.w;
    }
    #pragma unroll
    for (int t = 0; t < 12; ++t) z2[t] += y1[t];
  }

  {
    float g2v = g2[lane], b2v = be2[lane];
    #pragma unroll
    for (int t = 0; t < 12; ++t) {
      float m = waveRedSum(z2[t]) * (1.f/64.f);
      float dd = z2[t] - m;
      float vv = waveRedSum(dd*dd) * (1.f/64.f);
      outg[base + t*64 + lane] = f2bf(dd * rsqrtf(vv + 1e-5f) * g2v + b2v);
    }
  }
}

// ---------------- K7: fuse-matrix prep ----------------
__global__ void k_mvec(const float* __restrict__ flow, const float* __restrict__ clw,
                       const float* __restrict__ clb, float* __restrict__ mv)
{
  int n = blockIdx.x*blockDim.x + threadIdx.x;
  if (n < N_) {
    float s = 0.f;
    float bias = clb[0];
    for (int b = 0; b < B_; ++b) {
      const float* f = flow + ((size_t)b*N_ + n)*T_;
      float acc = bias;
      #pragma unroll
      for (int t = 0; t < T_; ++t) acc += f[t]*clw[t];
      s += fmaxf(acc, 0.f);
    }
    mv[n] = s * (1.f/16.f);
  }
}

__global__ void k_fusemat(const float* __restrict__ mv, unsigned short* __restrict__ F)
{
  int idx = blockIdx.x*256 + threadIdx.x;
  int m = idx >> 10, n = idx & 1023;
  float x = 0.5f*(mv[m] + mv[n]);
  F[idx] = f2bf(1.f/(1.f + __expf(-x)));
}

// ---------------- launch ----------------
extern "C" void kernel_launch(void* const* d_in, const int* in_sizes, int n_in,
                              void* d_out, int out_size, void* d_ws, size_t ws_size,
                              hipStream_t stream)
{
  const float* flow = (const float*)d_in[0];
  const int*   day  = (const int*)d_in[1];
  const int*   week = (const int*)d_in[2];
  const float* semb = (const float*)d_in[3];
  const float* demb = (const float*)d_in[4];
  const float* wemb = (const float*)d_in[5];
  const float* gfsw = (const float*)d_in[6];
  const float* gfsb = (const float*)d_in[7];
  const float* gluw = (const float*)d_in[8];
  const float* glub = (const float*)d_in[9];
  const float* gcw  = (const float*)d_in[10];
  const float* gcA  = (const float*)d_in[11];
  const float* gcA2 = (const float*)d_in[12];
  const float* wi   = (const float*)d_in[13];
  const float* bi   = (const float*)d_in[14];
  const float* w1m  = (const float*)d_in[15];
  const float* b1m  = (const float*)d_in[16];
  const float* w1g  = (const float*)d_in[17];
  const float* b1g  = (const float*)d_in[18];
  const float* w2m  = (const float*)d_in[19];
  const float* b2m  = (const float*)d_in[20];
  const float* w2g  = (const float*)d_in[21];
  const float* b2g  = (const float*)d_in[22];
  const float* wfc  = (const float*)d_in[23];
  const float* bfc  = (const float*)d_in[24];
  const float* wq   = (const float*)d_in[25];
  const float* bq   = (const float*)d_in[26];
  const float* wk   = (const float*)d_in[27];
  const float* bk   = (const float*)d_in[28];
  const float* wv   = (const float*)d_in[29];
  const float* bv   = (const float*)d_in[30];
  const float* wo   = (const float*)d_in[31];
  const float* bo   = (const float*)d_in[32];
  const float* f1w  = (const float*)d_in[33];
  const float* f1b  = (const float*)d_in[34];
  const float* f2w  = (const float*)d_in[35];
  const float* f2b  = (const float*)d_in[36];
  const float* g1   = (const float*)d_in[37];
  const float* be1  = (const float*)d_in[38];
  const float* g2   = (const float*)d_in[39];
  const float* be2  = (const float*)d_in[40];
  const float* clw  = (const float*)d_in[41];
  const float* clb  = (const float*)d_in[42];

  float* out = (float*)d_out;
  char* ws = (char*)d_ws;
  unsigned short* Amat = (unsigned short*)ws;                          // 2 MB (bf16, also fuse mat)
  float* mv  = (float*)(ws + (size_t)2*1024*1024);                     // 64 KB region
  float* wTp = (float*)(ws + (size_t)2*1024*1024 + 65536);             // 256 KB region
  unsigned short* wds = (unsigned short*)(ws + (size_t)2*1024*1024 + 65536 + 262144); // 192 KB region
  unsigned short* xw  = (unsigned short*)(ws + (size_t)3*1024*1024);   // 24 MB (bf16, also y2)
  unsigned short* xds = (unsigned short*)(ws + (size_t)28*1024*1024);  // 24 MB (bf16)

  k_wprep<<<64, 256, 0, stream>>>(wq, wk, wv, wo, f1w, f2w, gfsw, gluw, wTp);
  k_wprep3<<<96, 256, 0, stream>>>(wi, w1m, w1g, w2m, w2g, wfc, wds);
  // xw = GLU(gfs_fc(embed)) @ gc_weight -> bf16
  k_embed2<<<BNT/64, 256, 0, stream>>>(flow, day, week, semb, demb, wemb,
                                       wTp, gfsb, glub, gcw, xw);
  // combined adjacency (bf16)
  k_aprep<<<N_, 256, 0, stream>>>(gcA, gcA2, Amat);
  // xds = relu(A @ xw) -> bf16 (relu fused in epilogue)
  dim3 gg(TD/128, N_/128, B_);
  k_gemm_mfma<1,1><<<gg, 256, 0, stream>>>(Amat, xw, xds, N_, TD);
  // ds block (MFMA) -> d_out fp32
  k_ds3<<<BN_/8, 256, 0, stream>>>(xds, wds, bi, b1m, b1g, b2m, b2g, bfc, out);
  // y2 = attn+ffn block -> bf16 (reuse xw region)
  k_attn2<<<BN_/4, 256, 0, stream>>>(out, wTp, bq, bk, bv, bo, f1b, f2b,
                                     g1, be1, g2, be2, xw);
  // fuse matrix (bf16, reuse Amat region)
  k_mvec<<<N_/256, 256, 0, stream>>>(flow, clw, clb, mv);
  k_fusemat<<<(N_*N_)/256, 256, 0, stream>>>(mv, Amat);
  // out = fuse @ y2 -> d_out
  k_gemm_mfma<0,0><<<gg, 256, 0, stream>>>(Amat, xw, out, N_, TD);
}

// Round 6
// 403.784 us; speedup vs baseline: 16.0342x; 1.5827x over previous
//
#include <hip/hip_runtime.h>
#include <cstdint>

#define B_ 16
#define N_ 1024
#define T_ 12
#define HD 64
#define BN_ (B_*N_)     // 16384
#define BNT (B_*N_*T_)  // 196608
#define TD (T_*HD)      // 768

typedef __attribute__((ext_vector_type(8))) short short8;
typedef __attribute__((ext_vector_type(4))) float f32x4;

#define MFMA16(a,b,c) __builtin_amdgcn_mfma_f32_16x16x32_bf16(a,b,c,0,0,0)

__device__ __forceinline__ float sigmoidf_(float x) { return 1.f / (1.f + __expf(-x)); }

__device__ __forceinline__ unsigned short f2bf(float f) {
  unsigned int u = __float_as_uint(f);
  u += 0x7fffu + ((u >> 16) & 1u);   // round-to-nearest-even
  return (unsigned short)(u >> 16);
}
__device__ __forceinline__ float bf2f(unsigned short h) {
  unsigned int u = ((unsigned int)h) << 16;
  return __uint_as_float(u);
}

#define F4E(v, ii) ((ii)==0?(v).x:((ii)==1?(v).y:((ii)==2?(v).z:(v).w)))

// ---------------- reductions ----------------
__device__ __forceinline__ float blkRedMax(float v, float* red) {
  #pragma unroll
  for (int off = 32; off >= 1; off >>= 1) v = fmaxf(v, __shfl_xor(v, off));
  int w = threadIdx.x >> 6;
  if ((threadIdx.x & 63) == 0) red[w] = v;
  __syncthreads();
  v = fmaxf(fmaxf(red[0], red[1]), fmaxf(red[2], red[3]));
  __syncthreads();
  return v;
}
__device__ __forceinline__ float blkRedSum(float v, float* red) {
  #pragma unroll
  for (int off = 32; off >= 1; off >>= 1) v += __shfl_xor(v, off);
  int w = threadIdx.x >> 6;
  if ((threadIdx.x & 63) == 0) red[w] = v;
  __syncthreads();
  v = red[0] + red[1] + red[2] + red[3];
  __syncthreads();
  return v;
}

// ---------------- K-wprep-e: embed/glu weight transposes (fp32) ----------------
// wT: w1T[64][64]@0 | w2T[64][128]@4096
__global__ void k_wprep_e(const float* __restrict__ w1, const float* __restrict__ w2,
                          float* __restrict__ wT)
{
  int tid = blockIdx.x*256 + threadIdx.x;   // 48*256 = 12288
  if (tid < 4096) { int d = tid >> 6, j = tid & 63; wT[j*64 + d] = w1[tid]; }
  if (tid < 8192) { int o = tid >> 6, j = tid & 63; wT[4096 + j*128 + o] = w2[tid]; }
}

// ---------------- K-wprep3: bf16 tap-major conv weights for k_ds3 ----------------
__global__ void k_wprep3(const float* __restrict__ wi,
                         const float* __restrict__ w1m, const float* __restrict__ w1g,
                         const float* __restrict__ w2m, const float* __restrict__ w2g,
                         const float* __restrict__ wfc, unsigned short* __restrict__ W)
{
  int t = blockIdx.x*256 + threadIdx.x;  // 96*256 = 24576
  {
    int o = t / 192, k = t - o*192, tap = k >> 6, i = k & 63;
    W[o*192 + k] = f2bf(wi[(o*64 + i)*3 + tap]);
  }
  if (t < 12288) {
    int o = t / 192, k = t - o*192, tap = k >> 6, i = k & 63;
    int src = (o*64 + i)*3 + tap;
    W[24576 + o*192 + k]      = f2bf(w1m[src]);
    W[24576 + (64+o)*192 + k] = f2bf(w1g[src]);
    W[49152 + o*192 + k]      = f2bf(w2m[src]);
    W[49152 + (64+o)*192 + k] = f2bf(w2g[src]);
  }
  if (t < 8192) W[73728 + t] = f2bf(wfc[t]);
}

// ---------------- K-wprep4: bf16 cast of attn/ffn weights (natural layout) -------------
// W u16: Wqkv[192][64]@0 (q|k|v) | Wo[64][64]@12288 | F1[256][64]@16384 | F2[64][256]@32768
__global__ void k_wprep4(const float* __restrict__ wq, const float* __restrict__ wk,
                         const float* __restrict__ wv, const float* __restrict__ wo,
                         const float* __restrict__ f1w, const float* __restrict__ f2w,
                         unsigned short* __restrict__ W)
{
  int t = blockIdx.x*256 + threadIdx.x;  // 192*256 = 49152
  if (t < 4096)        W[t] = f2bf(wq[t]);
  else if (t < 8192)   W[t] = f2bf(wk[t-4096]);
  else if (t < 12288)  W[t] = f2bf(wv[t-8192]);
  else if (t < 16384)  W[t] = f2bf(wo[t-12288]);
  else if (t < 32768)  W[t] = f2bf(f1w[t-16384]);
  else                 W[t] = f2bf(f2w[t-32768]);
}

// ---------------- K1: embed + gfs_fc + GLU + (x @ gc_weight), ONE WAVE per 16 rows ----------
__global__ __launch_bounds__(256) void k_embed2(
    const float* __restrict__ flow, const int* __restrict__ day, const int* __restrict__ week,
    const float* __restrict__ semb, const float* __restrict__ demb, const float* __restrict__ wemb,
    const float* __restrict__ wT, const float* __restrict__ b1,
    const float* __restrict__ b2, const float* __restrict__ gcw,
    unsigned short* __restrict__ outw)
{
  __shared__ float4 vb_all[4][256];
  int lane = threadIdx.x & 63, wid = threadIdx.x >> 6;
  float4* vb = vb_all[wid];
  const float* w1T = wT;
  const float* w2T = wT + 4096;
  int row0 = (blockIdx.x*4 + wid) * 16;

  float x[16];
  #pragma unroll
  for (int r = 0; r < 16; ++r) {
    int row = row0 + r;
    int n = (row / T_) & (N_-1);
    int c = lane;
    float val;
    if (c == 0)      val = flow[row];
    else if (c < 33) val = semb[n*32 + (c-1)];
    else if (c < 49) val = demb[day[row]*16 + (c-33)];
    else             val = wemb[week[row]*15 + (c-49)];
    x[r] = val;
  }
  #pragma unroll
  for (int q = 0; q < 4; ++q)
    vb[lane*4 + q] = make_float4(x[4*q], x[4*q+1], x[4*q+2], x[4*q+3]);

  float acc[16];
  {
    float bv = b1[lane];
    #pragma unroll
    for (int r = 0; r < 16; ++r) acc[r] = bv;
    for (int j = 0; j < 64; ++j) {
      float w = w1T[j*64 + lane];
      #pragma unroll
      for (int q = 0; q < 4; ++q) {
        float4 v = vb[j*4 + q];
        acc[4*q]   += w*v.x; acc[4*q+1] += w*v.y;
        acc[4*q+2] += w*v.z; acc[4*q+3] += w*v.w;
      }
    }
  }
  #pragma unroll
  for (int q = 0; q < 4; ++q)
    vb[lane*4 + q] = make_float4(acc[4*q], acc[4*q+1], acc[4*q+2], acc[4*q+3]);

  float lo[16], hi[16];
  {
    float blo = b2[lane], bhi = b2[64 + lane];
    #pragma unroll
    for (int r = 0; r < 16; ++r) { lo[r] = blo; hi[r] = bhi; }
    for (int j = 0; j < 64; ++j) {
      float wl = w2T[j*128 + lane];
      float wh = w2T[j*128 + 64 + lane];
      #pragma unroll
      for (int q = 0; q < 4; ++q) {
        float4 v = vb[j*4 + q];
        lo[4*q]   += wl*v.x; lo[4*q+1] += wl*v.y; lo[4*q+2] += wl*v.z; lo[4*q+3] += wl*v.w;
        hi[4*q]   += wh*v.x; hi[4*q+1] += wh*v.y; hi[4*q+2] += wh*v.z; hi[4*q+3] += wh*v.w;
      }
    }
    #pragma unroll
    for (int r = 0; r < 16; ++r) lo[r] = lo[r] * sigmoidf_(hi[r]);
  }
  #pragma unroll
  for (int q = 0; q < 4; ++q)
    vb[lane*4 + q] = make_float4(lo[4*q], lo[4*q+1], lo[4*q+2], lo[4*q+3]);

  {
    #pragma unroll
    for (int r = 0; r < 16; ++r) acc[r] = 0.f;
    for (int j = 0; j < 64; ++j) {
      float w = gcw[j*64 + lane];
      #pragma unroll
      for (int q = 0; q < 4; ++q) {
        float4 v = vb[j*4 + q];
        acc[4*q]   += w*v.x; acc[4*q+1] += w*v.y;
        acc[4*q+2] += w*v.z; acc[4*q+3] += w*v.w;
      }
    }
    #pragma unroll
    for (int r = 0; r < 16; ++r)
      outw[(size_t)(row0 + r)*64 + lane] = f2bf(acc[r]);
  }
}

// ---------------- K2: A = softmax(relu(A1),1) + softmax(relu(A2),1), bf16 out ------------
__global__ __launch_bounds__(256) void k_aprep(
    const float* __restrict__ A1, const float* __restrict__ A2, unsigned short* __restrict__ Aout)
{
  __shared__ float red[4];
  int m = blockIdx.x, tid = threadIdx.x;
  float mx0, is0, mx1, is1;
  {
    const float* src = A1 + (size_t)m*N_;
    float mx = 0.f;
    for (int i = tid; i < N_; i += 256) mx = fmaxf(mx, fmaxf(src[i], 0.f));
    mx = blkRedMax(mx, red);
    float s = 0.f;
    for (int i = tid; i < N_; i += 256) s += __expf(fmaxf(src[i], 0.f) - mx);
    s = blkRedSum(s, red);
    mx0 = mx; is0 = 1.f / s;
  }
  {
    const float* src = A2 + (size_t)m*N_;
    float mx = 0.f;
    for (int i = tid; i < N_; i += 256) mx = fmaxf(mx, fmaxf(src[i], 0.f));
    mx = blkRedMax(mx, red);
    float s = 0.f;
    for (int i = tid; i < N_; i += 256) s += __expf(fmaxf(src[i], 0.f) - mx);
    s = blkRedSum(s, red);
    mx1 = mx; is1 = 1.f / s;
  }
  const float* s1 = A1 + (size_t)m*N_;
  const float* s2 = A2 + (size_t)m*N_;
  for (int i = tid; i < N_; i += 256) {
    float v1 = __expf(fmaxf(s1[i], 0.f) - mx0) * is0;
    float v2 = __expf(fmaxf(s2[i], 0.f) - mx1) * is1;
    Aout[(size_t)m*N_ + i] = f2bf(v1 + v2);
  }
}

// ---------------- K3: bf16 MFMA batched GEMM ----------------
template<int RELU, int OB16>
__global__ __launch_bounds__(256) void k_gemm_mfma(
    const unsigned short* __restrict__ A, const unsigned short* __restrict__ X,
    void* __restrict__ C, int K, int P)
{
  __shared__ unsigned short sA[128*40];
  __shared__ unsigned short sB[128*40];
  int tid = threadIdx.x, lane = tid & 63, wid = tid >> 6;
  int M = gridDim.y * 128;
  int b = blockIdx.z;
  const unsigned short* Xb = X + (size_t)b*K*P;
  int m0 = blockIdx.y*128, p0 = blockIdx.x*128;
  int wr = wid >> 1, wc = wid & 1;

  f32x4 acc[4][4] = {};

  for (int k0 = 0; k0 < K; k0 += 32) {
    #pragma unroll
    for (int pass = 0; pass < 2; ++pass) {
      int r = (tid >> 2) + 64*pass, kk = (tid & 3)*8;
      short8 v = *(const short8*)&A[(size_t)(m0+r)*K + k0 + kk];
      *(short8*)&sA[r*40 + kk] = v;
    }
    #pragma unroll
    for (int pass = 0; pass < 4; ++pass) {
      int p  = (tid & 63) + 64*(pass & 1);
      int k4 = (tid >> 6)*4 + 16*(pass >> 1);
      ushort4 h;
      h.x = Xb[(size_t)(k0+k4+0)*P + p0 + p];
      h.y = Xb[(size_t)(k0+k4+1)*P + p0 + p];
      h.z = Xb[(size_t)(k0+k4+2)*P + p0 + p];
      h.w = Xb[(size_t)(k0+k4+3)*P + p0 + p];
      *(ushort4*)&sB[p*40 + k4] = h;
    }
    __syncthreads();
    short8 af[4], bf[4];
    #pragma unroll
    for (int f = 0; f < 4; ++f) {
      af[f] = *(const short8*)&sA[(wr*64 + f*16 + (lane & 15))*40 + (lane >> 4)*8];
      bf[f] = *(const short8*)&sB[(wc*64 + f*16 + (lane & 15))*40 + (lane >> 4)*8];
    }
    #pragma unroll
    for (int fm = 0; fm < 4; ++fm)
      #pragma unroll
      for (int fn = 0; fn < 4; ++fn)
        acc[fm][fn] = MFMA16(af[fm], bf[fn], acc[fm][fn]);
    __syncthreads();
  }
  #pragma unroll
  for (int fm = 0; fm < 4; ++fm) {
    int row = m0 + wr*64 + fm*16 + (lane >> 4)*4;
    #pragma unroll
    for (int fn = 0; fn < 4; ++fn) {
      int col = p0 + wc*64 + fn*16 + (lane & 15);
      #pragma unroll
      for (int r = 0; r < 4; ++r) {
        float v = acc[fm][fn][r];
        if (RELU) v = fmaxf(v, 0.f);
        if (OB16) {
          unsigned short* Cb = (unsigned short*)C + (size_t)b*M*P;
          Cb[(size_t)(row + r)*P + col] = f2bf(v);
        } else {
          float* Cb = (float*)C + (size_t)b*M*P;
          Cb[(size_t)(row + r)*P + col] = v;
        }
      }
    }
  }
}

// ---------------- K5: ds temporal-conv block, MFMA, 8 bn per block ----------------
__global__ __launch_bounds__(256) void k_ds3(
    const unsigned short* __restrict__ xds,
    const unsigned short* __restrict__ Wall,
    const float* __restrict__ bi,
    const float* __restrict__ b1m, const float* __restrict__ b1g,
    const float* __restrict__ b2m, const float* __restrict__ b2g,
    const float* __restrict__ bfc,
    float* __restrict__ outg)
{
  __shared__ unsigned short smem[36352];
  unsigned short* X_lds  = smem;               // [8][14][72]
  unsigned short* xi_lds = smem + 8064;        // [8][14][136]
  unsigned short* fu_lds = smem + 23296;       // [96][136]
  const unsigned short* WiB  = Wall;
  const unsigned short* Wg1B = Wall + 24576;
  const unsigned short* Wg2B = Wall + 49152;
  const unsigned short* WfB  = Wall + 73728;

  int tid = threadIdx.x, lane = tid & 63, wid = tid >> 6;
  int l15 = lane & 15, l4 = lane >> 4;
  int bn0 = blockIdx.x * 8;

  for (int i = tid; i < 8*2*72; i += 256) {
    int g = i / 144, r = i - g*144;
    int tp = (r < 72) ? 0 : 13, c = (r < 72) ? r : r - 72;
    X_lds[(g*14 + tp)*72 + c] = 0;
  }
  for (int i = tid; i < 8*2*136; i += 256) {
    int g = i / 272, r = i - g*272;
    int tp = (r < 136) ? 0 : 13, c = (r < 136) ? r : r - 136;
    xi_lds[(g*14 + tp)*136 + c] = 0;
  }
  for (int i = tid; i < 768; i += 256) {
    int g = i / 96, rem = i - g*96, t = rem >> 3, i8 = rem & 7;
    short8 v = *(const short8*)&xds[(size_t)(bn0+g)*768 + t*64 + i8*8];
    *(short8*)&X_lds[(g*14 + t + 1)*72 + i8*8] = v;
  }
  __syncthreads();

  int ga[6], ta[6];
  #pragma unroll
  for (int mt = 0; mt < 6; ++mt) {
    int r = mt*16 + l15;
    ga[mt] = r / 12; ta[mt] = r - ga[mt]*12;
  }

  {
    f32x4 acc1[6][2] = {};
    int nb = wid*2;
    #pragma unroll
    for (int ks = 0; ks < 6; ++ks) {
      int tap = ks >> 1, i0 = (ks & 1)*32;
      short8 af[6];
      #pragma unroll
      for (int mt = 0; mt < 6; ++mt)
        af[mt] = *(const short8*)&X_lds[(ga[mt]*14 + ta[mt] + tap)*72 + i0 + l4*8];
      short8 bf0 = *(const short8*)&WiB[(size_t)((nb  )*16 + l15)*192 + ks*32 + l4*8];
      short8 bf1 = *(const short8*)&WiB[(size_t)((nb+1)*16 + l15)*192 + ks*32 + l4*8];
      #pragma unroll
      for (int mt = 0; mt < 6; ++mt) {
        acc1[mt][0] = MFMA16(af[mt], bf0, acc1[mt][0]);
        acc1[mt][1] = MFMA16(af[mt], bf1, acc1[mt][1]);
      }
    }
    #pragma unroll
    for (int nn = 0; nn < 2; ++nn) {
      int o = (nb+nn)*16 + l15;
      float bv = bi[o];
      #pragma unroll
      for (int mt = 0; mt < 6; ++mt) {
        #pragma unroll
        for (int reg = 0; reg < 4; ++reg) {
          int r = mt*16 + l4*4 + reg;
          int g = r / 12, t = r - g*12;
          xi_lds[(g*14 + t + 1)*136 + o] = f2bf(acc1[mt][nn][reg] + bv);
        }
      }
    }
  }
  __syncthreads();

  #pragma unroll
  for (int h = 0; h < 2; ++h) {
    const unsigned short* Wg = h ? Wg2B : Wg1B;
    f32x4 am[6] = {}, ag[6] = {};
    #pragma unroll
    for (int ks = 0; ks < 6; ++ks) {
      int tap = ks >> 1, i0 = (ks & 1)*32;
      short8 af[6];
      #pragma unroll
      for (int mt = 0; mt < 6; ++mt)
        af[mt] = *(const short8*)&xi_lds[(ga[mt]*14 + ta[mt] + tap)*136 + h*64 + i0 + l4*8];
      short8 bm = *(const short8*)&Wg[(size_t)(wid*16 + l15)*192 + ks*32 + l4*8];
      short8 bg = *(const short8*)&Wg[(size_t)((wid+4)*16 + l15)*192 + ks*32 + l4*8];
      #pragma unroll
      for (int mt = 0; mt < 6; ++mt) {
        am[mt] = MFMA16(af[mt], bm, am[mt]);
        ag[mt] = MFMA16(af[mt], bg, ag[mt]);
      }
    }
    int o = wid*16 + l15;
    float bmv = (h ? b2m : b1m)[o];
    float bgv = (h ? b2g : b1g)[o];
    #pragma unroll
    for (int mt = 0; mt < 6; ++mt) {
      #pragma unroll
      for (int reg = 0; reg < 4; ++reg) {
        int r = mt*16 + l4*4 + reg;
        int g = r / 12, t = r - g*12;
        float pm = am[mt][reg] + bmv;
        float pg = ag[mt][reg] + bgv;
        float po = pm * sigmoidf_(pg);
        float xi = bf2f(xi_lds[(g*14 + t + 1)*136 + h*64 + o]);
        fu_lds[r*136 + h*64 + o] = f2bf(fmaxf(po + xi, 0.f));
      }
    }
  }
  __syncthreads();

  {
    f32x4 a3[6] = {};
    #pragma unroll
    for (int ks = 0; ks < 4; ++ks) {
      short8 af = *(const short8*)&WfB[(size_t)(wid*16 + l15)*128 + ks*32 + l4*8];
      #pragma unroll
      for (int nt = 0; nt < 6; ++nt) {
        short8 bf = *(const short8*)&fu_lds[(nt*16 + l15)*136 + ks*32 + l4*8];
        a3[nt] = MFMA16(af, bf, a3[nt]);
      }
    }
    int e0 = wid*16 + l4*4;
    float4 bb = *(const float4*)&bfc[e0];
    #pragma unroll
    for (int nt = 0; nt < 6; ++nt) {
      float4 vv = make_float4(a3[nt][0] + bb.x, a3[nt][1] + bb.y,
                              a3[nt][2] + bb.z, a3[nt][3] + bb.w);
      *(float4*)&outg[((size_t)(bn0 + ga[nt])*12 + ta[nt])*64 + e0] = vv;
    }
  }
}

// ---------------- K6: attention + FFN + 2x LN, full MFMA, 4 bn per block --------------
// LDS: Ybuf[48][80] (y->o->y1 bf16) | R2: Qkv[52][216] then h[48][280] | att_s[4][16][24]
__global__ __launch_bounds__(256) void k_attn3(
    const float* __restrict__ xg,
    const unsigned short* __restrict__ Wat,
    const float* __restrict__ bq, const float* __restrict__ bk, const float* __restrict__ bv,
    const float* __restrict__ bo,
    const float* __restrict__ f1b, const float* __restrict__ f2b,
    const float* __restrict__ g1, const float* __restrict__ be1,
    const float* __restrict__ g2, const float* __restrict__ be2,
    unsigned short* __restrict__ outg)
{
  __shared__ unsigned short su[18816];
  __shared__ float part[2][4][48];
  __shared__ float stats[2][48];
  unsigned short* Ybuf = su;           // [48][80]
  unsigned short* Qkv  = su + 3840;    // [52][216]
  unsigned short* Hb   = su + 3840;    // [48][280] (union with Qkv)
  unsigned short* atts = su + 17280;   // [4][16][24]

  const unsigned short* Wqkv = Wat;
  const unsigned short* Wo   = Wat + 12288;
  const unsigned short* F1   = Wat + 16384;
  const unsigned short* F2   = Wat + 32768;

  int tid = threadIdx.x, lane = tid & 63, w = tid >> 6;
  int l15 = lane & 15, l4 = lane >> 4;
  size_t base = (size_t)blockIdx.x * 4 * 768;

  // stage y -> bf16
  for (int i = tid; i < 3072; i += 256) {
    int r = i >> 6, c = i & 63;
    Ybuf[r*80 + c] = f2bf(xg[base + i]);
  }
  __syncthreads();

  // ---- QKV GEMM: Qkv[48][192] ----
  {
    f32x4 acc[3][3] = {};
    #pragma unroll
    for (int ks = 0; ks < 2; ++ks) {
      short8 af[3];
      #pragma unroll
      for (int mt = 0; mt < 3; ++mt)
        af[mt] = *(const short8*)&Ybuf[(mt*16 + l15)*80 + ks*32 + l4*8];
      #pragma unroll
      for (int i = 0; i < 3; ++i) {
        int nt = w*3 + i;
        short8 bf = *(const short8*)&Wqkv[(size_t)(nt*16 + l15)*64 + ks*32 + l4*8];
        #pragma unroll
        for (int mt = 0; mt < 3; ++mt)
          acc[mt][i] = MFMA16(af[mt], bf, acc[mt][i]);
      }
    }
    #pragma unroll
    for (int i = 0; i < 3; ++i) {
      int col = (w*3+i)*16 + l15;
      float bias = col < 64 ? bq[col] : (col < 128 ? bk[col-64] : bv[col-128]);
      #pragma unroll
      for (int mt = 0; mt < 3; ++mt)
        #pragma unroll
        for (int r = 0; r < 4; ++r)
          Qkv[(mt*16 + l4*4 + r)*216 + col] = f2bf(acc[mt][i][r] + bias);
    }
  }
  __syncthreads();

  // ---- attention: wave w owns bn w (scoresT = mfma(K,Q); PV via attn-frag chain) ----
  {
    int rb = w*12;
    unsigned short* as = atts + w*384;   // [16][24]
    #pragma unroll
    for (int h = 0; h < 4; ++h) {
      short8 kf = {}, qf = {};
      if (l4 < 2) {
        kf = *(const short8*)&Qkv[(rb + l15)*216 + 64 + h*16 + l4*8];
        qf = *(const short8*)&Qkv[(rb + l15)*216 +      h*16 + l4*8];
      }
      f32x4 sc = {};
      sc = MFMA16(kf, qf, sc);
      float e[4]; float mx = -3e38f;
      #pragma unroll
      for (int r = 0; r < 4; ++r) {
        float v = (l4 == 3) ? -3e38f : sc[r]*0.25f;
        e[r] = v; mx = fmaxf(mx, v);
      }
      mx = fmaxf(mx, __shfl_xor(mx, 16));
      mx = fmaxf(mx, __shfl_xor(mx, 32));
      float s = 0.f;
      #pragma unroll
      for (int r = 0; r < 4; ++r) { e[r] = __expf(e[r] - mx); s += e[r]; }
      s += __shfl_xor(s, 16); s += __shfl_xor(s, 32);
      float inv = 1.f/s;
      ushort4 pk;
      pk.x = f2bf(e[0]*inv); pk.y = f2bf(e[1]*inv);
      pk.z = f2bf(e[2]*inv); pk.w = f2bf(e[3]*inv);
      *(ushort4*)&as[l15*24 + l4*4] = pk;        // attn[l][s], in-order DS per wave
      short8 aaf = {};
      if (l4 < 2) aaf = *(const short8*)&as[l15*24 + l4*8];
      short8 vf = {};
      if (l4 < 2) {
        #pragma unroll
        for (int j = 0; j < 8; ++j) {
          int s_ = l4*8 + j;
          vf[j] = (s_ < 12) ? (short)Qkv[(rb + s_)*216 + 128 + h*16 + l15] : (short)0;
        }
      }
      f32x4 o = {};
      o = MFMA16(aaf, vf, o);
      if (l4 < 3) {
        #pragma unroll
        for (int r = 0; r < 4; ++r)
          Ybuf[(rb + l4*4 + r)*80 + h*16 + l15] = f2bf(o[r]);
      }
    }
  }
  __syncthreads();

  // ---- WO GEMM + residual + LN1 (stats in regs/partials) ----
  {
    f32x4 zacc[3] = {};
    #pragma unroll
    for (int ks = 0; ks < 2; ++ks) {
      short8 bf = *(const short8*)&Wo[(size_t)(w*16 + l15)*64 + ks*32 + l4*8];
      #pragma unroll
      for (int mt = 0; mt < 3; ++mt) {
        short8 af = *(const short8*)&Ybuf[(mt*16 + l15)*80 + ks*32 + l4*8];
        zacc[mt] = MFMA16(af, bf, zacc[mt]);
      }
    }
    int col = w*16 + l15;
    float bias = bo[col];
    #pragma unroll
    for (int mt = 0; mt < 3; ++mt)
      #pragma unroll
      for (int r = 0; r < 4; ++r) {
        int row = mt*16 + l4*4 + r;
        float z = zacc[mt][r] + bias + xg[base + row*64 + col];
        zacc[mt][r] = z;
        float s1 = z, s2 = z*z;
        #pragma unroll
        for (int off = 1; off <= 8; off <<= 1) { s1 += __shfl_xor(s1, off); s2 += __shfl_xor(s2, off); }
        if (l15 == 0) { part[0][w][row] = s1; part[1][w][row] = s2; }
      }
    __syncthreads();
    if (tid < 48) {
      float s = part[0][0][tid]+part[0][1][tid]+part[0][2][tid]+part[0][3][tid];
      float q = part[1][0][tid]+part[1][1][tid]+part[1][2][tid]+part[1][3][tid];
      float mu = s * (1.f/64.f);
      float var = q * (1.f/64.f) - mu*mu;
      stats[0][tid] = mu; stats[1][tid] = rsqrtf(var + 1e-5f);
    }
    __syncthreads();
    float gv = g1[col], bvv = be1[col];
    #pragma unroll
    for (int mt = 0; mt < 3; ++mt)
      #pragma unroll
      for (int r = 0; r < 4; ++r) {
        int row = mt*16 + l4*4 + r;
        Ybuf[row*80 + col] = f2bf((zacc[mt][r] - stats[0][row]) * stats[1][row] * gv + bvv);
      }
  }
  __syncthreads();

  // ---- FF1: h[48][256] = relu(y1 @ F1^T) ----
  {
    f32x4 acc[3][4] = {};
    #pragma unroll
    for (int ks = 0; ks < 2; ++ks) {
      short8 af[3];
      #pragma unroll
      for (int mt = 0; mt < 3; ++mt)
        af[mt] = *(const short8*)&Ybuf[(mt*16 + l15)*80 + ks*32 + l4*8];
      #pragma unroll
      for (int i = 0; i < 4; ++i) {
        int nt = w*4 + i;
        short8 bf = *(const short8*)&F1[(size_t)(nt*16 + l15)*64 + ks*32 + l4*8];
        #pragma unroll
        for (int mt = 0; mt < 3; ++mt)
          acc[mt][i] = MFMA16(af[mt], bf, acc[mt][i]);
      }
    }
    #pragma unroll
    for (int i = 0; i < 4; ++i) {
      int col = (w*4+i)*16 + l15;
      float bias = f1b[col];
      #pragma unroll
      for (int mt = 0; mt < 3; ++mt)
        #pragma unroll
        for (int r = 0; r < 4; ++r)
          Hb[(mt*16 + l4*4 + r)*280 + col] = f2bf(fmaxf(acc[mt][i][r] + bias, 0.f));
    }
  }
  __syncthreads();

  // ---- FF2 + residual + LN2 + store y2 bf16 ----
  {
    f32x4 acc[3] = {};
    #pragma unroll
    for (int ks = 0; ks < 8; ++ks) {
      short8 bf = *(const short8*)&F2[(size_t)(w*16 + l15)*256 + ks*32 + l4*8];
      #pragma unroll
      for (int mt = 0; mt < 3; ++mt) {
        short8 af = *(const short8*)&Hb[(mt*16 + l15)*280 + ks*32 + l4*8];
        acc[mt] = MFMA16(af, bf, acc[mt]);
      }
    }
    int col = w*16 + l15;
    float bias = f2b[col];
    #pragma unroll
    for (int mt = 0; mt < 3; ++mt)
      #pragma unroll
      for (int r = 0; r < 4; ++r) {
        int row = mt*16 + l4*4 + r;
        float z = acc[mt][r] + bias + bf2f(Ybuf[row*80 + col]);
        acc[mt][r] = z;
        float s1 = z, s2 = z*z;
        #pragma unroll
        for (int off = 1; off <= 8; off <<= 1) { s1 += __shfl_xor(s1, off); s2 += __shfl_xor(s2, off); }
        if (l15 == 0) { part[0][w][row] = s1; part[1][w][row] = s2; }
      }
    __syncthreads();
    if (tid < 48) {
      float s = part[0][0][tid]+part[0][1][tid]+part[0][2][tid]+part[0][3][tid];
      float q = part[1][0][tid]+part[1][1][tid]+part[1][2][tid]+part[1][3][tid];
      float mu = s * (1.f/64.f);
      float var = q * (1.f/64.f) - mu*mu;
      stats[0][tid] = mu; stats[1][tid] = rsqrtf(var + 1e-5f);
    }
    __syncthreads();
    float gv = g2[col], bvv = be2[col];
    #pragma unroll
    for (int mt = 0; mt < 3; ++mt)
      #pragma unroll
      for (int r = 0; r < 4; ++r) {
        int row = mt*16 + l4*4 + r;
        outg[base + row*64 + col] = f2bf((acc[mt][r] - stats[0][row]) * stats[1][row] * gv + bvv);
      }
  }
}

// ---------------- K7: fuse-matrix prep ----------------
__global__ void k_mvec(const float* __restrict__ flow, const float* __restrict__ clw,
                       const float* __restrict__ clb, float* __restrict__ mv)
{
  int n = blockIdx.x*blockDim.x + threadIdx.x;
  if (n < N_) {
    float s = 0.f;
    float bias = clb[0];
    for (int b = 0; b < B_; ++b) {
      const float* f = flow + ((size_t)b*N_ + n)*T_;
      float acc = bias;
      #pragma unroll
      for (int t = 0; t < T_; ++t) acc += f[t]*clw[t];
      s += fmaxf(acc, 0.f);
    }
    mv[n] = s * (1.f/16.f);
  }
}

__global__ void k_fusemat(const float* __restrict__ mv, unsigned short* __restrict__ F)
{
  int idx = blockIdx.x*256 + threadIdx.x;
  int m = idx >> 10, n = idx & 1023;
  float x = 0.5f*(mv[m] + mv[n]);
  F[idx] = f2bf(1.f/(1.f + __expf(-x)));
}

// ---------------- launch ----------------
extern "C" void kernel_launch(void* const* d_in, const int* in_sizes, int n_in,
                              void* d_out, int out_size, void* d_ws, size_t ws_size,
                              hipStream_t stream)
{
  const float* flow = (const float*)d_in[0];
  const int*   day  = (const int*)d_in[1];
  const int*   week = (const int*)d_in[2];
  const float* semb = (const float*)d_in[3];
  const float* demb = (const float*)d_in[4];
  const float* wemb = (const float*)d_in[5];
  const float* gfsw = (const float*)d_in[6];
  const float* gfsb = (const float*)d_in[7];
  const float* gluw = (const float*)d_in[8];
  const float* glub = (const float*)d_in[9];
  const float* gcw  = (const float*)d_in[10];
  const float* gcA  = (const float*)d_in[11];
  const float* gcA2 = (const float*)d_in[12];
  const float* wi   = (const float*)d_in[13];
  const float* bi   = (const float*)d_in[14];
  const float* w1m  = (const float*)d_in[15];
  const float* b1m  = (const float*)d_in[16];
  const float* w1g  = (const float*)d_in[17];
  const float* b1g  = (const float*)d_in[18];
  const float* w2m  = (const float*)d_in[19];
  const float* b2m  = (const float*)d_in[20];
  const float* w2g  = (const float*)d_in[21];
  const float* b2g  = (const float*)d_in[22];
  const float* wfc  = (const float*)d_in[23];
  const float* bfc  = (const float*)d_in[24];
  const float* wq   = (const float*)d_in[25];
  const float* bq   = (const float*)d_in[26];
  const float* wk   = (const float*)d_in[27];
  const float* bk   = (const float*)d_in[28];
  const float* wv   = (const float*)d_in[29];
  const float* bv   = (const float*)d_in[30];
  const float* wo   = (const float*)d_in[31];
  const float* bo   = (const float*)d_in[32];
  const float* f1w  = (const float*)d_in[33];
  const float* f1b  = (const float*)d_in[34];
  const float* f2w  = (const float*)d_in[35];
  const float* f2b  = (const float*)d_in[36];
  const float* g1   = (const float*)d_in[37];
  const float* be1  = (const float*)d_in[38];
  const float* g2   = (const float*)d_in[39];
  const float* be2  = (const float*)d_in[40];
  const float* clw  = (const float*)d_in[41];
  const float* clb  = (const float*)d_in[42];

  float* out = (float*)d_out;
  char* ws = (char*)d_ws;
  unsigned short* Amat = (unsigned short*)ws;                               // 2 MB
  float* mv  = (float*)(ws + (size_t)2*1024*1024);                          // 64 KB region
  float* wTe = (float*)(ws + (size_t)2*1024*1024 + 64*1024);                // 64 KB region
  unsigned short* wds = (unsigned short*)(ws + (size_t)2*1024*1024 + 128*1024); // 192 KB region
  unsigned short* wat = (unsigned short*)(ws + (size_t)2*1024*1024 + 320*1024); // 128 KB region
  unsigned short* xw  = (unsigned short*)(ws + (size_t)3*1024*1024);        // 24 MB
  unsigned short* xds = (unsigned short*)(ws + (size_t)28*1024*1024);       // 24 MB

  k_wprep_e<<<48, 256, 0, stream>>>(gfsw, gluw, wTe);
  k_wprep3<<<96, 256, 0, stream>>>(wi, w1m, w1g, w2m, w2g, wfc, wds);
  k_wprep4<<<192, 256, 0, stream>>>(wq, wk, wv, wo, f1w, f2w, wat);
  // xw = GLU(gfs_fc(embed)) @ gc_weight -> bf16
  k_embed2<<<BNT/64, 256, 0, stream>>>(flow, day, week, semb, demb, wemb,
                                       wTe, gfsb, glub, gcw, xw);
  // combined adjacency (bf16)
  k_aprep<<<N_, 256, 0, stream>>>(gcA, gcA2, Amat);
  // xds = relu(A @ xw) -> bf16
  dim3 gg(TD/128, N_/128, B_);
  k_gemm_mfma<1,1><<<gg, 256, 0, stream>>>(Amat, xw, xds, N_, TD);
  // ds block (MFMA) -> d_out fp32
  k_ds3<<<BN_/8, 256, 0, stream>>>(xds, wds, bi, b1m, b1g, b2m, b2g, bfc, out);
  // y2 = attn+ffn block (MFMA) -> bf16 (reuse xw region)
  k_attn3<<<BN_/4, 256, 0, stream>>>(out, wat, bq, bk, bv, bo, f1b, f2b,
                                     g1, be1, g2, be2, xw);
  // fuse matrix (bf16, reuse Amat region)
  k_mvec<<<N_/256, 256, 0, stream>>>(flow, clw, clb, mv);
  k_fusemat<<<(N_*N_)/256, 256, 0, stream>>>(mv, Amat);
  // out = fuse @ y2 -> d_out
  k_gemm_mfma<0,0><<<gg, 256, 0, stream>>>(Amat, xw, out, N_, TD);
}

// Round 7
// 386.559 us; speedup vs baseline: 16.7486x; 1.0446x over previous
//
#include <hip/hip_runtime.h>
#include <cstdint>

#define B_ 16
#define N_ 1024
#define T_ 12
#define HD 64
#define BN_ (B_*N_)     // 16384
#define BNT (B_*N_*T_)  // 196608
#define TD (T_*HD)      // 768

typedef __attribute__((ext_vector_type(8))) short short8;
typedef __attribute__((ext_vector_type(4))) float f32x4;

#define MFMA16(a,b,c) __builtin_amdgcn_mfma_f32_16x16x32_bf16(a,b,c,0,0,0)

__device__ __forceinline__ float sigmoidf_(float x) { return 1.f / (1.f + __expf(-x)); }

__device__ __forceinline__ unsigned short f2bf(float f) {
  unsigned int u = __float_as_uint(f);
  u += 0x7fffu + ((u >> 16) & 1u);   // round-to-nearest-even
  return (unsigned short)(u >> 16);
}
__device__ __forceinline__ float bf2f(unsigned short h) {
  unsigned int u = ((unsigned int)h) << 16;
  return __uint_as_float(u);
}

#define F4E(v, ii) ((ii)==0?(v).x:((ii)==1?(v).y:((ii)==2?(v).z:(v).w)))

// ---------------- reductions ----------------
__device__ __forceinline__ float blkRedMax(float v, float* red) {
  #pragma unroll
  for (int off = 32; off >= 1; off >>= 1) v = fmaxf(v, __shfl_xor(v, off));
  int w = threadIdx.x >> 6;
  if ((threadIdx.x & 63) == 0) red[w] = v;
  __syncthreads();
  v = fmaxf(fmaxf(red[0], red[1]), fmaxf(red[2], red[3]));
  __syncthreads();
  return v;
}
__device__ __forceinline__ float blkRedSum(float v, float* red) {
  #pragma unroll
  for (int off = 32; off >= 1; off >>= 1) v += __shfl_xor(v, off);
  int w = threadIdx.x >> 6;
  if ((threadIdx.x & 63) == 0) red[w] = v;
  __syncthreads();
  v = red[0] + red[1] + red[2] + red[3];
  __syncthreads();
  return v;
}

// ---------------- K-wprep-e: embed/glu weight transposes (fp32) ----------------
__global__ void k_wprep_e(const float* __restrict__ w1, const float* __restrict__ w2,
                          float* __restrict__ wT)
{
  int tid = blockIdx.x*256 + threadIdx.x;   // 48*256 = 12288
  if (tid < 4096) { int d = tid >> 6, j = tid & 63; wT[j*64 + d] = w1[tid]; }
  if (tid < 8192) { int o = tid >> 6, j = tid & 63; wT[4096 + j*128 + o] = w2[tid]; }
}

// ---------------- K-wprep3: bf16 tap-major conv weights for k_ds3 ----------------
__global__ void k_wprep3(const float* __restrict__ wi,
                         const float* __restrict__ w1m, const float* __restrict__ w1g,
                         const float* __restrict__ w2m, const float* __restrict__ w2g,
                         const float* __restrict__ wfc, unsigned short* __restrict__ W)
{
  int t = blockIdx.x*256 + threadIdx.x;  // 96*256 = 24576
  {
    int o = t / 192, k = t - o*192, tap = k >> 6, i = k & 63;
    W[o*192 + k] = f2bf(wi[(o*64 + i)*3 + tap]);
  }
  if (t < 12288) {
    int o = t / 192, k = t - o*192, tap = k >> 6, i = k & 63;
    int src = (o*64 + i)*3 + tap;
    W[24576 + o*192 + k]      = f2bf(w1m[src]);
    W[24576 + (64+o)*192 + k] = f2bf(w1g[src]);
    W[49152 + o*192 + k]      = f2bf(w2m[src]);
    W[49152 + (64+o)*192 + k] = f2bf(w2g[src]);
  }
  if (t < 8192) W[73728 + t] = f2bf(wfc[t]);
}

// ---------------- K-wprep4: bf16 cast of attn/ffn weights (natural layout) -------------
__global__ void k_wprep4(const float* __restrict__ wq, const float* __restrict__ wk,
                         const float* __restrict__ wv, const float* __restrict__ wo,
                         const float* __restrict__ f1w, const float* __restrict__ f2w,
                         unsigned short* __restrict__ W)
{
  int t = blockIdx.x*256 + threadIdx.x;  // 192*256 = 49152
  if (t < 4096)        W[t] = f2bf(wq[t]);
  else if (t < 8192)   W[t] = f2bf(wk[t-4096]);
  else if (t < 12288)  W[t] = f2bf(wv[t-8192]);
  else if (t < 16384)  W[t] = f2bf(wo[t-12288]);
  else if (t < 32768)  W[t] = f2bf(f1w[t-16384]);
  else                 W[t] = f2bf(f2w[t-32768]);
}

// ---------------- K1: embed + gfs_fc + GLU + (x @ gc_weight), ONE WAVE per 16 rows ----------
__global__ __launch_bounds__(256) void k_embed2(
    const float* __restrict__ flow, const int* __restrict__ day, const int* __restrict__ week,
    const float* __restrict__ semb, const float* __restrict__ demb, const float* __restrict__ wemb,
    const float* __restrict__ wT, const float* __restrict__ b1,
    const float* __restrict__ b2, const float* __restrict__ gcw,
    unsigned short* __restrict__ outw)
{
  __shared__ float4 vb_all[4][256];
  int lane = threadIdx.x & 63, wid = threadIdx.x >> 6;
  float4* vb = vb_all[wid];
  const float* w1T = wT;
  const float* w2T = wT + 4096;
  int row0 = (blockIdx.x*4 + wid) * 16;

  float x[16];
  #pragma unroll
  for (int r = 0; r < 16; ++r) {
    int row = row0 + r;
    int n = (row / T_) & (N_-1);
    int c = lane;
    float val;
    if (c == 0)      val = flow[row];
    else if (c < 33) val = semb[n*32 + (c-1)];
    else if (c < 49) val = demb[day[row]*16 + (c-33)];
    else             val = wemb[week[row]*15 + (c-49)];
    x[r] = val;
  }
  #pragma unroll
  for (int q = 0; q < 4; ++q)
    vb[lane*4 + q] = make_float4(x[4*q], x[4*q+1], x[4*q+2], x[4*q+3]);

  float acc[16];
  {
    float bv = b1[lane];
    #pragma unroll
    for (int r = 0; r < 16; ++r) acc[r] = bv;
    for (int j = 0; j < 64; ++j) {
      float w = w1T[j*64 + lane];
      #pragma unroll
      for (int q = 0; q < 4; ++q) {
        float4 v = vb[j*4 + q];
        acc[4*q]   += w*v.x; acc[4*q+1] += w*v.y;
        acc[4*q+2] += w*v.z; acc[4*q+3] += w*v.w;
      }
    }
  }
  #pragma unroll
  for (int q = 0; q < 4; ++q)
    vb[lane*4 + q] = make_float4(acc[4*q], acc[4*q+1], acc[4*q+2], acc[4*q+3]);

  float lo[16], hi[16];
  {
    float blo = b2[lane], bhi = b2[64 + lane];
    #pragma unroll
    for (int r = 0; r < 16; ++r) { lo[r] = blo; hi[r] = bhi; }
    for (int j = 0; j < 64; ++j) {
      float wl = w2T[j*128 + lane];
      float wh = w2T[j*128 + 64 + lane];
      #pragma unroll
      for (int q = 0; q < 4; ++q) {
        float4 v = vb[j*4 + q];
        lo[4*q]   += wl*v.x; lo[4*q+1] += wl*v.y; lo[4*q+2] += wl*v.z; lo[4*q+3] += wl*v.w;
        hi[4*q]   += wh*v.x; hi[4*q+1] += wh*v.y; hi[4*q+2] += wh*v.z; hi[4*q+3] += wh*v.w;
      }
    }
    #pragma unroll
    for (int r = 0; r < 16; ++r) lo[r] = lo[r] * sigmoidf_(hi[r]);
  }
  #pragma unroll
  for (int q = 0; q < 4; ++q)
    vb[lane*4 + q] = make_float4(lo[4*q], lo[4*q+1], lo[4*q+2], lo[4*q+3]);

  {
    #pragma unroll
    for (int r = 0; r < 16; ++r) acc[r] = 0.f;
    for (int j = 0; j < 64; ++j) {
      float w = gcw[j*64 + lane];
      #pragma unroll
      for (int q = 0; q < 4; ++q) {
        float4 v = vb[j*4 + q];
        acc[4*q]   += w*v.x; acc[4*q+1] += w*v.y;
        acc[4*q+2] += w*v.z; acc[4*q+3] += w*v.w;
      }
    }
    #pragma unroll
    for (int r = 0; r < 16; ++r)
      outw[(size_t)(row0 + r)*64 + lane] = f2bf(acc[r]);
  }
}

// ---------------- K2: A = softmax(relu(A1),1) + softmax(relu(A2),1), bf16 out ------------
__global__ __launch_bounds__(256) void k_aprep(
    const float* __restrict__ A1, const float* __restrict__ A2, unsigned short* __restrict__ Aout)
{
  __shared__ float red[4];
  int m = blockIdx.x, tid = threadIdx.x;
  float mx0, is0, mx1, is1;
  {
    const float* src = A1 + (size_t)m*N_;
    float mx = 0.f;
    for (int i = tid; i < N_; i += 256) mx = fmaxf(mx, fmaxf(src[i], 0.f));
    mx = blkRedMax(mx, red);
    float s = 0.f;
    for (int i = tid; i < N_; i += 256) s += __expf(fmaxf(src[i], 0.f) - mx);
    s = blkRedSum(s, red);
    mx0 = mx; is0 = 1.f / s;
  }
  {
    const float* src = A2 + (size_t)m*N_;
    float mx = 0.f;
    for (int i = tid; i < N_; i += 256) mx = fmaxf(mx, fmaxf(src[i], 0.f));
    mx = blkRedMax(mx, red);
    float s = 0.f;
    for (int i = tid; i < N_; i += 256) s += __expf(fmaxf(src[i], 0.f) - mx);
    s = blkRedSum(s, red);
    mx1 = mx; is1 = 1.f / s;
  }
  const float* s1 = A1 + (size_t)m*N_;
  const float* s2 = A2 + (size_t)m*N_;
  for (int i = tid; i < N_; i += 256) {
    float v1 = __expf(fmaxf(s1[i], 0.f) - mx0) * is0;
    float v2 = __expf(fmaxf(s2[i], 0.f) - mx1) * is1;
    Aout[(size_t)m*N_ + i] = f2bf(v1 + v2);
  }
}

// ---------------- K3: bf16 MFMA batched GEMM ----------------
template<int RELU, int OB16>
__global__ __launch_bounds__(256) void k_gemm_mfma(
    const unsigned short* __restrict__ A, const unsigned short* __restrict__ X,
    void* __restrict__ C, int K, int P)
{
  __shared__ unsigned short sA[128*40];
  __shared__ unsigned short sB[128*40];
  int tid = threadIdx.x, lane = tid & 63, wid = tid >> 6;
  int M = gridDim.y * 128;
  int b = blockIdx.z;
  const unsigned short* Xb = X + (size_t)b*K*P;
  int m0 = blockIdx.y*128, p0 = blockIdx.x*128;
  int wr = wid >> 1, wc = wid & 1;

  f32x4 acc[4][4] = {};

  for (int k0 = 0; k0 < K; k0 += 32) {
    #pragma unroll
    for (int pass = 0; pass < 2; ++pass) {
      int r = (tid >> 2) + 64*pass, kk = (tid & 3)*8;
      short8 v = *(const short8*)&A[(size_t)(m0+r)*K + k0 + kk];
      *(short8*)&sA[r*40 + kk] = v;
    }
    #pragma unroll
    for (int pass = 0; pass < 4; ++pass) {
      int p  = (tid & 63) + 64*(pass & 1);
      int k4 = (tid >> 6)*4 + 16*(pass >> 1);
      ushort4 h;
      h.x = Xb[(size_t)(k0+k4+0)*P + p0 + p];
      h.y = Xb[(size_t)(k0+k4+1)*P + p0 + p];
      h.z = Xb[(size_t)(k0+k4+2)*P + p0 + p];
      h.w = Xb[(size_t)(k0+k4+3)*P + p0 + p];
      *(ushort4*)&sB[p*40 + k4] = h;
    }
    __syncthreads();
    short8 af[4], bf[4];
    #pragma unroll
    for (int f = 0; f < 4; ++f) {
      af[f] = *(const short8*)&sA[(wr*64 + f*16 + (lane & 15))*40 + (lane >> 4)*8];
      bf[f] = *(const short8*)&sB[(wc*64 + f*16 + (lane & 15))*40 + (lane >> 4)*8];
    }
    #pragma unroll
    for (int fm = 0; fm < 4; ++fm)
      #pragma unroll
      for (int fn = 0; fn < 4; ++fn)
        acc[fm][fn] = MFMA16(af[fm], bf[fn], acc[fm][fn]);
    __syncthreads();
  }
  #pragma unroll
  for (int fm = 0; fm < 4; ++fm) {
    int row = m0 + wr*64 + fm*16 + (lane >> 4)*4;
    #pragma unroll
    for (int fn = 0; fn < 4; ++fn) {
      int col = p0 + wc*64 + fn*16 + (lane & 15);
      #pragma unroll
      for (int r = 0; r < 4; ++r) {
        float v = acc[fm][fn][r];
        if (RELU) v = fmaxf(v, 0.f);
        if (OB16) {
          unsigned short* Cb = (unsigned short*)C + (size_t)b*M*P;
          Cb[(size_t)(row + r)*P + col] = f2bf(v);
        } else {
          float* Cb = (float*)C + (size_t)b*M*P;
          Cb[(size_t)(row + r)*P + col] = v;
        }
      }
    }
  }
}

// ---------------- K5: ds temporal-conv block, MFMA, 8 bn per block; bf16 out (in-place) ----
__global__ __launch_bounds__(256) void k_ds3(
    const unsigned short* xds,                 // in/out: [BNT][64] bf16 (in-place safe per-block)
    const unsigned short* __restrict__ Wall,
    const float* __restrict__ bi,
    const float* __restrict__ b1m, const float* __restrict__ b1g,
    const float* __restrict__ b2m, const float* __restrict__ b2g,
    const float* __restrict__ bfc,
    unsigned short* outg)
{
  __shared__ unsigned short smem[36352];
  unsigned short* X_lds  = smem;               // [8][14][72]
  unsigned short* xi_lds = smem + 8064;        // [8][14][136]
  unsigned short* fu_lds = smem + 23296;       // [96][136]
  const unsigned short* WiB  = Wall;
  const unsigned short* Wg1B = Wall + 24576;
  const unsigned short* Wg2B = Wall + 49152;
  const unsigned short* WfB  = Wall + 73728;

  int tid = threadIdx.x, lane = tid & 63, wid = tid >> 6;
  int l15 = lane & 15, l4 = lane >> 4;
  int bn0 = blockIdx.x * 8;

  for (int i = tid; i < 8*2*72; i += 256) {
    int g = i / 144, r = i - g*144;
    int tp = (r < 72) ? 0 : 13, c = (r < 72) ? r : r - 72;
    X_lds[(g*14 + tp)*72 + c] = 0;
  }
  for (int i = tid; i < 8*2*136; i += 256) {
    int g = i / 272, r = i - g*272;
    int tp = (r < 136) ? 0 : 13, c = (r < 136) ? r : r - 136;
    xi_lds[(g*14 + tp)*136 + c] = 0;
  }
  for (int i = tid; i < 768; i += 256) {
    int g = i / 96, rem = i - g*96, t = rem >> 3, i8 = rem & 7;
    short8 v = *(const short8*)&xds[(size_t)(bn0+g)*768 + t*64 + i8*8];
    *(short8*)&X_lds[(g*14 + t + 1)*72 + i8*8] = v;
  }
  __syncthreads();

  int ga[6], ta[6];
  #pragma unroll
  for (int mt = 0; mt < 6; ++mt) {
    int r = mt*16 + l15;
    ga[mt] = r / 12; ta[mt] = r - ga[mt]*12;
  }

  {
    f32x4 acc1[6][2] = {};
    int nb = wid*2;
    #pragma unroll
    for (int ks = 0; ks < 6; ++ks) {
      int tap = ks >> 1, i0 = (ks & 1)*32;
      short8 af[6];
      #pragma unroll
      for (int mt = 0; mt < 6; ++mt)
        af[mt] = *(const short8*)&X_lds[(ga[mt]*14 + ta[mt] + tap)*72 + i0 + l4*8];
      short8 bf0 = *(const short8*)&WiB[(size_t)((nb  )*16 + l15)*192 + ks*32 + l4*8];
      short8 bf1 = *(const short8*)&WiB[(size_t)((nb+1)*16 + l15)*192 + ks*32 + l4*8];
      #pragma unroll
      for (int mt = 0; mt < 6; ++mt) {
        acc1[mt][0] = MFMA16(af[mt], bf0, acc1[mt][0]);
        acc1[mt][1] = MFMA16(af[mt], bf1, acc1[mt][1]);
      }
    }
    #pragma unroll
    for (int nn = 0; nn < 2; ++nn) {
      int o = (nb+nn)*16 + l15;
      float bv = bi[o];
      #pragma unroll
      for (int mt = 0; mt < 6; ++mt) {
        #pragma unroll
        for (int reg = 0; reg < 4; ++reg) {
          int r = mt*16 + l4*4 + reg;
          int g = r / 12, t = r - g*12;
          xi_lds[(g*14 + t + 1)*136 + o] = f2bf(acc1[mt][nn][reg] + bv);
        }
      }
    }
  }
  __syncthreads();

  #pragma unroll
  for (int h = 0; h < 2; ++h) {
    const unsigned short* Wg = h ? Wg2B : Wg1B;
    f32x4 am[6] = {}, ag[6] = {};
    #pragma unroll
    for (int ks = 0; ks < 6; ++ks) {
      int tap = ks >> 1, i0 = (ks & 1)*32;
      short8 af[6];
      #pragma unroll
      for (int mt = 0; mt < 6; ++mt)
        af[mt] = *(const short8*)&xi_lds[(ga[mt]*14 + ta[mt] + tap)*136 + h*64 + i0 + l4*8];
      short8 bm = *(const short8*)&Wg[(size_t)(wid*16 + l15)*192 + ks*32 + l4*8];
      short8 bg = *(const short8*)&Wg[(size_t)((wid+4)*16 + l15)*192 + ks*32 + l4*8];
      #pragma unroll
      for (int mt = 0; mt < 6; ++mt) {
        am[mt] = MFMA16(af[mt], bm, am[mt]);
        ag[mt] = MFMA16(af[mt], bg, ag[mt]);
      }
    }
    int o = wid*16 + l15;
    float bmv = (h ? b2m : b1m)[o];
    float bgv = (h ? b2g : b1g)[o];
    #pragma unroll
    for (int mt = 0; mt < 6; ++mt) {
      #pragma unroll
      for (int reg = 0; reg < 4; ++reg) {
        int r = mt*16 + l4*4 + reg;
        int g = r / 12, t = r - g*12;
        float pm = am[mt][reg] + bmv;
        float pg = ag[mt][reg] + bgv;
        float po = pm * sigmoidf_(pg);
        float xi = bf2f(xi_lds[(g*14 + t + 1)*136 + h*64 + o]);
        fu_lds[r*136 + h*64 + o] = f2bf(fmaxf(po + xi, 0.f));
      }
    }
  }
  __syncthreads();

  {
    f32x4 a3[6] = {};
    #pragma unroll
    for (int ks = 0; ks < 4; ++ks) {
      short8 af = *(const short8*)&WfB[(size_t)(wid*16 + l15)*128 + ks*32 + l4*8];
      #pragma unroll
      for (int nt = 0; nt < 6; ++nt) {
        short8 bf = *(const short8*)&fu_lds[(nt*16 + l15)*136 + ks*32 + l4*8];
        a3[nt] = MFMA16(af, bf, a3[nt]);
      }
    }
    int e0 = wid*16 + l4*4;
    float4 bb = *(const float4*)&bfc[e0];
    #pragma unroll
    for (int nt = 0; nt < 6; ++nt) {
      ushort4 vv;
      vv.x = f2bf(a3[nt][0] + bb.x); vv.y = f2bf(a3[nt][1] + bb.y);
      vv.z = f2bf(a3[nt][2] + bb.z); vv.w = f2bf(a3[nt][3] + bb.w);
      *(ushort4*)&outg[((size_t)(bn0 + ga[nt])*12 + ta[nt])*64 + e0] = vv;
    }
  }
}

// ---------------- K6: attention + FFN + 2x LN, full MFMA, bf16 in/out, 4 bn per block ----
// LDS: Ybuf[48][72] (y->o->y1) | Qkv[52][216] / Hb[48][280] union | atts[4][16][24]
__global__ __launch_bounds__(256) void k_attn3(
    const unsigned short* __restrict__ xg,     // bf16 [BN][12][64]
    const unsigned short* __restrict__ Wat,
    const float* __restrict__ bq, const float* __restrict__ bk, const float* __restrict__ bv,
    const float* __restrict__ bo,
    const float* __restrict__ f1b, const float* __restrict__ f2b,
    const float* __restrict__ g1, const float* __restrict__ be1,
    const float* __restrict__ g2, const float* __restrict__ be2,
    unsigned short* __restrict__ outg)
{
  __shared__ unsigned short su[18432];
  __shared__ float part[2][4][48];
  __shared__ float stats[2][48];
  unsigned short* Ybuf = su;           // [48][72]
  unsigned short* Qkv  = su + 3456;    // [52][216]
  unsigned short* Hb   = su + 3456;    // [48][280] (union with Qkv)
  unsigned short* atts = su + 16896;   // [4][16][24]

  const unsigned short* Wqkv = Wat;
  const unsigned short* Wo   = Wat + 12288;
  const unsigned short* F1   = Wat + 16384;
  const unsigned short* F2   = Wat + 32768;

  int tid = threadIdx.x, lane = tid & 63, w = tid >> 6;
  int l15 = lane & 15, l4 = lane >> 4;
  size_t base = (size_t)blockIdx.x * 4 * 768;

  // stage y (bf16, wide copies)
  for (int i = tid; i < 384; i += 256) {
    int r = i >> 3, c = i & 7;
    *(short8*)&Ybuf[r*72 + c*8] = *(const short8*)&xg[base + r*64 + c*8];
  }
  __syncthreads();

  // ---- QKV GEMM: Qkv[48][192] ----
  {
    f32x4 acc[3][3] = {};
    #pragma unroll
    for (int ks = 0; ks < 2; ++ks) {
      short8 af[3];
      #pragma unroll
      for (int mt = 0; mt < 3; ++mt)
        af[mt] = *(const short8*)&Ybuf[(mt*16 + l15)*72 + ks*32 + l4*8];
      #pragma unroll
      for (int i = 0; i < 3; ++i) {
        int nt = w*3 + i;
        short8 bf = *(const short8*)&Wqkv[(size_t)(nt*16 + l15)*64 + ks*32 + l4*8];
        #pragma unroll
        for (int mt = 0; mt < 3; ++mt)
          acc[mt][i] = MFMA16(af[mt], bf, acc[mt][i]);
      }
    }
    #pragma unroll
    for (int i = 0; i < 3; ++i) {
      int col = (w*3+i)*16 + l15;
      float bias = col < 64 ? bq[col] : (col < 128 ? bk[col-64] : bv[col-128]);
      #pragma unroll
      for (int mt = 0; mt < 3; ++mt)
        #pragma unroll
        for (int r = 0; r < 4; ++r)
          Qkv[(mt*16 + l4*4 + r)*216 + col] = f2bf(acc[mt][i][r] + bias);
    }
  }
  __syncthreads();

  // ---- attention: wave w owns bn w ----
  {
    int rb = w*12;
    unsigned short* as = atts + w*384;   // [16][24]
    #pragma unroll
    for (int h = 0; h < 4; ++h) {
      short8 kf = {}, qf = {};
      if (l4 < 2) {
        kf = *(const short8*)&Qkv[(rb + l15)*216 + 64 + h*16 + l4*8];
        qf = *(const short8*)&Qkv[(rb + l15)*216 +      h*16 + l4*8];
      }
      f32x4 sc = {};
      sc = MFMA16(kf, qf, sc);
      float e[4]; float mx = -3e38f;
      #pragma unroll
      for (int r = 0; r < 4; ++r) {
        float v = (l4 == 3) ? -3e38f : sc[r]*0.25f;
        e[r] = v; mx = fmaxf(mx, v);
      }
      mx = fmaxf(mx, __shfl_xor(mx, 16));
      mx = fmaxf(mx, __shfl_xor(mx, 32));
      float s = 0.f;
      #pragma unroll
      for (int r = 0; r < 4; ++r) { e[r] = __expf(e[r] - mx); s += e[r]; }
      s += __shfl_xor(s, 16); s += __shfl_xor(s, 32);
      float inv = 1.f/s;
      ushort4 pk;
      pk.x = f2bf(e[0]*inv); pk.y = f2bf(e[1]*inv);
      pk.z = f2bf(e[2]*inv); pk.w = f2bf(e[3]*inv);
      *(ushort4*)&as[l15*24 + l4*4] = pk;
      short8 aaf = {};
      if (l4 < 2) aaf = *(const short8*)&as[l15*24 + l4*8];
      short8 vf = {};
      if (l4 < 2) {
        #pragma unroll
        for (int j = 0; j < 8; ++j) {
          int s_ = l4*8 + j;
          vf[j] = (s_ < 12) ? (short)Qkv[(rb + s_)*216 + 128 + h*16 + l15] : (short)0;
        }
      }
      f32x4 o = {};
      o = MFMA16(aaf, vf, o);
      if (l4 < 3) {
        #pragma unroll
        for (int r = 0; r < 4; ++r)
          Ybuf[(rb + l4*4 + r)*72 + h*16 + l15] = f2bf(o[r]);
      }
    }
  }
  __syncthreads();

  // ---- WO GEMM + residual(bf16 global) + LN1 ----
  {
    f32x4 zacc[3] = {};
    #pragma unroll
    for (int ks = 0; ks < 2; ++ks) {
      short8 bf = *(const short8*)&Wo[(size_t)(w*16 + l15)*64 + ks*32 + l4*8];
      #pragma unroll
      for (int mt = 0; mt < 3; ++mt) {
        short8 af = *(const short8*)&Ybuf[(mt*16 + l15)*72 + ks*32 + l4*8];
        zacc[mt] = MFMA16(af, bf, zacc[mt]);
      }
    }
    int col = w*16 + l15;
    float bias = bo[col];
    #pragma unroll
    for (int mt = 0; mt < 3; ++mt)
      #pragma unroll
      for (int r = 0; r < 4; ++r) {
        int row = mt*16 + l4*4 + r;
        float z = zacc[mt][r] + bias + bf2f(xg[base + row*64 + col]);
        zacc[mt][r] = z;
        float s1 = z, s2 = z*z;
        #pragma unroll
        for (int off = 1; off <= 8; off <<= 1) { s1 += __shfl_xor(s1, off); s2 += __shfl_xor(s2, off); }
        if (l15 == 0) { part[0][w][row] = s1; part[1][w][row] = s2; }
      }
    __syncthreads();
    if (tid < 48) {
      float s = part[0][0][tid]+part[0][1][tid]+part[0][2][tid]+part[0][3][tid];
      float q = part[1][0][tid]+part[1][1][tid]+part[1][2][tid]+part[1][3][tid];
      float mu = s * (1.f/64.f);
      float var = q * (1.f/64.f) - mu*mu;
      stats[0][tid] = mu; stats[1][tid] = rsqrtf(var + 1e-5f);
    }
    __syncthreads();
    float gv = g1[col], bvv = be1[col];
    #pragma unroll
    for (int mt = 0; mt < 3; ++mt)
      #pragma unroll
      for (int r = 0; r < 4; ++r) {
        int row = mt*16 + l4*4 + r;
        Ybuf[row*72 + col] = f2bf((zacc[mt][r] - stats[0][row]) * stats[1][row] * gv + bvv);
      }
  }
  __syncthreads();

  // ---- FF1: h[48][256] = relu(y1 @ F1^T) ----
  {
    f32x4 acc[3][4] = {};
    #pragma unroll
    for (int ks = 0; ks < 2; ++ks) {
      short8 af[3];
      #pragma unroll
      for (int mt = 0; mt < 3; ++mt)
        af[mt] = *(const short8*)&Ybuf[(mt*16 + l15)*72 + ks*32 + l4*8];
      #pragma unroll
      for (int i = 0; i < 4; ++i) {
        int nt = w*4 + i;
        short8 bf = *(const short8*)&F1[(size_t)(nt*16 + l15)*64 + ks*32 + l4*8];
        #pragma unroll
        for (int mt = 0; mt < 3; ++mt)
          acc[mt][i] = MFMA16(af[mt], bf, acc[mt][i]);
      }
    }
    #pragma unroll
    for (int i = 0; i < 4; ++i) {
      int col = (w*4+i)*16 + l15;
      float bias = f1b[col];
      #pragma unroll
      for (int mt = 0; mt < 3; ++mt)
        #pragma unroll
        for (int r = 0; r < 4; ++r)
          Hb[(mt*16 + l4*4 + r)*280 + col] = f2bf(fmaxf(acc[mt][i][r] + bias, 0.f));
    }
  }
  __syncthreads();

  // ---- FF2 + residual + LN2 + store y2 bf16 ----
  {
    f32x4 acc[3] = {};
    #pragma unroll
    for (int ks = 0; ks < 8; ++ks) {
      short8 bf = *(const short8*)&F2[(size_t)(w*16 + l15)*256 + ks*32 + l4*8];
      #pragma unroll
      for (int mt = 0; mt < 3; ++mt) {
        short8 af = *(const short8*)&Hb[(mt*16 + l15)*280 + ks*32 + l4*8];
        acc[mt] = MFMA16(af, bf, acc[mt]);
      }
    }
    int col = w*16 + l15;
    float bias = f2b[col];
    #pragma unroll
    for (int mt = 0; mt < 3; ++mt)
      #pragma unroll
      for (int r = 0; r < 4; ++r) {
        int row = mt*16 + l4*4 + r;
        float z = acc[mt][r] + bias + bf2f(Ybuf[row*72 + col]);
        acc[mt][r] = z;
        float s1 = z, s2 = z*z;
        #pragma unroll
        for (int off = 1; off <= 8; off <<= 1) { s1 += __shfl_xor(s1, off); s2 += __shfl_xor(s2, off); }
        if (l15 == 0) { part[0][w][row] = s1; part[1][w][row] = s2; }
      }
    __syncthreads();
    if (tid < 48) {
      float s = part[0][0][tid]+part[0][1][tid]+part[0][2][tid]+part[0][3][tid];
      float q = part[1][0][tid]+part[1][1][tid]+part[1][2][tid]+part[1][3][tid];
      float mu = s * (1.f/64.f);
      float var = q * (1.f/64.f) - mu*mu;
      stats[0][tid] = mu; stats[1][tid] = rsqrtf(var + 1e-5f);
    }
    __syncthreads();
    float gv = g2[col], bvv = be2[col];
    #pragma unroll
    for (int mt = 0; mt < 3; ++mt)
      #pragma unroll
      for (int r = 0; r < 4; ++r) {
        int row = mt*16 + l4*4 + r;
        outg[base + row*64 + col] = f2bf((acc[mt][r] - stats[0][row]) * stats[1][row] * gv + bvv);
      }
  }
}

// ---------------- K7: fuse-matrix prep ----------------
__global__ void k_mvec(const float* __restrict__ flow, const float* __restrict__ clw,
                       const float* __restrict__ clb, float* __restrict__ mv)
{
  int n = blockIdx.x*blockDim.x + threadIdx.x;
  if (n < N_) {
    float s = 0.f;
    float bias = clb[0];
    for (int b = 0; b < B_; ++b) {
      const float* f = flow + ((size_t)b*N_ + n)*T_;
      float acc = bias;
      #pragma unroll
      for (int t = 0; t < T_; ++t) acc += f[t]*clw[t];
      s += fmaxf(acc, 0.f);
    }
    mv[n] = s * (1.f/16.f);
  }
}

__global__ void k_fusemat(const float* __restrict__ mv, unsigned short* __restrict__ F)
{
  int idx = blockIdx.x*256 + threadIdx.x;
  int m = idx >> 10, n = idx & 1023;
  float x = 0.5f*(mv[m] + mv[n]);
  F[idx] = f2bf(1.f/(1.f + __expf(-x)));
}

// ---------------- launch ----------------
extern "C" void kernel_launch(void* const* d_in, const int* in_sizes, int n_in,
                              void* d_out, int out_size, void* d_ws, size_t ws_size,
                              hipStream_t stream)
{
  const float* flow = (const float*)d_in[0];
  const int*   day  = (const int*)d_in[1];
  const int*   week = (const int*)d_in[2];
  const float* semb = (const float*)d_in[3];
  const float* demb = (const float*)d_in[4];
  const float* wemb = (const float*)d_in[5];
  const float* gfsw = (const float*)d_in[6];
  const float* gfsb = (const float*)d_in[7];
  const float* gluw = (const float*)d_in[8];
  const float* glub = (const float*)d_in[9];
  const float* gcw  = (const float*)d_in[10];
  const float* gcA  = (const float*)d_in[11];
  const float* gcA2 = (const float*)d_in[12];
  const float* wi   = (const float*)d_in[13];
  const float* bi   = (const float*)d_in[14];
  const float* w1m  = (const float*)d_in[15];
  const float* b1m  = (const float*)d_in[16];
  const float* w1g  = (const float*)d_in[17];
  const float* b1g  = (const float*)d_in[18];
  const float* w2m  = (const float*)d_in[19];
  const float* b2m  = (const float*)d_in[20];
  const float* w2g  = (const float*)d_in[21];
  const float* b2g  = (const float*)d_in[22];
  const float* wfc  = (const float*)d_in[23];
  const float* bfc  = (const float*)d_in[24];
  const float* wq   = (const float*)d_in[25];
  const float* bq   = (const float*)d_in[26];
  const float* wk   = (const float*)d_in[27];
  const float* bk   = (const float*)d_in[28];
  const float* wv   = (const float*)d_in[29];
  const float* bv   = (const float*)d_in[30];
  const float* wo   = (const float*)d_in[31];
  const float* bo   = (const float*)d_in[32];
  const float* f1w  = (const float*)d_in[33];
  const float* f1b  = (const float*)d_in[34];
  const float* f2w  = (const float*)d_in[35];
  const float* f2b  = (const float*)d_in[36];
  const float* g1   = (const float*)d_in[37];
  const float* be1  = (const float*)d_in[38];
  const float* g2   = (const float*)d_in[39];
  const float* be2  = (const float*)d_in[40];
  const float* clw  = (const float*)d_in[41];
  const float* clb  = (const float*)d_in[42];

  float* out = (float*)d_out;
  char* ws = (char*)d_ws;
  unsigned short* Amat = (unsigned short*)ws;                               // 2 MB
  float* mv  = (float*)(ws + (size_t)2*1024*1024);                          // 64 KB region
  float* wTe = (float*)(ws + (size_t)2*1024*1024 + 64*1024);                // 64 KB region
  unsigned short* wds = (unsigned short*)(ws + (size_t)2*1024*1024 + 128*1024); // 192 KB region
  unsigned short* wat = (unsigned short*)(ws + (size_t)2*1024*1024 + 320*1024); // 128 KB region
  unsigned short* xw  = (unsigned short*)(ws + (size_t)3*1024*1024);        // 24 MB
  unsigned short* xds = (unsigned short*)(ws + (size_t)28*1024*1024);       // 24 MB

  k_wprep_e<<<48, 256, 0, stream>>>(gfsw, gluw, wTe);
  k_wprep3<<<96, 256, 0, stream>>>(wi, w1m, w1g, w2m, w2g, wfc, wds);
  k_wprep4<<<192, 256, 0, stream>>>(wq, wk, wv, wo, f1w, f2w, wat);
  // xw = GLU(gfs_fc(embed)) @ gc_weight -> bf16
  k_embed2<<<BNT/64, 256, 0, stream>>>(flow, day, week, semb, demb, wemb,
                                       wTe, gfsb, glub, gcw, xw);
  // combined adjacency (bf16)
  k_aprep<<<N_, 256, 0, stream>>>(gcA, gcA2, Amat);
  // xds = relu(A @ xw) -> bf16
  dim3 gg(TD/128, N_/128, B_);
  k_gemm_mfma<1,1><<<gg, 256, 0, stream>>>(Amat, xw, xds, N_, TD);
  // ds block (MFMA) -> bf16, in-place on xds
  k_ds3<<<BN_/8, 256, 0, stream>>>(xds, wds, bi, b1m, b1g, b2m, b2g, bfc, xds);
  // y2 = attn+ffn block (MFMA, bf16 in) -> bf16 (reuse xw region)
  k_attn3<<<BN_/4, 256, 0, stream>>>(xds, wat, bq, bk, bv, bo, f1b, f2b,
                                     g1, be1, g2, be2, xw);
  // fuse matrix (bf16, reuse Amat region)
  k_mvec<<<N_/256, 256, 0, stream>>>(flow, clw, clb, mv);
  k_fusemat<<<(N_*N_)/256, 256, 0, stream>>>(mv, Amat);
  // out = fuse @ y2 -> d_out (fp32)
  k_gemm_mfma<0,0><<<gg, 256, 0, stream>>>(Amat, xw, out, N_, TD);
}

// Round 9
// 341.173 us; speedup vs baseline: 18.9767x; 1.1330x over previous
//
#include <hip/hip_runtime.h>
#include <cstdint>

#define B_ 16
#define N_ 1024
#define T_ 12
#define HD 64
#define BN_ (B_*N_)     // 16384
#define BNT (B_*N_*T_)  // 196608
#define TD (T_*HD)      // 768

typedef __attribute__((ext_vector_type(8))) short short8;
typedef __attribute__((ext_vector_type(4))) float f32x4;

#define MFMA16(a,b,c) __builtin_amdgcn_mfma_f32_16x16x32_bf16(a,b,c,0,0,0)

__device__ __forceinline__ float sigmoidf_(float x) { return 1.f / (1.f + __expf(-x)); }

__device__ __forceinline__ unsigned short f2bf(float f) {
  unsigned int u = __float_as_uint(f);
  u += 0x7fffu + ((u >> 16) & 1u);   // round-to-nearest-even
  return (unsigned short)(u >> 16);
}
__device__ __forceinline__ float bf2f(unsigned short h) {
  unsigned int u = ((unsigned int)h) << 16;
  return __uint_as_float(u);
}

// ---------------- reductions ----------------
__device__ __forceinline__ float blkRedMax(float v, float* red) {
  #pragma unroll
  for (int off = 32; off >= 1; off >>= 1) v = fmaxf(v, __shfl_xor(v, off));
  int w = threadIdx.x >> 6;
  if ((threadIdx.x & 63) == 0) red[w] = v;
  __syncthreads();
  v = fmaxf(fmaxf(red[0], red[1]), fmaxf(red[2], red[3]));
  __syncthreads();
  return v;
}
__device__ __forceinline__ float blkRedSum(float v, float* red) {
  #pragma unroll
  for (int off = 32; off >= 1; off >>= 1) v += __shfl_xor(v, off);
  int w = threadIdx.x >> 6;
  if ((threadIdx.x & 63) == 0) red[w] = v;
  __syncthreads();
  v = red[0] + red[1] + red[2] + red[3];
  __syncthreads();
  return v;
}

// ---------------- K-wprep-e2: bf16 embed/glu/gc weights, B-frag natural [out][in] ------
// wTe u16: W1[64][64]@0 | W2[128][64]@4096 | GcT[64][64]@12288
__global__ void k_wprep_e2(const float* __restrict__ w1, const float* __restrict__ w2,
                           const float* __restrict__ gcw, unsigned short* __restrict__ W)
{
  int t = blockIdx.x*256 + threadIdx.x;   // 64*256 = 16384
  if (t < 4096)       W[t] = f2bf(w1[t]);
  else if (t < 12288) W[t] = f2bf(w2[t-4096]);
  else {
    int r = t - 12288, e = r >> 6, d = r & 63;
    W[12288 + e*64 + d] = f2bf(gcw[d*64 + e]);   // gcwT[e][d]
  }
}

// ---------------- K-wprep3: bf16 tap-major conv weights for k_ds3 ----------------
__global__ void k_wprep3(const float* __restrict__ wi,
                         const float* __restrict__ w1m, const float* __restrict__ w1g,
                         const float* __restrict__ w2m, const float* __restrict__ w2g,
                         const float* __restrict__ wfc, unsigned short* __restrict__ W)
{
  int t = blockIdx.x*256 + threadIdx.x;  // 96*256 = 24576
  {
    int o = t / 192, k = t - o*192, tap = k >> 6, i = k & 63;
    W[o*192 + k] = f2bf(wi[(o*64 + i)*3 + tap]);
  }
  if (t < 12288) {
    int o = t / 192, k = t - o*192, tap = k >> 6, i = k & 63;
    int src = (o*64 + i)*3 + tap;
    W[24576 + o*192 + k]      = f2bf(w1m[src]);
    W[24576 + (64+o)*192 + k] = f2bf(w1g[src]);
    W[49152 + o*192 + k]      = f2bf(w2m[src]);
    W[49152 + (64+o)*192 + k] = f2bf(w2g[src]);
  }
  if (t < 8192) W[73728 + t] = f2bf(wfc[t]);
}

// ---------------- K-wprep4: bf16 cast of attn/ffn weights (natural layout) -------------
__global__ void k_wprep4(const float* __restrict__ wq, const float* __restrict__ wk,
                         const float* __restrict__ wv, const float* __restrict__ wo,
                         const float* __restrict__ f1w, const float* __restrict__ f2w,
                         unsigned short* __restrict__ W)
{
  int t = blockIdx.x*256 + threadIdx.x;  // 192*256 = 49152
  if (t < 4096)        W[t] = f2bf(wq[t]);
  else if (t < 8192)   W[t] = f2bf(wk[t-4096]);
  else if (t < 12288)  W[t] = f2bf(wv[t-8192]);
  else if (t < 16384)  W[t] = f2bf(wo[t-12288]);
  else if (t < 32768)  W[t] = f2bf(f1w[t-16384]);
  else                 W[t] = f2bf(f2w[t-32768]);
}

// ---------------- K1: embed + gfs_fc + GLU + (x @ gc_weight), full MFMA ----------------
// 128 rows/block, 4 waves (wave owns 16-col n-tile). LDS ping-pong sEa->sEb->sEa->global.
__global__ __launch_bounds__(256) void k_embed3(
    const float* __restrict__ flow, const int* __restrict__ day, const int* __restrict__ week,
    const float* __restrict__ semb, const float* __restrict__ demb, const float* __restrict__ wemb,
    const unsigned short* __restrict__ wTe, const float* __restrict__ b1,
    const float* __restrict__ b2,
    unsigned short* __restrict__ outw)
{
  __shared__ unsigned short sEa[128*72];   // 18432 B
  __shared__ unsigned short sEb[128*72];   // 18432 B
  const unsigned short* W1  = wTe;
  const unsigned short* W2  = wTe + 4096;
  const unsigned short* GcT = wTe + 12288;

  int tid = threadIdx.x, lane = tid & 63, w = tid >> 6;
  int l15 = lane & 15, l4 = lane >> 4;
  int row0 = blockIdx.x * 128;

  // gather features -> bf16 LDS
  for (int i = tid; i < 8192; i += 256) {
    int r = i >> 6, c = i & 63;
    int row = row0 + r;
    int n = (row / T_) & (N_-1);
    float val;
    if (c == 0)      val = flow[row];
    else if (c < 33) val = semb[n*32 + (c-1)];
    else if (c < 49) val = demb[day[row]*16 + (c-33)];
    else             val = wemb[week[row]*15 + (c-49)];
    sEa[r*72 + c] = f2bf(val);
  }
  __syncthreads();

  // G1: sEb = sEa @ W1^T + b1
  {
    f32x4 acc[8] = {};
    #pragma unroll
    for (int ks = 0; ks < 2; ++ks) {
      short8 bf = *(const short8*)&W1[(w*16 + l15)*64 + ks*32 + l4*8];
      #pragma unroll
      for (int mt = 0; mt < 8; ++mt) {
        short8 af = *(const short8*)&sEa[(mt*16 + l15)*72 + ks*32 + l4*8];
        acc[mt] = MFMA16(af, bf, acc[mt]);
      }
    }
    float bias = b1[w*16 + l15];
    #pragma unroll
    for (int mt = 0; mt < 8; ++mt)
      #pragma unroll
      for (int r = 0; r < 4; ++r)
        sEb[(mt*16 + l4*4 + r)*72 + w*16 + l15] = f2bf(acc[mt][r] + bias);
  }
  __syncthreads();

  // G2: GLU — lo/hi in same lane -> sEa
  {
    f32x4 alo[8] = {}, ahi[8] = {};
    #pragma unroll
    for (int ks = 0; ks < 2; ++ks) {
      short8 blo = *(const short8*)&W2[(size_t)(w*16 + l15)*64 + ks*32 + l4*8];
      short8 bhi = *(const short8*)&W2[(size_t)(64 + w*16 + l15)*64 + ks*32 + l4*8];
      #pragma unroll
      for (int mt = 0; mt < 8; ++mt) {
        short8 af = *(const short8*)&sEb[(mt*16 + l15)*72 + ks*32 + l4*8];
        alo[mt] = MFMA16(af, blo, alo[mt]);
        ahi[mt] = MFMA16(af, bhi, ahi[mt]);
      }
    }
    float blov = b2[w*16 + l15], bhiv = b2[64 + w*16 + l15];
    #pragma unroll
    for (int mt = 0; mt < 8; ++mt)
      #pragma unroll
      for (int r = 0; r < 4; ++r) {
        float v = (alo[mt][r] + blov) * sigmoidf_(ahi[mt][r] + bhiv);
        sEa[(mt*16 + l4*4 + r)*72 + w*16 + l15] = f2bf(v);
      }
  }
  __syncthreads();

  // G3: out = sEa @ gcw  (GcT natural) -> global bf16
  {
    f32x4 acc[8] = {};
    #pragma unroll
    for (int ks = 0; ks < 2; ++ks) {
      short8 bf = *(const short8*)&GcT[(w*16 + l15)*64 + ks*32 + l4*8];
      #pragma unroll
      for (int mt = 0; mt < 8; ++mt) {
        short8 af = *(const short8*)&sEa[(mt*16 + l15)*72 + ks*32 + l4*8];
        acc[mt] = MFMA16(af, bf, acc[mt]);
      }
    }
    #pragma unroll
    for (int mt = 0; mt < 8; ++mt)
      #pragma unroll
      for (int r = 0; r < 4; ++r)
        outw[(size_t)(row0 + mt*16 + l4*4 + r)*64 + w*16 + l15] = f2bf(acc[mt][r]);
  }
}

// ---------------- K2: A = softmax(relu(A1),1) + softmax(relu(A2),1), bf16 out ------------
__global__ __launch_bounds__(256) void k_aprep(
    const float* __restrict__ A1, const float* __restrict__ A2, unsigned short* __restrict__ Aout)
{
  __shared__ float red[4];
  int m = blockIdx.x, tid = threadIdx.x;
  float mx0, is0, mx1, is1;
  {
    const float* src = A1 + (size_t)m*N_;
    float mx = 0.f;
    for (int i = tid; i < N_; i += 256) mx = fmaxf(mx, fmaxf(src[i], 0.f));
    mx = blkRedMax(mx, red);
    float s = 0.f;
    for (int i = tid; i < N_; i += 256) s += __expf(fmaxf(src[i], 0.f) - mx);
    s = blkRedSum(s, red);
    mx0 = mx; is0 = 1.f / s;
  }
  {
    const float* src = A2 + (size_t)m*N_;
    float mx = 0.f;
    for (int i = tid; i < N_; i += 256) mx = fmaxf(mx, fmaxf(src[i], 0.f));
    mx = blkRedMax(mx, red);
    float s = 0.f;
    for (int i = tid; i < N_; i += 256) s += __expf(fmaxf(src[i], 0.f) - mx);
    s = blkRedSum(s, red);
    mx1 = mx; is1 = 1.f / s;
  }
  const float* s1 = A1 + (size_t)m*N_;
  const float* s2 = A2 + (size_t)m*N_;
  for (int i = tid; i < N_; i += 256) {
    float v1 = __expf(fmaxf(s1[i], 0.f) - mx0) * is0;
    float v2 = __expf(fmaxf(s2[i], 0.f) - mx1) * is1;
    Aout[(size_t)m*N_ + i] = f2bf(v1 + v2);
  }
}

// ---------------- K3: bf16 MFMA batched GEMM ----------------
template<int RELU, int OB16>
__global__ __launch_bounds__(256) void k_gemm_mfma(
    const unsigned short* __restrict__ A, const unsigned short* __restrict__ X,
    void* __restrict__ C, int K, int P)
{
  __shared__ unsigned short sA[128*40];
  __shared__ unsigned short sB[128*40];
  int tid = threadIdx.x, lane = tid & 63, wid = tid >> 6;
  int M = gridDim.y * 128;
  int b = blockIdx.z;
  const unsigned short* Xb = X + (size_t)b*K*P;
  int m0 = blockIdx.y*128, p0 = blockIdx.x*128;
  int wr = wid >> 1, wc = wid & 1;

  f32x4 acc[4][4] = {};

  for (int k0 = 0; k0 < K; k0 += 32) {
    #pragma unroll
    for (int pass = 0; pass < 2; ++pass) {
      int r = (tid >> 2) + 64*pass, kk = (tid & 3)*8;
      short8 v = *(const short8*)&A[(size_t)(m0+r)*K + k0 + kk];
      *(short8*)&sA[r*40 + kk] = v;
    }
    #pragma unroll
    for (int pass = 0; pass < 4; ++pass) {
      int p  = (tid & 63) + 64*(pass & 1);
      int k4 = (tid >> 6)*4 + 16*(pass >> 1);
      ushort4 h;
      h.x = Xb[(size_t)(k0+k4+0)*P + p0 + p];
      h.y = Xb[(size_t)(k0+k4+1)*P + p0 + p];
      h.z = Xb[(size_t)(k0+k4+2)*P + p0 + p];
      h.w = Xb[(size_t)(k0+k4+3)*P + p0 + p];
      *(ushort4*)&sB[p*40 + k4] = h;
    }
    __syncthreads();
    short8 af[4], bf[4];
    #pragma unroll
    for (int f = 0; f < 4; ++f) {
      af[f] = *(const short8*)&sA[(wr*64 + f*16 + (lane & 15))*40 + (lane >> 4)*8];
      bf[f] = *(const short8*)&sB[(wc*64 + f*16 + (lane & 15))*40 + (lane >> 4)*8];
    }
    #pragma unroll
    for (int fm = 0; fm < 4; ++fm)
      #pragma unroll
      for (int fn = 0; fn < 4; ++fn)
        acc[fm][fn] = MFMA16(af[fm], bf[fn], acc[fm][fn]);
    __syncthreads();
  }
  #pragma unroll
  for (int fm = 0; fm < 4; ++fm) {
    int row = m0 + wr*64 + fm*16 + (lane >> 4)*4;
    #pragma unroll
    for (int fn = 0; fn < 4; ++fn) {
      int col = p0 + wc*64 + fn*16 + (lane & 15);
      #pragma unroll
      for (int r = 0; r < 4; ++r) {
        float v = acc[fm][fn][r];
        if (RELU) v = fmaxf(v, 0.f);
        if (OB16) {
          unsigned short* Cb = (unsigned short*)C + (size_t)b*M*P;
          Cb[(size_t)(row + r)*P + col] = f2bf(v);
        } else {
          float* Cb = (float*)C + (size_t)b*M*P;
          Cb[(size_t)(row + r)*P + col] = v;
        }
      }
    }
  }
}

// ---------------- K5: ds temporal-conv block, MFMA, 8 bn per block; bf16 out (in-place) ----
__global__ __launch_bounds__(256) void k_ds3(
    const unsigned short* xds,
    const unsigned short* __restrict__ Wall,
    const float* __restrict__ bi,
    const float* __restrict__ b1m, const float* __restrict__ b1g,
    const float* __restrict__ b2m, const float* __restrict__ b2g,
    const float* __restrict__ bfc,
    unsigned short* outg)
{
  __shared__ unsigned short smem[36352];
  unsigned short* X_lds  = smem;               // [8][14][72]
  unsigned short* xi_lds = smem + 8064;        // [8][14][136]
  unsigned short* fu_lds = smem + 23296;       // [96][136]
  const unsigned short* WiB  = Wall;
  const unsigned short* Wg1B = Wall + 24576;
  const unsigned short* Wg2B = Wall + 49152;
  const unsigned short* WfB  = Wall + 73728;

  int tid = threadIdx.x, lane = tid & 63, wid = tid >> 6;
  int l15 = lane & 15, l4 = lane >> 4;
  int bn0 = blockIdx.x * 8;

  for (int i = tid; i < 8*2*72; i += 256) {
    int g = i / 144, r = i - g*144;
    int tp = (r < 72) ? 0 : 13, c = (r < 72) ? r : r - 72;
    X_lds[(g*14 + tp)*72 + c] = 0;
  }
  for (int i = tid; i < 8*2*136; i += 256) {
    int g = i / 272, r = i - g*272;
    int tp = (r < 136) ? 0 : 13, c = (r < 136) ? r : r - 136;
    xi_lds[(g*14 + tp)*136 + c] = 0;
  }
  for (int i = tid; i < 768; i += 256) {
    int g = i / 96, rem = i - g*96, t = rem >> 3, i8 = rem & 7;
    short8 v = *(const short8*)&xds[(size_t)(bn0+g)*768 + t*64 + i8*8];
    *(short8*)&X_lds[(g*14 + t + 1)*72 + i8*8] = v;
  }
  __syncthreads();

  int ga[6], ta[6];
  #pragma unroll
  for (int mt = 0; mt < 6; ++mt) {
    int r = mt*16 + l15;
    ga[mt] = r / 12; ta[mt] = r - ga[mt]*12;
  }

  {
    f32x4 acc1[6][2] = {};
    int nb = wid*2;
    #pragma unroll
    for (int ks = 0; ks < 6; ++ks) {
      int tap = ks >> 1, i0 = (ks & 1)*32;
      short8 af[6];
      #pragma unroll
      for (int mt = 0; mt < 6; ++mt)
        af[mt] = *(const short8*)&X_lds[(ga[mt]*14 + ta[mt] + tap)*72 + i0 + l4*8];
      short8 bf0 = *(const short8*)&WiB[(size_t)((nb  )*16 + l15)*192 + ks*32 + l4*8];
      short8 bf1 = *(const short8*)&WiB[(size_t)((nb+1)*16 + l15)*192 + ks*32 + l4*8];
      #pragma unroll
      for (int mt = 0; mt < 6; ++mt) {
        acc1[mt][0] = MFMA16(af[mt], bf0, acc1[mt][0]);
        acc1[mt][1] = MFMA16(af[mt], bf1, acc1[mt][1]);
      }
    }
    #pragma unroll
    for (int nn = 0; nn < 2; ++nn) {
      int o = (nb+nn)*16 + l15;
      float bv = bi[o];
      #pragma unroll
      for (int mt = 0; mt < 6; ++mt) {
        #pragma unroll
        for (int reg = 0; reg < 4; ++reg) {
          int r = mt*16 + l4*4 + reg;
          int g = r / 12, t = r - g*12;
          xi_lds[(g*14 + t + 1)*136 + o] = f2bf(acc1[mt][nn][reg] + bv);
        }
      }
    }
  }
  __syncthreads();

  #pragma unroll
  for (int h = 0; h < 2; ++h) {
    const unsigned short* Wg = h ? Wg2B : Wg1B;
    f32x4 am[6] = {}, ag[6] = {};
    #pragma unroll
    for (int ks = 0; ks < 6; ++ks) {
      int tap = ks >> 1, i0 = (ks & 1)*32;
      short8 af[6];
      #pragma unroll
      for (int mt = 0; mt < 6; ++mt)
        af[mt] = *(const short8*)&xi_lds[(ga[mt]*14 + ta[mt] + tap)*136 + h*64 + i0 + l4*8];
      short8 bm = *(const short8*)&Wg[(size_t)(wid*16 + l15)*192 + ks*32 + l4*8];
      short8 bg = *(const short8*)&Wg[(size_t)((wid+4)*16 + l15)*192 + ks*32 + l4*8];
      #pragma unroll
      for (int mt = 0; mt < 6; ++mt) {
        am[mt] = MFMA16(af[mt], bm, am[mt]);
        ag[mt] = MFMA16(af[mt], bg, ag[mt]);
      }
    }
    int o = wid*16 + l15;
    float bmv = (h ? b2m : b1m)[o];
    float bgv = (h ? b2g : b1g)[o];
    #pragma unroll
    for (int mt = 0; mt < 6; ++mt) {
      #pragma unroll
      for (int reg = 0; reg < 4; ++reg) {
        int r = mt*16 + l4*4 + reg;
        int g = r / 12, t = r - g*12;
        float pm = am[mt][reg] + bmv;
        float pg = ag[mt][reg] + bgv;
        float po = pm * sigmoidf_(pg);
        float xi = bf2f(xi_lds[(g*14 + t + 1)*136 + h*64 + o]);
        fu_lds[r*136 + h*64 + o] = f2bf(fmaxf(po + xi, 0.f));
      }
    }
  }
  __syncthreads();

  {
    f32x4 a3[6] = {};
    #pragma unroll
    for (int ks = 0; ks < 4; ++ks) {
      short8 af = *(const short8*)&WfB[(size_t)(wid*16 + l15)*128 + ks*32 + l4*8];
      #pragma unroll
      for (int nt = 0; nt < 6; ++nt) {
        short8 bf = *(const short8*)&fu_lds[(nt*16 + l15)*136 + ks*32 + l4*8];
        a3[nt] = MFMA16(af, bf, a3[nt]);
      }
    }
    int e0 = wid*16 + l4*4;
    float4 bb = *(const float4*)&bfc[e0];
    #pragma unroll
    for (int nt = 0; nt < 6; ++nt) {
      ushort4 vv;
      vv.x = f2bf(a3[nt][0] + bb.x); vv.y = f2bf(a3[nt][1] + bb.y);
      vv.z = f2bf(a3[nt][2] + bb.z); vv.w = f2bf(a3[nt][3] + bb.w);
      *(ushort4*)&outg[((size_t)(bn0 + ga[nt])*12 + ta[nt])*64 + e0] = vv;
    }
  }
}

// ---------------- K6: attention + FFN + 2x LN, full MFMA, bf16 in/out, 4 bn per block ----
__global__ __launch_bounds__(256) void k_attn3(
    const unsigned short* __restrict__ xg,     // bf16 [BN][12][64]
    const unsigned short* __restrict__ Wat,
    const float* __restrict__ bq, const float* __restrict__ bk, const float* __restrict__ bv,
    const float* __restrict__ bo,
    const float* __restrict__ f1b, const float* __restrict__ f2b,
    const float* __restrict__ g1, const float* __restrict__ be1,
    const float* __restrict__ g2, const float* __restrict__ be2,
    unsigned short* __restrict__ outg)
{
  __shared__ unsigned short su[18432];
  __shared__ float part[2][4][48];
  __shared__ float stats[2][48];
  unsigned short* Ybuf = su;           // [48][72]
  unsigned short* Qkv  = su + 3456;    // [52][216]
  unsigned short* Hb   = su + 3456;    // [48][280] (union with Qkv)
  unsigned short* atts = su + 16896;   // [4][16][24]

  const unsigned short* Wqkv = Wat;
  const unsigned short* Wo   = Wat + 12288;
  const unsigned short* F1   = Wat + 16384;
  const unsigned short* F2   = Wat + 32768;

  int tid = threadIdx.x, lane = tid & 63, w = tid >> 6;
  int l15 = lane & 15, l4 = lane >> 4;
  size_t base = (size_t)blockIdx.x * 4 * 768;

  for (int i = tid; i < 384; i += 256) {
    int r = i >> 3, c = i & 7;
    *(short8*)&Ybuf[r*72 + c*8] = *(const short8*)&xg[base + r*64 + c*8];
  }
  __syncthreads();

  // ---- QKV GEMM: Qkv[48][192] ----
  {
    f32x4 acc[3][3] = {};
    #pragma unroll
    for (int ks = 0; ks < 2; ++ks) {
      short8 af[3];
      #pragma unroll
      for (int mt = 0; mt < 3; ++mt)
        af[mt] = *(const short8*)&Ybuf[(mt*16 + l15)*72 + ks*32 + l4*8];
      #pragma unroll
      for (int i = 0; i < 3; ++i) {
        int nt = w*3 + i;
        short8 bf = *(const short8*)&Wqkv[(size_t)(nt*16 + l15)*64 + ks*32 + l4*8];
        #pragma unroll
        for (int mt = 0; mt < 3; ++mt)
          acc[mt][i] = MFMA16(af[mt], bf, acc[mt][i]);
      }
    }
    #pragma unroll
    for (int i = 0; i < 3; ++i) {
      int col = (w*3+i)*16 + l15;
      float bias = col < 64 ? bq[col] : (col < 128 ? bk[col-64] : bv[col-128]);
      #pragma unroll
      for (int mt = 0; mt < 3; ++mt)
        #pragma unroll
        for (int r = 0; r < 4; ++r)
          Qkv[(mt*16 + l4*4 + r)*216 + col] = f2bf(acc[mt][i][r] + bias);
    }
  }
  __syncthreads();

  // ---- attention: wave w owns bn w ----
  {
    int rb = w*12;
    unsigned short* as = atts + w*384;   // [16][24]
    #pragma unroll
    for (int h = 0; h < 4; ++h) {
      short8 kf = {}, qf = {};
      if (l4 < 2) {
        kf = *(const short8*)&Qkv[(rb + l15)*216 + 64 + h*16 + l4*8];
        qf = *(const short8*)&Qkv[(rb + l15)*216 +      h*16 + l4*8];
      }
      f32x4 sc = {};
      sc = MFMA16(kf, qf, sc);
      float e[4]; float mx = -3e38f;
      #pragma unroll
      for (int r = 0; r < 4; ++r) {
        float v = (l4 == 3) ? -3e38f : sc[r]*0.25f;
        e[r] = v; mx = fmaxf(mx, v);
      }
      mx = fmaxf(mx, __shfl_xor(mx, 16));
      mx = fmaxf(mx, __shfl_xor(mx, 32));
      float s = 0.f;
      #pragma unroll
      for (int r = 0; r < 4; ++r) { e[r] = __expf(e[r] - mx); s += e[r]; }
      s += __shfl_xor(s, 16); s += __shfl_xor(s, 32);
      float inv = 1.f/s;
      ushort4 pk;
      pk.x = f2bf(e[0]*inv); pk.y = f2bf(e[1]*inv);
      pk.z = f2bf(e[2]*inv); pk.w = f2bf(e[3]*inv);
      *(ushort4*)&as[l15*24 + l4*4] = pk;
      short8 aaf = {};
      if (l4 < 2) aaf = *(const short8*)&as[l15*24 + l4*8];
      short8 vf = {};
      if (l4 < 2) {
        #pragma unroll
        for (int j = 0; j < 8; ++j) {
          int s_ = l4*8 + j;
          vf[j] = (s_ < 12) ? (short)Qkv[(rb + s_)*216 + 128 + h*16 + l15] : (short)0;
        }
      }
      f32x4 o = {};
      o = MFMA16(aaf, vf, o);
      if (l4 < 3) {
        #pragma unroll
        for (int r = 0; r < 4; ++r)
          Ybuf[(rb + l4*4 + r)*72 + h*16 + l15] = f2bf(o[r]);
      }
    }
  }
  __syncthreads();

  // ---- WO GEMM + residual(bf16 global) + LN1 ----
  {
    f32x4 zacc[3] = {};
    #pragma unroll
    for (int ks = 0; ks < 2; ++ks) {
      short8 bf = *(const short8*)&Wo[(size_t)(w*16 + l15)*64 + ks*32 + l4*8];
      #pragma unroll
      for (int mt = 0; mt < 3; ++mt) {
        short8 af = *(const short8*)&Ybuf[(mt*16 + l15)*72 + ks*32 + l4*8];
        zacc[mt] = MFMA16(af, bf, zacc[mt]);
      }
    }
    int col = w*16 + l15;
    float bias = bo[col];
    #pragma unroll
    for (int mt = 0; mt < 3; ++mt)
      #pragma unroll
      for (int r = 0; r < 4; ++r) {
        int row = mt*16 + l4*4 + r;
        float z = zacc[mt][r] + bias + bf2f(xg[base + row*64 + col]);
        zacc[mt][r] = z;
        float s1 = z, s2 = z*z;
        #pragma unroll
        for (int off = 1; off <= 8; off <<= 1) { s1 += __shfl_xor(s1, off); s2 += __shfl_xor(s2, off); }
        if (l15 == 0) { part[0][w][row] = s1; part[1][w][row] = s2; }
      }
    __syncthreads();
    if (tid < 48) {
      float s = part[0][0][tid]+part[0][1][tid]+part[0][2][tid]+part[0][3][tid];
      float q = part[1][0][tid]+part[1][1][tid]+part[1][2][tid]+part[1][3][tid];
      float mu = s * (1.f/64.f);
      float var = q * (1.f/64.f) - mu*mu;
      stats[0][tid] = mu; stats[1][tid] = rsqrtf(var + 1e-5f);
    }
    __syncthreads();
    float gv = g1[col], bvv = be1[col];
    #pragma unroll
    for (int mt = 0; mt < 3; ++mt)
      #pragma unroll
      for (int r = 0; r < 4; ++r) {
        int row = mt*16 + l4*4 + r;
        Ybuf[row*72 + col] = f2bf((zacc[mt][r] - stats[0][row]) * stats[1][row] * gv + bvv);
      }
  }
  __syncthreads();

  // ---- FF1: h[48][256] = relu(y1 @ F1^T) ----
  {
    f32x4 acc[3][4] = {};
    #pragma unroll
    for (int ks = 0; ks < 2; ++ks) {
      short8 af[3];
      #pragma unroll
      for (int mt = 0; mt < 3; ++mt)
        af[mt] = *(const short8*)&Ybuf[(mt*16 + l15)*72 + ks*32 + l4*8];
      #pragma unroll
      for (int i = 0; i < 4; ++i) {
        int nt = w*4 + i;
        short8 bf = *(const short8*)&F1[(size_t)(nt*16 + l15)*64 + ks*32 + l4*8];
        #pragma unroll
        for (int mt = 0; mt < 3; ++mt)
          acc[mt][i] = MFMA16(af[mt], bf, acc[mt][i]);
      }
    }
    #pragma unroll
    for (int i = 0; i < 4; ++i) {
      int col = (w*4+i)*16 + l15;
      float bias = f1b[col];
      #pragma unroll
      for (int mt = 0; mt < 3; ++mt)
        #pragma unroll
        for (int r = 0; r < 4; ++r)
          Hb[(mt*16 + l4*4 + r)*280 + col] = f2bf(fmaxf(acc[mt][i][r] + bias, 0.f));
    }
  }
  __syncthreads();

  // ---- FF2 + residual + LN2 + store y2 bf16 ----
  {
    f32x4 acc[3] = {};
    #pragma unroll
    for (int ks = 0; ks < 8; ++ks) {
      short8 bf = *(const short8*)&F2[(size_t)(w*16 + l15)*256 + ks*32 + l4*8];
      #pragma unroll
      for (int mt = 0; mt < 3; ++mt) {
        short8 af = *(const short8*)&Hb[(mt*16 + l15)*280 + ks*32 + l4*8];
        acc[mt] = MFMA16(af, bf, acc[mt]);
      }
    }
    int col = w*16 + l15;
    float bias = f2b[col];
    #pragma unroll
    for (int mt = 0; mt < 3; ++mt)
      #pragma unroll
      for (int r = 0; r < 4; ++r) {
        int row = mt*16 + l4*4 + r;
        float z = acc[mt][r] + bias + bf2f(Ybuf[row*72 + col]);
        acc[mt][r] = z;
        float s1 = z, s2 = z*z;
        #pragma unroll
        for (int off = 1; off <= 8; off <<= 1) { s1 += __shfl_xor(s1, off); s2 += __shfl_xor(s2, off); }
        if (l15 == 0) { part[0][w][row] = s1; part[1][w][row] = s2; }
      }
    __syncthreads();
    if (tid < 48) {
      float s = part[0][0][tid]+part[0][1][tid]+part[0][2][tid]+part[0][3][tid];
      float q = part[1][0][tid]+part[1][1][tid]+part[1][2][tid]+part[1][3][tid];
      float mu = s * (1.f/64.f);
      float var = q * (1.f/64.f) - mu*mu;
      stats[0][tid] = mu; stats[1][tid] = rsqrtf(var + 1e-5f);
    }
    __syncthreads();
    float gv = g2[col], bvv = be2[col];
    #pragma unroll
    for (int mt = 0; mt < 3; ++mt)
      #pragma unroll
      for (int r = 0; r < 4; ++r) {
        int row = mt*16 + l4*4 + r;
        outg[base + row*64 + col] = f2bf((acc[mt][r] - stats[0][row]) * stats[1][row] * gv + bvv);
      }
  }
}

// ---------------- K7: fuse-matrix prep ----------------
__global__ void k_mvec(const float* __restrict__ flow, const float* __restrict__ clw,
                       const float* __restrict__ clb, float* __restrict__ mv)
{
  int n = blockIdx.x*blockDim.x + threadIdx.x;
  if (n < N_) {
    float s = 0.f;
    float bias = clb[0];
    for (int b = 0; b < B_; ++b) {
      const float* f = flow + ((size_t)b*N_ + n)*T_;
      float acc = bias;
      #pragma unroll
      for (int t = 0; t < T_; ++t) acc += f[t]*clw[t];
      s += fmaxf(acc, 0.f);
    }
    mv[n] = s * (1.f/16.f);
  }
}

__global__ void k_fusemat(const float* __restrict__ mv, unsigned short* __restrict__ F)
{
  int idx = blockIdx.x*256 + threadIdx.x;
  int m = idx >> 10, n = idx & 1023;
  float x = 0.5f*(mv[m] + mv[n]);
  F[idx] = f2bf(1.f/(1.f + __expf(-x)));
}

// ---------------- launch ----------------
extern "C" void kernel_launch(void* const* d_in, const int* in_sizes, int n_in,
                              void* d_out, int out_size, void* d_ws, size_t ws_size,
                              hipStream_t stream)
{
  const float* flow = (const float*)d_in[0];
  const int*   day  = (const int*)d_in[1];
  const int*   week = (const int*)d_in[2];
  const float* semb = (const float*)d_in[3];
  const float* demb = (const float*)d_in[4];
  const float* wemb = (const float*)d_in[5];
  const float* gfsw = (const float*)d_in[6];
  const float* gfsb = (const float*)d_in[7];
  const float* gluw = (const float*)d_in[8];
  const float* glub = (const float*)d_in[9];
  const float* gcw  = (const float*)d_in[10];
  const float* gcA  = (const float*)d_in[11];
  const float* gcA2 = (const float*)d_in[12];
  const float* wi   = (const float*)d_in[13];
  const float* bi   = (const float*)d_in[14];
  const float* w1m  = (const float*)d_in[15];
  const float* b1m  = (const float*)d_in[16];
  const float* w1g  = (const float*)d_in[17];
  const float* b1g  = (const float*)d_in[18];
  const float* w2m  = (const float*)d_in[19];
  const float* b2m  = (const float*)d_in[20];
  const float* w2g  = (const float*)d_in[21];
  const float* b2g  = (const float*)d_in[22];
  const float* wfc  = (const float*)d_in[23];
  const float* bfc  = (const float*)d_in[24];
  const float* wq   = (const float*)d_in[25];
  const float* bq   = (const float*)d_in[26];
  const float* wk   = (const float*)d_in[27];
  const float* bk   = (const float*)d_in[28];
  const float* wv   = (const float*)d_in[29];
  const float* bv   = (const float*)d_in[30];
  const float* wo   = (const float*)d_in[31];
  const float* bo   = (const float*)d_in[32];
  const float* f1w  = (const float*)d_in[33];
  const float* f1b  = (const float*)d_in[34];
  const float* f2w  = (const float*)d_in[35];
  const float* f2b  = (const float*)d_in[36];
  const float* g1   = (const float*)d_in[37];
  const float* be1  = (const float*)d_in[38];
  const float* g2   = (const float*)d_in[39];
  const float* be2  = (const float*)d_in[40];
  const float* clw  = (const float*)d_in[41];
  const float* clb  = (const float*)d_in[42];

  float* out = (float*)d_out;
  char* ws = (char*)d_ws;
  unsigned short* Amat = (unsigned short*)ws;                               // 2 MB
  float* mv  = (float*)(ws + (size_t)2*1024*1024);                          // 64 KB region
  unsigned short* wTe = (unsigned short*)(ws + (size_t)2*1024*1024 + 64*1024); // 64 KB region
  unsigned short* wds = (unsigned short*)(ws + (size_t)2*1024*1024 + 128*1024); // 192 KB region
  unsigned short* wat = (unsigned short*)(ws + (size_t)2*1024*1024 + 320*1024); // 128 KB region
  unsigned short* xw  = (unsigned short*)(ws + (size_t)3*1024*1024);        // 24 MB
  unsigned short* xds = (unsigned short*)(ws + (size_t)28*1024*1024);       // 24 MB

  k_wprep_e2<<<64, 256, 0, stream>>>(gfsw, gluw, gcw, wTe);
  k_wprep3<<<96, 256, 0, stream>>>(wi, w1m, w1g, w2m, w2g, wfc, wds);
  k_wprep4<<<192, 256, 0, stream>>>(wq, wk, wv, wo, f1w, f2w, wat);
  // xw = GLU(gfs_fc(embed)) @ gc_weight -> bf16   (full MFMA)
  k_embed3<<<BNT/128, 256, 0, stream>>>(flow, day, week, semb, demb, wemb,
                                        wTe, gfsb, glub, xw);
  // combined adjacency (bf16)
  k_aprep<<<N_, 256, 0, stream>>>(gcA, gcA2, Amat);
  // xds = relu(A @ xw) -> bf16
  dim3 gg(TD/128, N_/128, B_);
  k_gemm_mfma<1,1><<<gg, 256, 0, stream>>>(Amat, xw, xds, N_, TD);
  // ds block (MFMA) -> bf16, in-place on xds
  k_ds3<<<BN_/8, 256, 0, stream>>>(xds, wds, bi, b1m, b1g, b2m, b2g, bfc, xds);
  // y2 = attn+ffn block (MFMA, bf16 in) -> bf16 (reuse xw region)
  k_attn3<<<BN_/4, 256, 0, stream>>>(xds, wat, bq, bk, bv, bo, f1b, f2b,
                                     g1, be1, g2, be2, xw);
  // fuse matrix (bf16, reuse Amat region)
  k_mvec<<<N_/256, 256, 0, stream>>>(flow, clw, clb, mv);
  k_fusemat<<<(N_*N_)/256, 256, 0, stream>>>(mv, Amat);
  // out = fuse @ y2 -> d_out (fp32)
  k_gemm_mfma<0,0><<<gg, 256, 0, stream>>>(Amat, xw, out, N_, TD);
}

// Round 10
// 339.061 us; speedup vs baseline: 19.0949x; 1.0062x over previous
//
#include <hip/hip_runtime.h>
#include <cstdint>

#define B_ 16
#define N_ 1024
#define T_ 12
#define HD 64
#define BN_ (B_*N_)     // 16384
#define BNT (B_*N_*T_)  // 196608
#define TD (T_*HD)      // 768

typedef __attribute__((ext_vector_type(8))) short short8;
typedef __attribute__((ext_vector_type(4))) float f32x4;

#define MFMA16(a,b,c) __builtin_amdgcn_mfma_f32_16x16x32_bf16(a,b,c,0,0,0)

__device__ __forceinline__ float sigmoidf_(float x) { return 1.f / (1.f + __expf(-x)); }

__device__ __forceinline__ unsigned short f2bf(float f) {
  unsigned int u = __float_as_uint(f);
  u += 0x7fffu + ((u >> 16) & 1u);   // round-to-nearest-even
  return (unsigned short)(u >> 16);
}
__device__ __forceinline__ float bf2f(unsigned short h) {
  unsigned int u = ((unsigned int)h) << 16;
  return __uint_as_float(u);
}

// ---------------- reductions ----------------
__device__ __forceinline__ float blkRedMax(float v, float* red) {
  #pragma unroll
  for (int off = 32; off >= 1; off >>= 1) v = fmaxf(v, __shfl_xor(v, off));
  int w = threadIdx.x >> 6;
  if ((threadIdx.x & 63) == 0) red[w] = v;
  __syncthreads();
  v = fmaxf(fmaxf(red[0], red[1]), fmaxf(red[2], red[3]));
  __syncthreads();
  return v;
}
__device__ __forceinline__ float blkRedSum(float v, float* red) {
  #pragma unroll
  for (int off = 32; off >= 1; off >>= 1) v += __shfl_xor(v, off);
  int w = threadIdx.x >> 6;
  if ((threadIdx.x & 63) == 0) red[w] = v;
  __syncthreads();
  v = red[0] + red[1] + red[2] + red[3];
  __syncthreads();
  return v;
}

// ---------------- K-wprep-e2: bf16 embed/glu/gc weights, B-frag natural [out][in] ------
// wTe u16: W1[64][64]@0 | W2[128][64]@4096 | GcT[64][64]@12288
__global__ void k_wprep_e2(const float* __restrict__ w1, const float* __restrict__ w2,
                           const float* __restrict__ gcw, unsigned short* __restrict__ W)
{
  int t = blockIdx.x*256 + threadIdx.x;   // 64*256 = 16384
  if (t < 4096)       W[t] = f2bf(w1[t]);
  else if (t < 12288) W[t] = f2bf(w2[t-4096]);
  else {
    int r = t - 12288, e = r >> 6, d = r & 63;
    W[12288 + e*64 + d] = f2bf(gcw[d*64 + e]);   // gcwT[e][d]
  }
}

// ---------------- K-wprep3: bf16 tap-major conv weights for k_ds3 ----------------
__global__ void k_wprep3(const float* __restrict__ wi,
                         const float* __restrict__ w1m, const float* __restrict__ w1g,
                         const float* __restrict__ w2m, const float* __restrict__ w2g,
                         const float* __restrict__ wfc, unsigned short* __restrict__ W)
{
  int t = blockIdx.x*256 + threadIdx.x;  // 96*256 = 24576
  {
    int o = t / 192, k = t - o*192, tap = k >> 6, i = k & 63;
    W[o*192 + k] = f2bf(wi[(o*64 + i)*3 + tap]);
  }
  if (t < 12288) {
    int o = t / 192, k = t - o*192, tap = k >> 6, i = k & 63;
    int src = (o*64 + i)*3 + tap;
    W[24576 + o*192 + k]      = f2bf(w1m[src]);
    W[24576 + (64+o)*192 + k] = f2bf(w1g[src]);
    W[49152 + o*192 + k]      = f2bf(w2m[src]);
    W[49152 + (64+o)*192 + k] = f2bf(w2g[src]);
  }
  if (t < 8192) W[73728 + t] = f2bf(wfc[t]);
}

// ---------------- K-wprep4: bf16 cast of attn/ffn weights (natural layout) -------------
__global__ void k_wprep4(const float* __restrict__ wq, const float* __restrict__ wk,
                         const float* __restrict__ wv, const float* __restrict__ wo,
                         const float* __restrict__ f1w, const float* __restrict__ f2w,
                         unsigned short* __restrict__ W)
{
  int t = blockIdx.x*256 + threadIdx.x;  // 192*256 = 49152
  if (t < 4096)        W[t] = f2bf(wq[t]);
  else if (t < 8192)   W[t] = f2bf(wk[t-4096]);
  else if (t < 12288)  W[t] = f2bf(wv[t-8192]);
  else if (t < 16384)  W[t] = f2bf(wo[t-12288]);
  else if (t < 32768)  W[t] = f2bf(f1w[t-16384]);
  else                 W[t] = f2bf(f2w[t-32768]);
}

// ---------------- K1: embed + gfs_fc + GLU + (x @ gc_weight), full MFMA ----------------
__global__ __launch_bounds__(256) void k_embed3(
    const float* __restrict__ flow, const int* __restrict__ day, const int* __restrict__ week,
    const float* __restrict__ semb, const float* __restrict__ demb, const float* __restrict__ wemb,
    const unsigned short* __restrict__ wTe, const float* __restrict__ b1,
    const float* __restrict__ b2,
    unsigned short* __restrict__ outw)
{
  __shared__ unsigned short sEa[128*72];   // 18432 B
  __shared__ unsigned short sEb[128*72];   // 18432 B
  const unsigned short* W1  = wTe;
  const unsigned short* W2  = wTe + 4096;
  const unsigned short* GcT = wTe + 12288;

  int tid = threadIdx.x, lane = tid & 63, w = tid >> 6;
  int l15 = lane & 15, l4 = lane >> 4;
  int row0 = blockIdx.x * 128;

  for (int i = tid; i < 8192; i += 256) {
    int r = i >> 6, c = i & 63;
    int row = row0 + r;
    int n = (row / T_) & (N_-1);
    float val;
    if (c == 0)      val = flow[row];
    else if (c < 33) val = semb[n*32 + (c-1)];
    else if (c < 49) val = demb[day[row]*16 + (c-33)];
    else             val = wemb[week[row]*15 + (c-49)];
    sEa[r*72 + c] = f2bf(val);
  }
  __syncthreads();

  {
    f32x4 acc[8] = {};
    #pragma unroll
    for (int ks = 0; ks < 2; ++ks) {
      short8 bf = *(const short8*)&W1[(w*16 + l15)*64 + ks*32 + l4*8];
      #pragma unroll
      for (int mt = 0; mt < 8; ++mt) {
        short8 af = *(const short8*)&sEa[(mt*16 + l15)*72 + ks*32 + l4*8];
        acc[mt] = MFMA16(af, bf, acc[mt]);
      }
    }
    float bias = b1[w*16 + l15];
    #pragma unroll
    for (int mt = 0; mt < 8; ++mt)
      #pragma unroll
      for (int r = 0; r < 4; ++r)
        sEb[(mt*16 + l4*4 + r)*72 + w*16 + l15] = f2bf(acc[mt][r] + bias);
  }
  __syncthreads();

  {
    f32x4 alo[8] = {}, ahi[8] = {};
    #pragma unroll
    for (int ks = 0; ks < 2; ++ks) {
      short8 blo = *(const short8*)&W2[(size_t)(w*16 + l15)*64 + ks*32 + l4*8];
      short8 bhi = *(const short8*)&W2[(size_t)(64 + w*16 + l15)*64 + ks*32 + l4*8];
      #pragma unroll
      for (int mt = 0; mt < 8; ++mt) {
        short8 af = *(const short8*)&sEb[(mt*16 + l15)*72 + ks*32 + l4*8];
        alo[mt] = MFMA16(af, blo, alo[mt]);
        ahi[mt] = MFMA16(af, bhi, ahi[mt]);
      }
    }
    float blov = b2[w*16 + l15], bhiv = b2[64 + w*16 + l15];
    #pragma unroll
    for (int mt = 0; mt < 8; ++mt)
      #pragma unroll
      for (int r = 0; r < 4; ++r) {
        float v = (alo[mt][r] + blov) * sigmoidf_(ahi[mt][r] + bhiv);
        sEa[(mt*16 + l4*4 + r)*72 + w*16 + l15] = f2bf(v);
      }
  }
  __syncthreads();

  {
    f32x4 acc[8] = {};
    #pragma unroll
    for (int ks = 0; ks < 2; ++ks) {
      short8 bf = *(const short8*)&GcT[(w*16 + l15)*64 + ks*32 + l4*8];
      #pragma unroll
      for (int mt = 0; mt < 8; ++mt) {
        short8 af = *(const short8*)&sEa[(mt*16 + l15)*72 + ks*32 + l4*8];
        acc[mt] = MFMA16(af, bf, acc[mt]);
      }
    }
    #pragma unroll
    for (int mt = 0; mt < 8; ++mt)
      #pragma unroll
      for (int r = 0; r < 4; ++r)
        outw[(size_t)(row0 + mt*16 + l4*4 + r)*64 + w*16 + l15] = f2bf(acc[mt][r]);
  }
}

// ---------------- K2: A = softmax(relu(A1),1) + softmax(relu(A2),1), bf16 out ------------
__global__ __launch_bounds__(256) void k_aprep(
    const float* __restrict__ A1, const float* __restrict__ A2, unsigned short* __restrict__ Aout)
{
  __shared__ float red[4];
  int m = blockIdx.x, tid = threadIdx.x;
  float mx0, is0, mx1, is1;
  {
    const float* src = A1 + (size_t)m*N_;
    float mx = 0.f;
    for (int i = tid; i < N_; i += 256) mx = fmaxf(mx, fmaxf(src[i], 0.f));
    mx = blkRedMax(mx, red);
    float s = 0.f;
    for (int i = tid; i < N_; i += 256) s += __expf(fmaxf(src[i], 0.f) - mx);
    s = blkRedSum(s, red);
    mx0 = mx; is0 = 1.f / s;
  }
  {
    const float* src = A2 + (size_t)m*N_;
    float mx = 0.f;
    for (int i = tid; i < N_; i += 256) mx = fmaxf(mx, fmaxf(src[i], 0.f));
    mx = blkRedMax(mx, red);
    float s = 0.f;
    for (int i = tid; i < N_; i += 256) s += __expf(fmaxf(src[i], 0.f) - mx);
    s = blkRedSum(s, red);
    mx1 = mx; is1 = 1.f / s;
  }
  const float* s1 = A1 + (size_t)m*N_;
  const float* s2 = A2 + (size_t)m*N_;
  for (int i = tid; i < N_; i += 256) {
    float v1 = __expf(fmaxf(s1[i], 0.f) - mx0) * is0;
    float v2 = __expf(fmaxf(s2[i], 0.f) - mx1) * is1;
    Aout[(size_t)m*N_ + i] = f2bf(v1 + v2);
  }
}

// ---------------- K3: bf16 MFMA batched GEMM ----------------
template<int RELU, int OB16>
__global__ __launch_bounds__(256) void k_gemm_mfma(
    const unsigned short* __restrict__ A, const unsigned short* __restrict__ X,
    void* __restrict__ C, int K, int P)
{
  __shared__ unsigned short sA[128*40];
  __shared__ unsigned short sB[128*40];
  int tid = threadIdx.x, lane = tid & 63, wid = tid >> 6;
  int M = gridDim.y * 128;
  int b = blockIdx.z;
  const unsigned short* Xb = X + (size_t)b*K*P;
  int m0 = blockIdx.y*128, p0 = blockIdx.x*128;
  int wr = wid >> 1, wc = wid & 1;

  f32x4 acc[4][4] = {};

  for (int k0 = 0; k0 < K; k0 += 32) {
    #pragma unroll
    for (int pass = 0; pass < 2; ++pass) {
      int r = (tid >> 2) + 64*pass, kk = (tid & 3)*8;
      short8 v = *(const short8*)&A[(size_t)(m0+r)*K + k0 + kk];
      *(short8*)&sA[r*40 + kk] = v;
    }
    #pragma unroll
    for (int pass = 0; pass < 4; ++pass) {
      int p  = (tid & 63) + 64*(pass & 1);
      int k4 = (tid >> 6)*4 + 16*(pass >> 1);
      ushort4 h;
      h.x = Xb[(size_t)(k0+k4+0)*P + p0 + p];
      h.y = Xb[(size_t)(k0+k4+1)*P + p0 + p];
      h.z = Xb[(size_t)(k0+k4+2)*P + p0 + p];
      h.w = Xb[(size_t)(k0+k4+3)*P + p0 + p];
      *(ushort4*)&sB[p*40 + k4] = h;
    }
    __syncthreads();
    short8 af[4], bf[4];
    #pragma unroll
    for (int f = 0; f < 4; ++f) {
      af[f] = *(const short8*)&sA[(wr*64 + f*16 + (lane & 15))*40 + (lane >> 4)*8];
      bf[f] = *(const short8*)&sB[(wc*64 + f*16 + (lane & 15))*40 + (lane >> 4)*8];
    }
    #pragma unroll
    for (int fm = 0; fm < 4; ++fm)
      #pragma unroll
      for (int fn = 0; fn < 4; ++fn)
        acc[fm][fn] = MFMA16(af[fm], bf[fn], acc[fm][fn]);
    __syncthreads();
  }
  #pragma unroll
  for (int fm = 0; fm < 4; ++fm) {
    int row = m0 + wr*64 + fm*16 + (lane >> 4)*4;
    #pragma unroll
    for (int fn = 0; fn < 4; ++fn) {
      int col = p0 + wc*64 + fn*16 + (lane & 15);
      #pragma unroll
      for (int r = 0; r < 4; ++r) {
        float v = acc[fm][fn][r];
        if (RELU) v = fmaxf(v, 0.f);
        if (OB16) {
          unsigned short* Cb = (unsigned short*)C + (size_t)b*M*P;
          Cb[(size_t)(row + r)*P + col] = f2bf(v);
        } else {
          float* Cb = (float*)C + (size_t)b*M*P;
          Cb[(size_t)(row + r)*P + col] = v;
        }
      }
    }
  }
}

// ---------------- K5: ds temporal-conv block, MFMA, 8 bn per block; bf16 out (in-place) ----
__global__ __launch_bounds__(256) void k_ds3(
    const unsigned short* xds,
    const unsigned short* __restrict__ Wall,
    const float* __restrict__ bi,
    const float* __restrict__ b1m, const float* __restrict__ b1g,
    const float* __restrict__ b2m, const float* __restrict__ b2g,
    const float* __restrict__ bfc,
    unsigned short* outg)
{
  __shared__ unsigned short smem[36352];
  unsigned short* X_lds  = smem;               // [8][14][72]
  unsigned short* xi_lds = smem + 8064;        // [8][14][136]
  unsigned short* fu_lds = smem + 23296;       // [96][136]
  const unsigned short* WiB  = Wall;
  const unsigned short* Wg1B = Wall + 24576;
  const unsigned short* Wg2B = Wall + 49152;
  const unsigned short* WfB  = Wall + 73728;

  int tid = threadIdx.x, lane = tid & 63, wid = tid >> 6;
  int l15 = lane & 15, l4 = lane >> 4;
  int bn0 = blockIdx.x * 8;

  for (int i = tid; i < 8*2*72; i += 256) {
    int g = i / 144, r = i - g*144;
    int tp = (r < 72) ? 0 : 13, c = (r < 72) ? r : r - 72;
    X_lds[(g*14 + tp)*72 + c] = 0;
  }
  for (int i = tid; i < 8*2*136; i += 256) {
    int g = i / 272, r = i - g*272;
    int tp = (r < 136) ? 0 : 13, c = (r < 136) ? r : r - 136;
    xi_lds[(g*14 + tp)*136 + c] = 0;
  }
  for (int i = tid; i < 768; i += 256) {
    int g = i / 96, rem = i - g*96, t = rem >> 3, i8 = rem & 7;
    short8 v = *(const short8*)&xds[(size_t)(bn0+g)*768 + t*64 + i8*8];
    *(short8*)&X_lds[(g*14 + t + 1)*72 + i8*8] = v;
  }
  __syncthreads();

  int ga[6], ta[6];
  #pragma unroll
  for (int mt = 0; mt < 6; ++mt) {
    int r = mt*16 + l15;
    ga[mt] = r / 12; ta[mt] = r - ga[mt]*12;
  }

  {
    f32x4 acc1[6][2] = {};
    int nb = wid*2;
    #pragma unroll
    for (int ks = 0; ks < 6; ++ks) {
      int tap = ks >> 1, i0 = (ks & 1)*32;
      short8 af[6];
      #pragma unroll
      for (int mt = 0; mt < 6; ++mt)
        af[mt] = *(const short8*)&X_lds[(ga[mt]*14 + ta[mt] + tap)*72 + i0 + l4*8];
      short8 bf0 = *(const short8*)&WiB[(size_t)((nb  )*16 + l15)*192 + ks*32 + l4*8];
      short8 bf1 = *(const short8*)&WiB[(size_t)((nb+1)*16 + l15)*192 + ks*32 + l4*8];
      #pragma unroll
      for (int mt = 0; mt < 6; ++mt) {
        acc1[mt][0] = MFMA16(af[mt], bf0, acc1[mt][0]);
        acc1[mt][1] = MFMA16(af[mt], bf1, acc1[mt][1]);
      }
    }
    #pragma unroll
    for (int nn = 0; nn < 2; ++nn) {
      int o = (nb+nn)*16 + l15;
      float bv = bi[o];
      #pragma unroll
      for (int mt = 0; mt < 6; ++mt) {
        #pragma unroll
        for (int reg = 0; reg < 4; ++reg) {
          int r = mt*16 + l4*4 + reg;
          int g = r / 12, t = r - g*12;
          xi_lds[(g*14 + t + 1)*136 + o] = f2bf(acc1[mt][nn][reg] + bv);
        }
      }
    }
  }
  __syncthreads();

  #pragma unroll
  for (int h = 0; h < 2; ++h) {
    const unsigned short* Wg = h ? Wg2B : Wg1B;
    f32x4 am[6] = {}, ag[6] = {};
    #pragma unroll
    for (int ks = 0; ks < 6; ++ks) {
      int tap = ks >> 1, i0 = (ks & 1)*32;
      short8 af[6];
      #pragma unroll
      for (int mt = 0; mt < 6; ++mt)
        af[mt] = *(const short8*)&xi_lds[(ga[mt]*14 + ta[mt] + tap)*136 + h*64 + i0 + l4*8];
      short8 bm = *(const short8*)&Wg[(size_t)(wid*16 + l15)*192 + ks*32 + l4*8];
      short8 bg = *(const short8*)&Wg[(size_t)((wid+4)*16 + l15)*192 + ks*32 + l4*8];
      #pragma unroll
      for (int mt = 0; mt < 6; ++mt) {
        am[mt] = MFMA16(af[mt], bm, am[mt]);
        ag[mt] = MFMA16(af[mt], bg, ag[mt]);
      }
    }
    int o = wid*16 + l15;
    float bmv = (h ? b2m : b1m)[o];
    float bgv = (h ? b2g : b1g)[o];
    #pragma unroll
    for (int mt = 0; mt < 6; ++mt) {
      #pragma unroll
      for (int reg = 0; reg < 4; ++reg) {
        int r = mt*16 + l4*4 + reg;
        int g = r / 12, t = r - g*12;
        float pm = am[mt][reg] + bmv;
        float pg = ag[mt][reg] + bgv;
        float po = pm * sigmoidf_(pg);
        float xi = bf2f(xi_lds[(g*14 + t + 1)*136 + h*64 + o]);
        fu_lds[r*136 + h*64 + o] = f2bf(fmaxf(po + xi, 0.f));
      }
    }
  }
  __syncthreads();

  {
    f32x4 a3[6] = {};
    #pragma unroll
    for (int ks = 0; ks < 4; ++ks) {
      short8 af = *(const short8*)&WfB[(size_t)(wid*16 + l15)*128 + ks*32 + l4*8];
      #pragma unroll
      for (int nt = 0; nt < 6; ++nt) {
        short8 bf = *(const short8*)&fu_lds[(nt*16 + l15)*136 + ks*32 + l4*8];
        a3[nt] = MFMA16(af, bf, a3[nt]);
      }
    }
    int e0 = wid*16 + l4*4;
    float4 bb = *(const float4*)&bfc[e0];
    #pragma unroll
    for (int nt = 0; nt < 6; ++nt) {
      ushort4 vv;
      vv.x = f2bf(a3[nt][0] + bb.x); vv.y = f2bf(a3[nt][1] + bb.y);
      vv.z = f2bf(a3[nt][2] + bb.z); vv.w = f2bf(a3[nt][3] + bb.w);
      *(ushort4*)&outg[((size_t)(bn0 + ga[nt])*12 + ta[nt])*64 + e0] = vv;
    }
  }
}

// ---------------- K6: attention + FFN + 2x LN, full MFMA, 8 bn / 512 thr per block ------
// Wave map: wn = w&3 (col group), wm = w>>2 (row half: m-tiles wm*3..+2).
// LDS: Ybuf[96][72] | Qkv[96][216] / Hb[96][280] union | atts[8][16][24]  = 73728 B
__global__ __launch_bounds__(512) void k_attn4(
    const unsigned short* __restrict__ xg,     // bf16 [BN][12][64]
    const unsigned short* __restrict__ Wat,
    const float* __restrict__ bq, const float* __restrict__ bk, const float* __restrict__ bv,
    const float* __restrict__ bo,
    const float* __restrict__ f1b, const float* __restrict__ f2b,
    const float* __restrict__ g1, const float* __restrict__ be1,
    const float* __restrict__ g2, const float* __restrict__ be2,
    unsigned short* __restrict__ outg)
{
  __shared__ unsigned short su[36864];
  __shared__ float part[2][4][96];
  __shared__ float stats[2][96];
  unsigned short* Ybuf = su;            // [96][72]
  unsigned short* Qkv  = su + 6912;     // [96][216]
  unsigned short* Hb   = su + 6912;     // [96][280] (union with Qkv)
  unsigned short* atts = su + 33792;    // [8][16][24]

  const unsigned short* Wqkv = Wat;
  const unsigned short* Wo   = Wat + 12288;
  const unsigned short* F1   = Wat + 16384;
  const unsigned short* F2   = Wat + 32768;

  int tid = threadIdx.x, lane = tid & 63, w = tid >> 6;
  int l15 = lane & 15, l4 = lane >> 4;
  int wn = w & 3, wm = w >> 2;
  size_t base = (size_t)blockIdx.x * 8 * 768;

  // stage y (bf16, wide copies): 96 rows x 8 chunks
  for (int i = tid; i < 768; i += 512) {
    int r = i >> 3, c = i & 7;
    *(short8*)&Ybuf[r*72 + c*8] = *(const short8*)&xg[base + r*64 + c*8];
  }
  __syncthreads();

  // ---- QKV GEMM: Qkv[96][192]; wave: m-tiles wm*3..+2, n-tiles wn*3..+2 ----
  {
    f32x4 acc[3][3] = {};
    #pragma unroll
    for (int ks = 0; ks < 2; ++ks) {
      short8 af[3];
      #pragma unroll
      for (int mi = 0; mi < 3; ++mi)
        af[mi] = *(const short8*)&Ybuf[((wm*3+mi)*16 + l15)*72 + ks*32 + l4*8];
      #pragma unroll
      for (int ni = 0; ni < 3; ++ni) {
        int nt = wn*3 + ni;
        short8 bf = *(const short8*)&Wqkv[(size_t)(nt*16 + l15)*64 + ks*32 + l4*8];
        #pragma unroll
        for (int mi = 0; mi < 3; ++mi)
          acc[mi][ni] = MFMA16(af[mi], bf, acc[mi][ni]);
      }
    }
    #pragma unroll
    for (int ni = 0; ni < 3; ++ni) {
      int col = (wn*3+ni)*16 + l15;
      float bias = col < 64 ? bq[col] : (col < 128 ? bk[col-64] : bv[col-128]);
      #pragma unroll
      for (int mi = 0; mi < 3; ++mi)
        #pragma unroll
        for (int r = 0; r < 4; ++r)
          Qkv[((wm*3+mi)*16 + l4*4 + r)*216 + col] = f2bf(acc[mi][ni][r] + bias);
    }
  }
  __syncthreads();

  // ---- attention: wave w owns bn w (rows w*12..+11) ----
  {
    int rb = w*12;
    unsigned short* as = atts + w*384;   // [16][24]
    #pragma unroll
    for (int h = 0; h < 4; ++h) {
      short8 kf = {}, qf = {};
      if (l4 < 2) {
        kf = *(const short8*)&Qkv[(rb + l15)*216 + 64 + h*16 + l4*8];
        qf = *(const short8*)&Qkv[(rb + l15)*216 +      h*16 + l4*8];
      }
      f32x4 sc = {};
      sc = MFMA16(kf, qf, sc);
      float e[4]; float mx = -3e38f;
      #pragma unroll
      for (int r = 0; r < 4; ++r) {
        float v = (l4 == 3) ? -3e38f : sc[r]*0.25f;
        e[r] = v; mx = fmaxf(mx, v);
      }
      mx = fmaxf(mx, __shfl_xor(mx, 16));
      mx = fmaxf(mx, __shfl_xor(mx, 32));
      float s = 0.f;
      #pragma unroll
      for (int r = 0; r < 4; ++r) { e[r] = __expf(e[r] - mx); s += e[r]; }
      s += __shfl_xor(s, 16); s += __shfl_xor(s, 32);
      float inv = 1.f/s;
      ushort4 pk;
      pk.x = f2bf(e[0]*inv); pk.y = f2bf(e[1]*inv);
      pk.z = f2bf(e[2]*inv); pk.w = f2bf(e[3]*inv);
      *(ushort4*)&as[l15*24 + l4*4] = pk;
      short8 aaf = {};
      if (l4 < 2) aaf = *(const short8*)&as[l15*24 + l4*8];
      short8 vf = {};
      if (l4 < 2) {
        #pragma unroll
        for (int j = 0; j < 8; ++j) {
          int s_ = l4*8 + j;
          vf[j] = (s_ < 12) ? (short)Qkv[(rb + s_)*216 + 128 + h*16 + l15] : (short)0;
        }
      }
      f32x4 o = {};
      o = MFMA16(aaf, vf, o);
      if (l4 < 3) {
        #pragma unroll
        for (int r = 0; r < 4; ++r)
          Ybuf[(rb + l4*4 + r)*72 + h*16 + l15] = f2bf(o[r]);
      }
    }
  }
  __syncthreads();

  // ---- WO GEMM + residual + LN1 ----
  {
    f32x4 zacc[3] = {};
    #pragma unroll
    for (int ks = 0; ks < 2; ++ks) {
      short8 bf = *(const short8*)&Wo[(size_t)(wn*16 + l15)*64 + ks*32 + l4*8];
      #pragma unroll
      for (int mi = 0; mi < 3; ++mi) {
        short8 af = *(const short8*)&Ybuf[((wm*3+mi)*16 + l15)*72 + ks*32 + l4*8];
        zacc[mi] = MFMA16(af, bf, zacc[mi]);
      }
    }
    int col = wn*16 + l15;
    float bias = bo[col];
    #pragma unroll
    for (int mi = 0; mi < 3; ++mi)
      #pragma unroll
      for (int r = 0; r < 4; ++r) {
        int row = (wm*3+mi)*16 + l4*4 + r;
        float z = zacc[mi][r] + bias + bf2f(xg[base + row*64 + col]);
        zacc[mi][r] = z;
        float s1 = z, s2 = z*z;
        #pragma unroll
        for (int off = 1; off <= 8; off <<= 1) { s1 += __shfl_xor(s1, off); s2 += __shfl_xor(s2, off); }
        if (l15 == 0) { part[0][wn][row] = s1; part[1][wn][row] = s2; }
      }
    __syncthreads();
    if (tid < 96) {
      float s = part[0][0][tid]+part[0][1][tid]+part[0][2][tid]+part[0][3][tid];
      float q = part[1][0][tid]+part[1][1][tid]+part[1][2][tid]+part[1][3][tid];
      float mu = s * (1.f/64.f);
      float var = q * (1.f/64.f) - mu*mu;
      stats[0][tid] = mu; stats[1][tid] = rsqrtf(var + 1e-5f);
    }
    __syncthreads();
    float gv = g1[col], bvv = be1[col];
    #pragma unroll
    for (int mi = 0; mi < 3; ++mi)
      #pragma unroll
      for (int r = 0; r < 4; ++r) {
        int row = (wm*3+mi)*16 + l4*4 + r;
        Ybuf[row*72 + col] = f2bf((zacc[mi][r] - stats[0][row]) * stats[1][row] * gv + bvv);
      }
  }
  __syncthreads();

  // ---- FF1: Hb[96][256] = relu(y1 @ F1^T); wave: n-tiles wn*4..+3, m-tiles wm*3..+2 ----
  {
    f32x4 acc[3][4] = {};
    #pragma unroll
    for (int ks = 0; ks < 2; ++ks) {
      short8 af[3];
      #pragma unroll
      for (int mi = 0; mi < 3; ++mi)
        af[mi] = *(const short8*)&Ybuf[((wm*3+mi)*16 + l15)*72 + ks*32 + l4*8];
      #pragma unroll
      for (int i = 0; i < 4; ++i) {
        int nt = wn*4 + i;
        short8 bf = *(const short8*)&F1[(size_t)(nt*16 + l15)*64 + ks*32 + l4*8];
        #pragma unroll
        for (int mi = 0; mi < 3; ++mi)
          acc[mi][i] = MFMA16(af[mi], bf, acc[mi][i]);
      }
    }
    #pragma unroll
    for (int i = 0; i < 4; ++i) {
      int col = (wn*4+i)*16 + l15;
      float bias = f1b[col];
      #pragma unroll
      for (int mi = 0; mi < 3; ++mi)
        #pragma unroll
        for (int r = 0; r < 4; ++r)
          Hb[((wm*3+mi)*16 + l4*4 + r)*280 + col] = f2bf(fmaxf(acc[mi][i][r] + bias, 0.f));
    }
  }
  __syncthreads();

  // ---- FF2 + residual + LN2 + store y2 bf16 ----
  {
    f32x4 acc[3] = {};
    #pragma unroll
    for (int ks = 0; ks < 8; ++ks) {
      short8 bf = *(const short8*)&F2[(size_t)(wn*16 + l15)*256 + ks*32 + l4*8];
      #pragma unroll
      for (int mi = 0; mi < 3; ++mi) {
        short8 af = *(const short8*)&Hb[((wm*3+mi)*16 + l15)*280 + ks*32 + l4*8];
        acc[mi] = MFMA16(af, bf, acc[mi]);
      }
    }
    int col = wn*16 + l15;
    float bias = f2b[col];
    #pragma unroll
    for (int mi = 0; mi < 3; ++mi)
      #pragma unroll
      for (int r = 0; r < 4; ++r) {
        int row = (wm*3+mi)*16 + l4*4 + r;
        float z = acc[mi][r] + bias + bf2f(Ybuf[row*72 + col]);
        acc[mi][r] = z;
        float s1 = z, s2 = z*z;
        #pragma unroll
        for (int off = 1; off <= 8; off <<= 1) { s1 += __shfl_xor(s1, off); s2 += __shfl_xor(s2, off); }
        if (l15 == 0) { part[0][wn][row] = s1; part[1][wn][row] = s2; }
      }
    __syncthreads();
    if (tid < 96) {
      float s = part[0][0][tid]+part[0][1][tid]+part[0][2][tid]+part[0][3][tid];
      float q = part[1][0][tid]+part[1][1][tid]+part[1][2][tid]+part[1][3][tid];
      float mu = s * (1.f/64.f);
      float var = q * (1.f/64.f) - mu*mu;
      stats[0][tid] = mu; stats[1][tid] = rsqrtf(var + 1e-5f);
    }
    __syncthreads();
    float gv = g2[col], bvv = be2[col];
    #pragma unroll
    for (int mi = 0; mi < 3; ++mi)
      #pragma unroll
      for (int r = 0; r < 4; ++r) {
        int row = (wm*3+mi)*16 + l4*4 + r;
        outg[base + row*64 + col] = f2bf((acc[mi][r] - stats[0][row]) * stats[1][row] * gv + bvv);
      }
  }
}

// ---------------- K7: fuse-matrix prep ----------------
__global__ void k_mvec(const float* __restrict__ flow, const float* __restrict__ clw,
                       const float* __restrict__ clb, float* __restrict__ mv)
{
  int n = blockIdx.x*blockDim.x + threadIdx.x;
  if (n < N_) {
    float s = 0.f;
    float bias = clb[0];
    for (int b = 0; b < B_; ++b) {
      const float* f = flow + ((size_t)b*N_ + n)*T_;
      float acc = bias;
      #pragma unroll
      for (int t = 0; t < T_; ++t) acc += f[t]*clw[t];
      s += fmaxf(acc, 0.f);
    }
    mv[n] = s * (1.f/16.f);
  }
}

__global__ void k_fusemat(const float* __restrict__ mv, unsigned short* __restrict__ F)
{
  int idx = blockIdx.x*256 + threadIdx.x;
  int m = idx >> 10, n = idx & 1023;
  float x = 0.5f*(mv[m] + mv[n]);
  F[idx] = f2bf(1.f/(1.f + __expf(-x)));
}

// ---------------- launch ----------------
extern "C" void kernel_launch(void* const* d_in, const int* in_sizes, int n_in,
                              void* d_out, int out_size, void* d_ws, size_t ws_size,
                              hipStream_t stream)
{
  const float* flow = (const float*)d_in[0];
  const int*   day  = (const int*)d_in[1];
  const int*   week = (const int*)d_in[2];
  const float* semb = (const float*)d_in[3];
  const float* demb = (const float*)d_in[4];
  const float* wemb = (const float*)d_in[5];
  const float* gfsw = (const float*)d_in[6];
  const float* gfsb = (const float*)d_in[7];
  const float* gluw = (const float*)d_in[8];
  const float* glub = (const float*)d_in[9];
  const float* gcw  = (const float*)d_in[10];
  const float* gcA  = (const float*)d_in[11];
  const float* gcA2 = (const float*)d_in[12];
  const float* wi   = (const float*)d_in[13];
  const float* bi   = (const float*)d_in[14];
  const float* w1m  = (const float*)d_in[15];
  const float* b1m  = (const float*)d_in[16];
  const float* w1g  = (const float*)d_in[17];
  const float* b1g  = (const float*)d_in[18];
  const float* w2m  = (const float*)d_in[19];
  const float* b2m  = (const float*)d_in[20];
  const float* w2g  = (const float*)d_in[21];
  const float* b2g  = (const float*)d_in[22];
  const float* wfc  = (const float*)d_in[23];
  const float* bfc  = (const float*)d_in[24];
  const float* wq   = (const float*)d_in[25];
  const float* bq   = (const float*)d_in[26];
  const float* wk   = (const float*)d_in[27];
  const float* bk   = (const float*)d_in[28];
  const float* wv   = (const float*)d_in[29];
  const float* bv   = (const float*)d_in[30];
  const float* wo   = (const float*)d_in[31];
  const float* bo   = (const float*)d_in[32];
  const float* f1w  = (const float*)d_in[33];
  const float* f1b  = (const float*)d_in[34];
  const float* f2w  = (const float*)d_in[35];
  const float* f2b  = (const float*)d_in[36];
  const float* g1   = (const float*)d_in[37];
  const float* be1  = (const float*)d_in[38];
  const float* g2   = (const float*)d_in[39];
  const float* be2  = (const float*)d_in[40];
  const float* clw  = (const float*)d_in[41];
  const float* clb  = (const float*)d_in[42];

  float* out = (float*)d_out;
  char* ws = (char*)d_ws;
  unsigned short* Amat = (unsigned short*)ws;                               // 2 MB
  float* mv  = (float*)(ws + (size_t)2*1024*1024);                          // 64 KB region
  unsigned short* wTe = (unsigned short*)(ws + (size_t)2*1024*1024 + 64*1024); // 64 KB region
  unsigned short* wds = (unsigned short*)(ws + (size_t)2*1024*1024 + 128*1024); // 192 KB region
  unsigned short* wat = (unsigned short*)(ws + (size_t)2*1024*1024 + 320*1024); // 128 KB region
  unsigned short* xw  = (unsigned short*)(ws + (size_t)3*1024*1024);        // 24 MB
  unsigned short* xds = (unsigned short*)(ws + (size_t)28*1024*1024);       // 24 MB

  k_wprep_e2<<<64, 256, 0, stream>>>(gfsw, gluw, gcw, wTe);
  k_wprep3<<<96, 256, 0, stream>>>(wi, w1m, w1g, w2m, w2g, wfc, wds);
  k_wprep4<<<192, 256, 0, stream>>>(wq, wk, wv, wo, f1w, f2w, wat);
  // xw = GLU(gfs_fc(embed)) @ gc_weight -> bf16   (full MFMA)
  k_embed3<<<BNT/128, 256, 0, stream>>>(flow, day, week, semb, demb, wemb,
                                        wTe, gfsb, glub, xw);
  // combined adjacency (bf16)
  k_aprep<<<N_, 256, 0, stream>>>(gcA, gcA2, Amat);
  // xds = relu(A @ xw) -> bf16
  dim3 gg(TD/128, N_/128, B_);
  k_gemm_mfma<1,1><<<gg, 256, 0, stream>>>(Amat, xw, xds, N_, TD);
  // ds block (MFMA) -> bf16, in-place on xds
  k_ds3<<<BN_/8, 256, 0, stream>>>(xds, wds, bi, b1m, b1g, b2m, b2g, bfc, xds);
  // y2 = attn+ffn block (MFMA, 8 bn / 512 thr) -> bf16 (reuse xw region)
  k_attn4<<<BN_/8, 512, 0, stream>>>(xds, wat, bq, bk, bv, bo, f1b, f2b,
                                     g1, be1, g2, be2, xw);
  // fuse matrix (bf16, reuse Amat region)
  k_mvec<<<N_/256, 256, 0, stream>>>(flow, clw, clb, mv);
  k_fusemat<<<(N_*N_)/256, 256, 0, stream>>>(mv, Amat);
  // out = fuse @ y2 -> d_out (fp32)
  k_gemm_mfma<0,0><<<gg, 256, 0, stream>>>(Amat, xw, out, N_, TD);
}

// Round 12
// 332.911 us; speedup vs baseline: 19.4476x; 1.0185x over previous
//
#include <hip/hip_runtime.h>
#include <hip/hip_bf16.h>
#include <cstdint>

#define B_ 16
#define N_ 1024
#define T_ 12
#define HD 64
#define BN_ (B_*N_)     // 16384
#define BNT (B_*N_*T_)  // 196608
#define TD (T_*HD)      // 768

typedef __attribute__((ext_vector_type(8))) short short8;
typedef __attribute__((ext_vector_type(4))) float f32x4;

#define MFMA16(a,b,c) __builtin_amdgcn_mfma_f32_16x16x32_bf16(a,b,c,0,0,0)

__device__ __forceinline__ float sigmoidf_(float x) { return 1.f / (1.f + __expf(-x)); }

// f32 -> bf16 via compiler-lowered scalar cast (guide m240: compiler handles this well)
__device__ __forceinline__ unsigned short f2bf(float f) {
  __hip_bfloat16 h = __float2bfloat16(f);
  return __builtin_bit_cast(unsigned short, h);
}
__device__ __forceinline__ unsigned int f2bf2(float lo, float hi) {
  return (unsigned int)f2bf(lo) | ((unsigned int)f2bf(hi) << 16);
}
__device__ __forceinline__ float bf2f(unsigned short h) {
  unsigned int u = ((unsigned int)h) << 16;
  return __uint_as_float(u);
}

// ---------------- reductions ----------------
__device__ __forceinline__ float blkRedMax(float v, float* red) {
  #pragma unroll
  for (int off = 32; off >= 1; off >>= 1) v = fmaxf(v, __shfl_xor(v, off));
  int w = threadIdx.x >> 6;
  if ((threadIdx.x & 63) == 0) red[w] = v;
  __syncthreads();
  v = fmaxf(fmaxf(red[0], red[1]), fmaxf(red[2], red[3]));
  __syncthreads();
  return v;
}
__device__ __forceinline__ float blkRedSum(float v, float* red) {
  #pragma unroll
  for (int off = 32; off >= 1; off >>= 1) v += __shfl_xor(v, off);
  int w = threadIdx.x >> 6;
  if ((threadIdx.x & 63) == 0) red[w] = v;
  __syncthreads();
  v = red[0] + red[1] + red[2] + red[3];
  __syncthreads();
  return v;
}

// ---------------- K-wprep-e2: bf16 embed/glu/gc weights, B-frag natural [out][in] ------
__global__ void k_wprep_e2(const float* __restrict__ w1, const float* __restrict__ w2,
                           const float* __restrict__ gcw, unsigned short* __restrict__ W)
{
  int t = blockIdx.x*256 + threadIdx.x;   // 64*256 = 16384
  if (t < 4096)       W[t] = f2bf(w1[t]);
  else if (t < 12288) W[t] = f2bf(w2[t-4096]);
  else {
    int r = t - 12288, e = r >> 6, d = r & 63;
    W[12288 + e*64 + d] = f2bf(gcw[d*64 + e]);
  }
}

// ---------------- K-wprep3: bf16 tap-major conv weights for k_ds3 ----------------
__global__ void k_wprep3(const float* __restrict__ wi,
                         const float* __restrict__ w1m, const float* __restrict__ w1g,
                         const float* __restrict__ w2m, const float* __restrict__ w2g,
                         const float* __restrict__ wfc, unsigned short* __restrict__ W)
{
  int t = blockIdx.x*256 + threadIdx.x;  // 96*256 = 24576
  {
    int o = t / 192, k = t - o*192, tap = k >> 6, i = k & 63;
    W[o*192 + k] = f2bf(wi[(o*64 + i)*3 + tap]);
  }
  if (t < 12288) {
    int o = t / 192, k = t - o*192, tap = k >> 6, i = k & 63;
    int src = (o*64 + i)*3 + tap;
    W[24576 + o*192 + k]      = f2bf(w1m[src]);
    W[24576 + (64+o)*192 + k] = f2bf(w1g[src]);
    W[49152 + o*192 + k]      = f2bf(w2m[src]);
    W[49152 + (64+o)*192 + k] = f2bf(w2g[src]);
  }
  if (t < 8192) W[73728 + t] = f2bf(wfc[t]);
}

// ---------------- K-wprep4: bf16 cast of attn/ffn weights (natural layout) -------------
__global__ void k_wprep4(const float* __restrict__ wq, const float* __restrict__ wk,
                         const float* __restrict__ wv, const float* __restrict__ wo,
                         const float* __restrict__ f1w, const float* __restrict__ f2w,
                         unsigned short* __restrict__ W)
{
  int t = blockIdx.x*256 + threadIdx.x;  // 192*256 = 49152
  if (t < 4096)        W[t] = f2bf(wq[t]);
  else if (t < 8192)   W[t] = f2bf(wk[t-4096]);
  else if (t < 12288)  W[t] = f2bf(wv[t-8192]);
  else if (t < 16384)  W[t] = f2bf(wo[t-12288]);
  else if (t < 32768)  W[t] = f2bf(f1w[t-16384]);
  else                 W[t] = f2bf(f2w[t-32768]);
}

// ---------------- K1: embed + gfs_fc + GLU + (x @ gc_weight), full MFMA ----------------
__global__ __launch_bounds__(256) void k_embed3(
    const float* __restrict__ flow, const int* __restrict__ day, const int* __restrict__ week,
    const float* __restrict__ semb, const float* __restrict__ demb, const float* __restrict__ wemb,
    const unsigned short* __restrict__ wTe, const float* __restrict__ b1,
    const float* __restrict__ b2,
    unsigned short* __restrict__ outw)
{
  __shared__ unsigned short sEa[128*72];
  __shared__ unsigned short sEb[128*72];
  const unsigned short* W1  = wTe;
  const unsigned short* W2  = wTe + 4096;
  const unsigned short* GcT = wTe + 12288;

  int tid = threadIdx.x, lane = tid & 63, w = tid >> 6;
  int l15 = lane & 15, l4 = lane >> 4;
  int row0 = blockIdx.x * 128;

  for (int i = tid; i < 8192; i += 256) {
    int r = i >> 6, c = i & 63;
    int row = row0 + r;
    int n = (row / T_) & (N_-1);
    float val;
    if (c == 0)      val = flow[row];
    else if (c < 33) val = semb[n*32 + (c-1)];
    else if (c < 49) val = demb[day[row]*16 + (c-33)];
    else             val = wemb[week[row]*15 + (c-49)];
    sEa[r*72 + c] = f2bf(val);
  }
  __syncthreads();

  {
    f32x4 acc[8] = {};
    #pragma unroll
    for (int ks = 0; ks < 2; ++ks) {
      short8 bf = *(const short8*)&W1[(w*16 + l15)*64 + ks*32 + l4*8];
      #pragma unroll
      for (int mt = 0; mt < 8; ++mt) {
        short8 af = *(const short8*)&sEa[(mt*16 + l15)*72 + ks*32 + l4*8];
        acc[mt] = MFMA16(af, bf, acc[mt]);
      }
    }
    float bias = b1[w*16 + l15];
    #pragma unroll
    for (int mt = 0; mt < 8; ++mt)
      #pragma unroll
      for (int r = 0; r < 4; ++r)
        sEb[(mt*16 + l4*4 + r)*72 + w*16 + l15] = f2bf(acc[mt][r] + bias);
  }
  __syncthreads();

  {
    f32x4 alo[8] = {}, ahi[8] = {};
    #pragma unroll
    for (int ks = 0; ks < 2; ++ks) {
      short8 blo = *(const short8*)&W2[(size_t)(w*16 + l15)*64 + ks*32 + l4*8];
      short8 bhi = *(const short8*)&W2[(size_t)(64 + w*16 + l15)*64 + ks*32 + l4*8];
      #pragma unroll
      for (int mt = 0; mt < 8; ++mt) {
        short8 af = *(const short8*)&sEb[(mt*16 + l15)*72 + ks*32 + l4*8];
        alo[mt] = MFMA16(af, blo, alo[mt]);
        ahi[mt] = MFMA16(af, bhi, ahi[mt]);
      }
    }
    float blov = b2[w*16 + l15], bhiv = b2[64 + w*16 + l15];
    #pragma unroll
    for (int mt = 0; mt < 8; ++mt)
      #pragma unroll
      for (int r = 0; r < 4; ++r) {
        float v = (alo[mt][r] + blov) * sigmoidf_(ahi[mt][r] + bhiv);
        sEa[(mt*16 + l4*4 + r)*72 + w*16 + l15] = f2bf(v);
      }
  }
  __syncthreads();

  {
    f32x4 acc[8] = {};
    #pragma unroll
    for (int ks = 0; ks < 2; ++ks) {
      short8 bf = *(const short8*)&GcT[(w*16 + l15)*64 + ks*32 + l4*8];
      #pragma unroll
      for (int mt = 0; mt < 8; ++mt) {
        short8 af = *(const short8*)&sEa[(mt*16 + l15)*72 + ks*32 + l4*8];
        acc[mt] = MFMA16(af, bf, acc[mt]);
      }
    }
    #pragma unroll
    for (int mt = 0; mt < 8; ++mt)
      #pragma unroll
      for (int r = 0; r < 4; ++r)
        outw[(size_t)(row0 + mt*16 + l4*4 + r)*64 + w*16 + l15] = f2bf(acc[mt][r]);
  }
}

// ---------------- K2: A = softmax(relu(A1),1) + softmax(relu(A2),1), bf16 out ------------
__global__ __launch_bounds__(256) void k_aprep(
    const float* __restrict__ A1, const float* __restrict__ A2, unsigned short* __restrict__ Aout)
{
  __shared__ float red[4];
  int m = blockIdx.x, tid = threadIdx.x;
  float mx0, is0, mx1, is1;
  {
    const float* src = A1 + (size_t)m*N_;
    float mx = 0.f;
    for (int i = tid; i < N_; i += 256) mx = fmaxf(mx, fmaxf(src[i], 0.f));
    mx = blkRedMax(mx, red);
    float s = 0.f;
    for (int i = tid; i < N_; i += 256) s += __expf(fmaxf(src[i], 0.f) - mx);
    s = blkRedSum(s, red);
    mx0 = mx; is0 = 1.f / s;
  }
  {
    const float* src = A2 + (size_t)m*N_;
    float mx = 0.f;
    for (int i = tid; i < N_; i += 256) mx = fmaxf(mx, fmaxf(src[i], 0.f));
    mx = blkRedMax(mx, red);
    float s = 0.f;
    for (int i = tid; i < N_; i += 256) s += __expf(fmaxf(src[i], 0.f) - mx);
    s = blkRedSum(s, red);
    mx1 = mx; is1 = 1.f / s;
  }
  const float* s1 = A1 + (size_t)m*N_;
  const float* s2 = A2 + (size_t)m*N_;
  for (int i = tid; i < N_; i += 256) {
    float v1 = __expf(fmaxf(s1[i], 0.f) - mx0) * is0;
    float v2 = __expf(fmaxf(s2[i], 0.f) - mx1) * is1;
    Aout[(size_t)m*N_ + i] = f2bf(v1 + v2);
  }
}

// ---------------- K3: bf16 MFMA batched GEMM ----------------
template<int RELU, int OB16>
__global__ __launch_bounds__(256) void k_gemm_mfma(
    const unsigned short* __restrict__ A, const unsigned short* __restrict__ X,
    void* __restrict__ C, int K, int P)
{
  __shared__ unsigned short sA[128*40];
  __shared__ unsigned short sB[128*40];
  int tid = threadIdx.x, lane = tid & 63, wid = tid >> 6;
  int M = gridDim.y * 128;
  int b = blockIdx.z;
  const unsigned short* Xb = X + (size_t)b*K*P;
  int m0 = blockIdx.y*128, p0 = blockIdx.x*128;
  int wr = wid >> 1, wc = wid & 1;

  f32x4 acc[4][4] = {};

  for (int k0 = 0; k0 < K; k0 += 32) {
    #pragma unroll
    for (int pass = 0; pass < 2; ++pass) {
      int r = (tid >> 2) + 64*pass, kk = (tid & 3)*8;
      short8 v = *(const short8*)&A[(size_t)(m0+r)*K + k0 + kk];
      *(short8*)&sA[r*40 + kk] = v;
    }
    #pragma unroll
    for (int pass = 0; pass < 4; ++pass) {
      int p  = (tid & 63) + 64*(pass & 1);
      int k4 = (tid >> 6)*4 + 16*(pass >> 1);
      ushort4 h;
      h.x = Xb[(size_t)(k0+k4+0)*P + p0 + p];
      h.y = Xb[(size_t)(k0+k4+1)*P + p0 + p];
      h.z = Xb[(size_t)(k0+k4+2)*P + p0 + p];
      h.w = Xb[(size_t)(k0+k4+3)*P + p0 + p];
      *(ushort4*)&sB[p*40 + k4] = h;
    }
    __syncthreads();
    short8 af[4], bf[4];
    #pragma unroll
    for (int f = 0; f < 4; ++f) {
      af[f] = *(const short8*)&sA[(wr*64 + f*16 + (lane & 15))*40 + (lane >> 4)*8];
      bf[f] = *(const short8*)&sB[(wc*64 + f*16 + (lane & 15))*40 + (lane >> 4)*8];
    }
    #pragma unroll
    for (int fm = 0; fm < 4; ++fm)
      #pragma unroll
      for (int fn = 0; fn < 4; ++fn)
        acc[fm][fn] = MFMA16(af[fm], bf[fn], acc[fm][fn]);
    __syncthreads();
  }
  #pragma unroll
  for (int fm = 0; fm < 4; ++fm) {
    int row = m0 + wr*64 + fm*16 + (lane >> 4)*4;
    #pragma unroll
    for (int fn = 0; fn < 4; ++fn) {
      int col = p0 + wc*64 + fn*16 + (lane & 15);
      #pragma unroll
      for (int r = 0; r < 4; ++r) {
        float v = acc[fm][fn][r];
        if (RELU) v = fmaxf(v, 0.f);
        if (OB16) {
          unsigned short* Cb = (unsigned short*)C + (size_t)b*M*P;
          Cb[(size_t)(row + r)*P + col] = f2bf(v);
        } else {
          float* Cb = (float*)C + (size_t)b*M*P;
          Cb[(size_t)(row + r)*P + col] = v;
        }
      }
    }
  }
}

// ---------------- K5: ds temporal-conv block, MFMA, 8 bn per block; bf16 out (in-place) ----
__global__ __launch_bounds__(256) void k_ds3(
    const unsigned short* xds,
    const unsigned short* __restrict__ Wall,
    const float* __restrict__ bi,
    const float* __restrict__ b1m, const float* __restrict__ b1g,
    const float* __restrict__ b2m, const float* __restrict__ b2g,
    const float* __restrict__ bfc,
    unsigned short* outg)
{
  __shared__ unsigned short smem[36352];
  unsigned short* X_lds  = smem;               // [8][14][72]
  unsigned short* xi_lds = smem + 8064;        // [8][14][136]
  unsigned short* fu_lds = smem + 23296;       // [96][136]
  const unsigned short* WiB  = Wall;
  const unsigned short* Wg1B = Wall + 24576;
  const unsigned short* Wg2B = Wall + 49152;
  const unsigned short* WfB  = Wall + 73728;

  int tid = threadIdx.x, lane = tid & 63, wid = tid >> 6;
  int l15 = lane & 15, l4 = lane >> 4;
  int bn0 = blockIdx.x * 8;

  for (int i = tid; i < 8*2*72; i += 256) {
    int g = i / 144, r = i - g*144;
    int tp = (r < 72) ? 0 : 13, c = (r < 72) ? r : r - 72;
    X_lds[(g*14 + tp)*72 + c] = 0;
  }
  for (int i = tid; i < 8*2*136; i += 256) {
    int g = i / 272, r = i - g*272;
    int tp = (r < 136) ? 0 : 13, c = (r < 136) ? r : r - 136;
    xi_lds[(g*14 + tp)*136 + c] = 0;
  }
  for (int i = tid; i < 768; i += 256) {
    int g = i / 96, rem = i - g*96, t = rem >> 3, i8 = rem & 7;
    short8 v = *(const short8*)&xds[(size_t)(bn0+g)*768 + t*64 + i8*8];
    *(short8*)&X_lds[(g*14 + t + 1)*72 + i8*8] = v;
  }
  __syncthreads();

  int ga[6], ta[6];
  #pragma unroll
  for (int mt = 0; mt < 6; ++mt) {
    int r = mt*16 + l15;
    ga[mt] = r / 12; ta[mt] = r - ga[mt]*12;
  }

  {
    f32x4 acc1[6][2] = {};
    int nb = wid*2;
    #pragma unroll
    for (int ks = 0; ks < 6; ++ks) {
      int tap = ks >> 1, i0 = (ks & 1)*32;
      short8 af[6];
      #pragma unroll
      for (int mt = 0; mt < 6; ++mt)
        af[mt] = *(const short8*)&X_lds[(ga[mt]*14 + ta[mt] + tap)*72 + i0 + l4*8];
      short8 bf0 = *(const short8*)&WiB[(size_t)((nb  )*16 + l15)*192 + ks*32 + l4*8];
      short8 bf1 = *(const short8*)&WiB[(size_t)((nb+1)*16 + l15)*192 + ks*32 + l4*8];
      #pragma unroll
      for (int mt = 0; mt < 6; ++mt) {
        acc1[mt][0] = MFMA16(af[mt], bf0, acc1[mt][0]);
        acc1[mt][1] = MFMA16(af[mt], bf1, acc1[mt][1]);
      }
    }
    #pragma unroll
    for (int nn = 0; nn < 2; ++nn) {
      int o = (nb+nn)*16 + l15;
      float bv = bi[o];
      #pragma unroll
      for (int mt = 0; mt < 6; ++mt) {
        #pragma unroll
        for (int reg = 0; reg < 4; ++reg) {
          int r = mt*16 + l4*4 + reg;
          int g = r / 12, t = r - g*12;
          xi_lds[(g*14 + t + 1)*136 + o] = f2bf(acc1[mt][nn][reg] + bv);
        }
      }
    }
  }
  __syncthreads();

  #pragma unroll
  for (int h = 0; h < 2; ++h) {
    const unsigned short* Wg = h ? Wg2B : Wg1B;
    f32x4 am[6] = {}, ag[6] = {};
    #pragma unroll
    for (int ks = 0; ks < 6; ++ks) {
      int tap = ks >> 1, i0 = (ks & 1)*32;
      short8 af[6];
      #pragma unroll
      for (int mt = 0; mt < 6; ++mt)
        af[mt] = *(const short8*)&xi_lds[(ga[mt]*14 + ta[mt] + tap)*136 + h*64 + i0 + l4*8];
      short8 bm = *(const short8*)&Wg[(size_t)(wid*16 + l15)*192 + ks*32 + l4*8];
      short8 bg = *(const short8*)&Wg[(size_t)((wid+4)*16 + l15)*192 + ks*32 + l4*8];
      #pragma unroll
      for (int mt = 0; mt < 6; ++mt) {
        am[mt] = MFMA16(af[mt], bm, am[mt]);
        ag[mt] = MFMA16(af[mt], bg, ag[mt]);
      }
    }
    int o = wid*16 + l15;
    float bmv = (h ? b2m : b1m)[o];
    float bgv = (h ? b2g : b1g)[o];
    #pragma unroll
    for (int mt = 0; mt < 6; ++mt) {
      #pragma unroll
      for (int reg = 0; reg < 4; ++reg) {
        int r = mt*16 + l4*4 + reg;
        int g = r / 12, t = r - g*12;
        float pm = am[mt][reg] + bmv;
        float pg = ag[mt][reg] + bgv;
        float po = pm * sigmoidf_(pg);
        float xi = bf2f(xi_lds[(g*14 + t + 1)*136 + h*64 + o]);
        fu_lds[r*136 + h*64 + o] = f2bf(fmaxf(po + xi, 0.f));
      }
    }
  }
  __syncthreads();

  {
    f32x4 a3[6] = {};
    #pragma unroll
    for (int ks = 0; ks < 4; ++ks) {
      short8 af = *(const short8*)&WfB[(size_t)(wid*16 + l15)*128 + ks*32 + l4*8];
      #pragma unroll
      for (int nt = 0; nt < 6; ++nt) {
        short8 bf = *(const short8*)&fu_lds[(nt*16 + l15)*136 + ks*32 + l4*8];
        a3[nt] = MFMA16(af, bf, a3[nt]);
      }
    }
    int e0 = wid*16 + l4*4;
    float4 bb = *(const float4*)&bfc[e0];
    #pragma unroll
    for (int nt = 0; nt < 6; ++nt) {
      uint2 vv;
      vv.x = f2bf2(a3[nt][0] + bb.x, a3[nt][1] + bb.y);
      vv.y = f2bf2(a3[nt][2] + bb.z, a3[nt][3] + bb.w);
      *(uint2*)&outg[((size_t)(bn0 + ga[nt])*12 + ta[nt])*64 + e0] = vv;
    }
  }
}

// ---------------- K6: attention + FFN + 2x LN, full MFMA, 8 bn / 512 thr per block ------
// o is written into the dead q-region of Qkv so Ybuf keeps y -> WO residual from LDS.
__global__ __launch_bounds__(512) void k_attn4(
    const unsigned short* __restrict__ xg,     // bf16 [BN][12][64]
    const unsigned short* __restrict__ Wat,
    const float* __restrict__ bq, const float* __restrict__ bk, const float* __restrict__ bv,
    const float* __restrict__ bo,
    const float* __restrict__ f1b, const float* __restrict__ f2b,
    const float* __restrict__ g1, const float* __restrict__ be1,
    const float* __restrict__ g2, const float* __restrict__ be2,
    unsigned short* __restrict__ outg)
{
  __shared__ unsigned short su[36864];
  __shared__ float part[2][4][96];
  __shared__ float stats[2][96];
  unsigned short* Ybuf = su;            // [96][72]
  unsigned short* Qkv  = su + 6912;     // [96][216]
  unsigned short* Hb   = su + 6912;     // [96][280] (union with Qkv)
  unsigned short* atts = su + 33792;    // [8][16][24]

  const unsigned short* Wqkv = Wat;
  const unsigned short* Wo   = Wat + 12288;
  const unsigned short* F1   = Wat + 16384;
  const unsigned short* F2   = Wat + 32768;

  int tid = threadIdx.x, lane = tid & 63, w = tid >> 6;
  int l15 = lane & 15, l4 = lane >> 4;
  int wn = w & 3, wm = w >> 2;
  size_t base = (size_t)blockIdx.x * 8 * 768;

  // stage y (bf16, wide copies): 96 rows x 8 chunks
  for (int i = tid; i < 768; i += 512) {
    int r = i >> 3, c = i & 7;
    *(short8*)&Ybuf[r*72 + c*8] = *(const short8*)&xg[base + r*64 + c*8];
  }
  __syncthreads();

  // ---- QKV GEMM: Qkv[96][192]; wave: m-tiles wm*3..+2, n-tiles wn*3..+2 ----
  {
    f32x4 acc[3][3] = {};
    #pragma unroll
    for (int ks = 0; ks < 2; ++ks) {
      short8 af[3];
      #pragma unroll
      for (int mi = 0; mi < 3; ++mi)
        af[mi] = *(const short8*)&Ybuf[((wm*3+mi)*16 + l15)*72 + ks*32 + l4*8];
      #pragma unroll
      for (int ni = 0; ni < 3; ++ni) {
        int nt = wn*3 + ni;
        short8 bf = *(const short8*)&Wqkv[(size_t)(nt*16 + l15)*64 + ks*32 + l4*8];
        #pragma unroll
        for (int mi = 0; mi < 3; ++mi)
          acc[mi][ni] = MFMA16(af[mi], bf, acc[mi][ni]);
      }
    }
    #pragma unroll
    for (int ni = 0; ni < 3; ++ni) {
      int col = (wn*3+ni)*16 + l15;
      float bias = col < 64 ? bq[col] : (col < 128 ? bk[col-64] : bv[col-128]);
      #pragma unroll
      for (int mi = 0; mi < 3; ++mi)
        #pragma unroll
        for (int r = 0; r < 4; ++r)
          Qkv[((wm*3+mi)*16 + l4*4 + r)*216 + col] = f2bf(acc[mi][ni][r] + bias);
    }
  }
  __syncthreads();

  // ---- attention: wave w owns bn w (rows w*12..+11); o -> Qkv q-region (cols 0..63) ----
  {
    int rb = w*12;
    unsigned short* as = atts + w*384;   // [16][24]
    #pragma unroll
    for (int h = 0; h < 4; ++h) {
      short8 kf = {}, qf = {};
      if (l4 < 2) {
        kf = *(const short8*)&Qkv[(rb + l15)*216 + 64 + h*16 + l4*8];
        qf = *(const short8*)&Qkv[(rb + l15)*216 +      h*16 + l4*8];
      }
      f32x4 sc = {};
      sc = MFMA16(kf, qf, sc);
      float e[4]; float mx = -3e38f;
      #pragma unroll
      for (int r = 0; r < 4; ++r) {
        float v = (l4 == 3) ? -3e38f : sc[r]*0.25f;
        e[r] = v; mx = fmaxf(mx, v);
      }
      mx = fmaxf(mx, __shfl_xor(mx, 16));
      mx = fmaxf(mx, __shfl_xor(mx, 32));
      float s = 0.f;
      #pragma unroll
      for (int r = 0; r < 4; ++r) { e[r] = __expf(e[r] - mx); s += e[r]; }
      s += __shfl_xor(s, 16); s += __shfl_xor(s, 32);
      float inv = 1.f/s;
      uint2 pk = make_uint2(f2bf2(e[0]*inv, e[1]*inv), f2bf2(e[2]*inv, e[3]*inv));
      *(uint2*)&as[l15*24 + l4*4] = pk;
      short8 aaf = {};
      if (l4 < 2) aaf = *(const short8*)&as[l15*24 + l4*8];
      short8 vf = {};
      if (l4 < 2) {
        #pragma unroll
        for (int j = 0; j < 8; ++j) {
          int s_ = l4*8 + j;
          vf[j] = (s_ < 12) ? (short)Qkv[(rb + s_)*216 + 128 + h*16 + l15] : (short)0;
        }
      }
      f32x4 o = {};
      o = MFMA16(aaf, vf, o);
      if (l4 < 3) {
        #pragma unroll
        for (int r = 0; r < 4; ++r)
          Qkv[(rb + l4*4 + r)*216 + h*16 + l15] = f2bf(o[r]);   // q-region (dead)
      }
    }
  }
  __syncthreads();

  // ---- WO GEMM (o from Qkv q-region) + residual (y from Ybuf) + LN1 ----
  {
    f32x4 zacc[3] = {};
    #pragma unroll
    for (int ks = 0; ks < 2; ++ks) {
      short8 bf = *(const short8*)&Wo[(size_t)(wn*16 + l15)*64 + ks*32 + l4*8];
      #pragma unroll
      for (int mi = 0; mi < 3; ++mi) {
        short8 af = *(const short8*)&Qkv[((wm*3+mi)*16 + l15)*216 + ks*32 + l4*8];
        zacc[mi] = MFMA16(af, bf, zacc[mi]);
      }
    }
    int col = wn*16 + l15;
    float bias = bo[col];
    #pragma unroll
    for (int mi = 0; mi < 3; ++mi)
      #pragma unroll
      for (int r = 0; r < 4; ++r) {
        int row = (wm*3+mi)*16 + l4*4 + r;
        float z = zacc[mi][r] + bias + bf2f(Ybuf[row*72 + col]);
        zacc[mi][r] = z;
        float s1 = z, s2 = z*z;
        #pragma unroll
        for (int off = 1; off <= 8; off <<= 1) { s1 += __shfl_xor(s1, off); s2 += __shfl_xor(s2, off); }
        if (l15 == 0) { part[0][wn][row] = s1; part[1][wn][row] = s2; }
      }
    __syncthreads();
    if (tid < 96) {
      float s = part[0][0][tid]+part[0][1][tid]+part[0][2][tid]+part[0][3][tid];
      float q = part[1][0][tid]+part[1][1][tid]+part[1][2][tid]+part[1][3][tid];
      float mu = s * (1.f/64.f);
      float var = q * (1.f/64.f) - mu*mu;
      stats[0][tid] = mu; stats[1][tid] = rsqrtf(var + 1e-5f);
    }
    __syncthreads();
    float gv = g1[col], bvv = be1[col];
    #pragma unroll
    for (int mi = 0; mi < 3; ++mi)
      #pragma unroll
      for (int r = 0; r < 4; ++r) {
        int row = (wm*3+mi)*16 + l4*4 + r;
        Ybuf[row*72 + col] = f2bf((zacc[mi][r] - stats[0][row]) * stats[1][row] * gv + bvv);
      }
  }
  __syncthreads();

  // ---- FF1: Hb[96][256] = relu(y1 @ F1^T) ----
  {
    f32x4 acc[3][4] = {};
    #pragma unroll
    for (int ks = 0; ks < 2; ++ks) {
      short8 af[3];
      #pragma unroll
      for (int mi = 0; mi < 3; ++mi)
        af[mi] = *(const short8*)&Ybuf[((wm*3+mi)*16 + l15)*72 + ks*32 + l4*8];
      #pragma unroll
      for (int i = 0; i < 4; ++i) {
        int nt = wn*4 + i;
        short8 bf = *(const short8*)&F1[(size_t)(nt*16 + l15)*64 + ks*32 + l4*8];
        #pragma unroll
        for (int mi = 0; mi < 3; ++mi)
          acc[mi][i] = MFMA16(af[mi], bf, acc[mi][i]);
      }
    }
    #pragma unroll
    for (int i = 0; i < 4; ++i) {
      int col = (wn*4+i)*16 + l15;
      float bias = f1b[col];
      #pragma unroll
      for (int mi = 0; mi < 3; ++mi)
        #pragma unroll
        for (int r = 0; r < 4; ++r)
          Hb[((wm*3+mi)*16 + l4*4 + r)*280 + col] = f2bf(fmaxf(acc[mi][i][r] + bias, 0.f));
    }
  }
  __syncthreads();

  // ---- FF2 + residual + LN2 + store y2 bf16 ----
  {
    f32x4 acc[3] = {};
    #pragma unroll
    for (int ks = 0; ks < 8; ++ks) {
      short8 bf = *(const short8*)&F2[(size_t)(wn*16 + l15)*256 + ks*32 + l4*8];
      #pragma unroll
      for (int mi = 0; mi < 3; ++mi) {
        short8 af = *(const short8*)&Hb[((wm*3+mi)*16 + l15)*280 + ks*32 + l4*8];
        acc[mi] = MFMA16(af, bf, acc[mi]);
      }
    }
    int col = wn*16 + l15;
    float bias = f2b[col];
    #pragma unroll
    for (int mi = 0; mi < 3; ++mi)
      #pragma unroll
      for (int r = 0; r < 4; ++r) {
        int row = (wm*3+mi)*16 + l4*4 + r;
        float z = acc[mi][r] + bias + bf2f(Ybuf[row*72 + col]);
        acc[mi][r] = z;
        float s1 = z, s2 = z*z;
        #pragma unroll
        for (int off = 1; off <= 8; off <<= 1) { s1 += __shfl_xor(s1, off); s2 += __shfl_xor(s2, off); }
        if (l15 == 0) { part[0][wn][row] = s1; part[1][wn][row] = s2; }
      }
    __syncthreads();
    if (tid < 96) {
      float s = part[0][0][tid]+part[0][1][tid]+part[0][2][tid]+part[0][3][tid];
      float q = part[1][0][tid]+part[1][1][tid]+part[1][2][tid]+part[1][3][tid];
      float mu = s * (1.f/64.f);
      float var = q * (1.f/64.f) - mu*mu;
      stats[0][tid] = mu; stats[1][tid] = rsqrtf(var + 1e-5f);
    }
    __syncthreads();
    float gv = g2[col], bvv = be2[col];
    #pragma unroll
    for (int mi = 0; mi < 3; ++mi)
      #pragma unroll
      for (int r = 0; r < 4; ++r) {
        int row = (wm*3+mi)*16 + l4*4 + r;
        outg[base + row*64 + col] = f2bf((acc[mi][r] - stats[0][row]) * stats[1][row] * gv + bvv);
      }
  }
}

// ---------------- K7: fuse-matrix prep ----------------
__global__ void k_mvec(const float* __restrict__ flow, const float* __restrict__ clw,
                       const float* __restrict__ clb, float* __restrict__ mv)
{
  int n = blockIdx.x*blockDim.x + threadIdx.x;
  if (n < N_) {
    float s = 0.f;
    float bias = clb[0];
    for (int b = 0; b < B_; ++b) {
      const float* f = flow + ((size_t)b*N_ + n)*T_;
      float acc = bias;
      #pragma unroll
      for (int t = 0; t < T_; ++t) acc += f[t]*clw[t];
      s += fmaxf(acc, 0.f);
    }
    mv[n] = s * (1.f/16.f);
  }
}

__global__ void k_fusemat(const float* __restrict__ mv, unsigned short* __restrict__ F)
{
  int idx = blockIdx.x*256 + threadIdx.x;
  int m = idx >> 10, n = idx & 1023;
  float x = 0.5f*(mv[m] + mv[n]);
  F[idx] = f2bf(1.f/(1.f + __expf(-x)));
}

// ---------------- launch ----------------
extern "C" void kernel_launch(void* const* d_in, const int* in_sizes, int n_in,
                              void* d_out, int out_size, void* d_ws, size_t ws_size,
                              hipStream_t stream)
{
  const float* flow = (const float*)d_in[0];
  const int*   day  = (const int*)d_in[1];
  const int*   week = (const int*)d_in[2];
  const float* semb = (const float*)d_in[3];
  const float* demb = (const float*)d_in[4];
  const float* wemb = (const float*)d_in[5];
  const float* gfsw = (const float*)d_in[6];
  const float* gfsb = (const float*)d_in[7];
  const float* gluw = (const float*)d_in[8];
  const float* glub = (const float*)d_in[9];
  const float* gcw  = (const float*)d_in[10];
  const float* gcA  = (const float*)d_in[11];
  const float* gcA2 = (const float*)d_in[12];
  const float* wi   = (const float*)d_in[13];
  const float* bi   = (const float*)d_in[14];
  const float* w1m  = (const float*)d_in[15];
  const float* b1m  = (const float*)d_in[16];
  const float* w1g  = (const float*)d_in[17];
  const float* b1g  = (const float*)d_in[18];
  const float* w2m  = (const float*)d_in[19];
  const float* b2m  = (const float*)d_in[20];
  const float* w2g  = (const float*)d_in[21];
  const float* b2g  = (const float*)d_in[22];
  const float* wfc  = (const float*)d_in[23];
  const float* bfc  = (const float*)d_in[24];
  const float* wq   = (const float*)d_in[25];
  const float* bq   = (const float*)d_in[26];
  const float* wk   = (const float*)d_in[27];
  const float* bk   = (const float*)d_in[28];
  const float* wv   = (const float*)d_in[29];
  const float* bv   = (const float*)d_in[30];
  const float* wo   = (const float*)d_in[31];
  const float* bo   = (const float*)d_in[32];
  const float* f1w  = (const float*)d_in[33];
  const float* f1b  = (const float*)d_in[34];
  const float* f2w  = (const float*)d_in[35];
  const float* f2b  = (const float*)d_in[36];
  const float* g1   = (const float*)d_in[37];
  const float* be1  = (const float*)d_in[38];
  const float* g2   = (const float*)d_in[39];
  const float* be2  = (const float*)d_in[40];
  const float* clw  = (const float*)d_in[41];
  const float* clb  = (const float*)d_in[42];

  float* out = (float*)d_out;
  char* ws = (char*)d_ws;
  unsigned short* Amat = (unsigned short*)ws;                               // 2 MB
  float* mv  = (float*)(ws + (size_t)2*1024*1024);                          // 64 KB region
  unsigned short* wTe = (unsigned short*)(ws + (size_t)2*1024*1024 + 64*1024); // 64 KB region
  unsigned short* wds = (unsigned short*)(ws + (size_t)2*1024*1024 + 128*1024); // 192 KB region
  unsigned short* wat = (unsigned short*)(ws + (size_t)2*1024*1024 + 320*1024); // 128 KB region
  unsigned short* xw  = (unsigned short*)(ws + (size_t)3*1024*1024);        // 24 MB
  unsigned short* xds = (unsigned short*)(ws + (size_t)28*1024*1024);       // 24 MB

  k_wprep_e2<<<64, 256, 0, stream>>>(gfsw, gluw, gcw, wTe);
  k_wprep3<<<96, 256, 0, stream>>>(wi, w1m, w1g, w2m, w2g, wfc, wds);
  k_wprep4<<<192, 256, 0, stream>>>(wq, wk, wv, wo, f1w, f2w, wat);
  // xw = GLU(gfs_fc(embed)) @ gc_weight -> bf16   (full MFMA)
  k_embed3<<<BNT/128, 256, 0, stream>>>(flow, day, week, semb, demb, wemb,
                                        wTe, gfsb, glub, xw);
  // combined adjacency (bf16)
  k_aprep<<<N_, 256, 0, stream>>>(gcA, gcA2, Amat);
  // xds = relu(A @ xw) -> bf16
  dim3 gg(TD/128, N_/128, B_);
  k_gemm_mfma<1,1><<<gg, 256, 0, stream>>>(Amat, xw, xds, N_, TD);
  // ds block (MFMA) -> bf16, in-place on xds
  k_ds3<<<BN_/8, 256, 0, stream>>>(xds, wds, bi, b1m, b1g, b2m, b2g, bfc, xds);
  // y2 = attn+ffn block (MFMA, 8 bn / 512 thr) -> bf16 (reuse xw region)
  k_attn4<<<BN_/8, 512, 0, stream>>>(xds, wat, bq, bk, bv, bo, f1b, f2b,
                                     g1, be1, g2, be2, xw);
  // fuse matrix (bf16, reuse Amat region)
  k_mvec<<<N_/256, 256, 0, stream>>>(flow, clw, clb, mv);
  k_fusemat<<<(N_*N_)/256, 256, 0, stream>>>(mv, Amat);
  // out = fuse @ y2 -> d_out (fp32)
  k_gemm_mfma<0,0><<<gg, 256, 0, stream>>>(Amat, xw, out, N_, TD);
}